// Round 3
// baseline (326.486 us; speedup 1.0000x reference)
//
#include <hip/hip_runtime.h>
#include <hip/hip_bf16.h>
#include <cstdint>

// ---------- types ----------
typedef __bf16 bf16x8 __attribute__((ext_vector_type(8)));
typedef __bf16 bf16x4 __attribute__((ext_vector_type(4)));
typedef float  f32x4  __attribute__((ext_vector_type(4)));
typedef __attribute__((address_space(3))) __bf16 lds_bf16;
typedef __attribute__((address_space(1))) const __bf16 gl_bf16;

// ---------- fp32 -> bf16 convert (vectorized) ----------
__global__ void cvt_f32_bf16(const float* __restrict__ src, __bf16* __restrict__ dst, int n) {
    int i = (blockIdx.x * blockDim.x + threadIdx.x) * 4;
    if (i + 3 < n) {
        float4 v = *reinterpret_cast<const float4*>(src + i);
        bf16x4 o;
        o.x = (__bf16)v.x; o.y = (__bf16)v.y; o.z = (__bf16)v.z; o.w = (__bf16)v.w;
        *reinterpret_cast<bf16x4*>(dst + i) = o;
    }
}

// ---------- concat bq|bk|bv into one 2560-float buffer ----------
__global__ void concat_bias(const float* __restrict__ bq, const float* __restrict__ bk,
                            const float* __restrict__ bv, float* __restrict__ dst) {
    int t = blockIdx.x * blockDim.x + threadIdx.x;
    if (t < 2048)      dst[t] = bq[t];
    else if (t < 2304) dst[t] = bk[t - 2048];
    else if (t < 2560) dst[t] = bv[t - 2304];
}

// ---------- GEMM: C[m,n] = sum_k A[m,k]*B[n,k] (+bias[n]), bf16 in / fp32 out ----------
// m97 structure: 128x128 tile, BK=32, 4 waves (2x2), 16x16x32 MFMA,
// global_load_lds width-16 staging, 2 barriers per K-step. 1-D grid with
// bijective XCD swizzle (grid % 8 == 0 guaranteed by launch).
template<bool BIAS>
__global__ __launch_bounds__(256)
void gemm_bt(const __bf16* __restrict__ A, const __bf16* __restrict__ B,
             const float* __restrict__ bias, float* __restrict__ C,
             int N, int K, int NBN) {
    __shared__ __align__(16) __bf16 As[128 * 32];
    __shared__ __align__(16) __bf16 Bs[128 * 32];
    const int tid  = threadIdx.x;
    const int wave = tid >> 6, lane = tid & 63, lg = lane >> 4, ll = lane & 15;
    const int wr = wave >> 1, wc = wave & 1;

    // XCD-aware bijective swizzle (nwg % 8 == 0)
    const int nwg  = gridDim.x;
    const int cpx  = nwg >> 3;
    const int orig = blockIdx.x;
    const int wg   = (orig & 7) * cpx + (orig >> 3);
    const int bm = wg / NBN, bn = wg - bm * NBN;

    const __bf16* Ab = A + (size_t)bm * 128 * K;
    const __bf16* Bb = B + (size_t)bn * 128 * K;

    lds_bf16* AsL = (lds_bf16*)As;
    lds_bf16* BsL = (lds_bf16*)Bs;

    f32x4 acc[4][4];
    for (int m = 0; m < 4; ++m)
        for (int n = 0; n < 4; ++n)
            acc[m][n] = f32x4{0.f, 0.f, 0.f, 0.f};

    const int row0 = tid >> 2;          // 0..63
    const int cs   = (tid & 3) * 8;     // 0,8,16,24
    const size_t rstride = (size_t)row0 * K + cs;

    for (int k0 = 0; k0 < K; k0 += 32) {
        __syncthreads();
        const __bf16* ga = Ab + rstride + k0;
        const __bf16* gb = Bb + rstride + k0;
        __builtin_amdgcn_global_load_lds((gl_bf16*)ga,                  AsL + wave * 512,        16, 0, 0);
        __builtin_amdgcn_global_load_lds((gl_bf16*)(ga + (size_t)64*K), AsL + 2048 + wave * 512, 16, 0, 0);
        __builtin_amdgcn_global_load_lds((gl_bf16*)gb,                  BsL + wave * 512,        16, 0, 0);
        __builtin_amdgcn_global_load_lds((gl_bf16*)(gb + (size_t)64*K), BsL + 2048 + wave * 512, 16, 0, 0);
        __syncthreads();

        bf16x8 af[4], bfr[4];
        for (int m = 0; m < 4; ++m)
            af[m] = *reinterpret_cast<const bf16x8*>(&As[(wr * 64 + m * 16 + ll) * 32 + lg * 8]);
        for (int n = 0; n < 4; ++n)
            bfr[n] = *reinterpret_cast<const bf16x8*>(&Bs[(wc * 64 + n * 16 + ll) * 32 + lg * 8]);
        for (int m = 0; m < 4; ++m)
            for (int n = 0; n < 4; ++n)
                acc[m][n] = __builtin_amdgcn_mfma_f32_16x16x32_bf16(af[m], bfr[n], acc[m][n], 0, 0, 0);
    }

    for (int m = 0; m < 4; ++m)
        for (int n = 0; n < 4; ++n) {
            const int col = bn * 128 + wc * 64 + n * 16 + ll;
            const float bv = BIAS ? bias[col] : 0.f;
            for (int r = 0; r < 4; ++r) {
                const int rowg = bm * 128 + wr * 64 + m * 16 + lg * 4 + r;
                C[(size_t)rowg * N + col] = acc[m][n][r] + bv;
            }
        }
}

// ---------- RoPE + layout transform ----------
__global__ void rope_kernel(const float* __restrict__ qkv, const float* __restrict__ cosb,
                            const float* __restrict__ sinb, __bf16* __restrict__ qT,
                            __bf16* __restrict__ kT, __bf16* __restrict__ vT) {
    const int row = blockIdx.x;          // b*2048 + l
    const int b = row >> 11, l = row & 2047;
    const int t = threadIdx.x;
    const float* r = qkv + (size_t)row * 2560;
    const float qscale = 0.08838834764831845f;   // 1/sqrt(128)

    for (int idx = t; idx < 2048; idx += 256) {
        const int h = idx >> 7, d = idx & 127;
        const float v = r[idx];
        const float partner = (d < 64) ? -r[h * 128 + d + 64] : r[h * 128 + d - 64];
        const float c = cosb[l * 128 + d], s = sinb[l * 128 + d];
        const float out = v * c + partner * s;
        qT[(((size_t)(b * 16 + h)) * 2048 + l) * 128 + d] = (__bf16)(out * qscale);
    }
    {
        const int idx = t;
        const int kvh = idx >> 7, d = idx & 127;
        const float v = r[2048 + idx];
        const float partner = (d < 64) ? -r[2048 + kvh * 128 + d + 64]
                                       : r[2048 + kvh * 128 + d - 64];
        const float c = cosb[l * 128 + d], s = sinb[l * 128 + d];
        const float out = v * c + partner * s;
        kT[(((size_t)(b * 2 + kvh)) * 2048 + l) * 128 + d] = (__bf16)out;
        const float vv = r[2304 + idx];
        vT[(((size_t)(b * 2 + kvh)) * 128 + d) * 2048 + l] = (__bf16)vv;
    }
}

// ---------- causal GQA flash attention ----------
// 1024 blocks, balanced qb permutation: each group of 4 blocks landing on one
// CU (bx, bx+256, bx+512, bx+768) sums to exactly 66 KV-tile units.
// 4 waves x 16 q rows, KV tile = 64. XOR-swizzled unpadded LDS (40 KB).
// Reg prefetch of next K/V tile; diag-only masking; defer-max rescale (T13);
// setprio around MFMA clusters (T5).
__global__ __launch_bounds__(256)
void attn_kernel(const __bf16* __restrict__ qT, const __bf16* __restrict__ kT,
                 const __bf16* __restrict__ vT, __bf16* __restrict__ attnb) {
    const int bx = blockIdx.x;
    const int i5 = bx >> 5, j = i5 & 7, g = i5 >> 3;
    int qb;
    if (g == 0)      qb = 31 - j;
    else if (g == 1) qb = 16 + j;
    else if (g == 2) qb = 15 - j;
    else             qb = j;
    const int hb = bx & 31;
    const int h = hb >> 1, b = hb & 1;
    const int kv = h >> 3;               // G = 8
    const int tid = threadIdx.x, wave = tid >> 6, lane = tid & 63, lg = lane >> 4, ll = lane & 15;

    __shared__ __align__(16) __bf16 Kl[64 * 128];     // [key][d], chunk^=(key&7)
    __shared__ __align__(16) __bf16 Vl[128 * 64];     // [d][key], chunk^=(d&7)
    __shared__ __align__(16) __bf16 Pl[4][16 * 64];   // per-wave, chunk^=(row&7)^((row>>3)<<1)

    const int q0 = qb * 64 + wave * 16;
    const __bf16* qbase = qT + ((size_t)((b * 16 + h) * 2048) + q0 + ll) * 128;
    bf16x8 qf[4];
    for (int kk = 0; kk < 4; ++kk)
        qf[kk] = *reinterpret_cast<const bf16x8*>(qbase + kk * 32 + lg * 8);

    f32x4 o[8];
    for (int nd = 0; nd < 8; ++nd) o[nd] = f32x4{0.f, 0.f, 0.f, 0.f};
    float mrow[4] = {-3e38f, -3e38f, -3e38f, -3e38f};
    float srow[4] = {0.f, 0.f, 0.f, 0.f};

    const __bf16* kbase = kT + (size_t)((b * 2 + kv) * 2048) * 128;
    const __bf16* vbase = vT + (size_t)((b * 2 + kv) * 128) * 2048;
    const int ntiles = qb + 1;

    char* KlB = (char*)Kl;
    char* VlB = (char*)Vl;
    char* PlB = (char*)&Pl[wave][0];

    bf16x8 kr[4], vr[4];
    // prologue: load tile 0 and store to LDS
    {
        #pragma unroll
        for (int i = 0; i < 4; ++i) {
            const int li = i * 256 + tid;
            const int key = li >> 4, c = li & 15;
            kr[i] = *reinterpret_cast<const bf16x8*>(kbase + (size_t)key * 128 + c * 8);
            const int dd = li >> 3, cv = li & 7;
            vr[i] = *reinterpret_cast<const bf16x8*>(vbase + (size_t)dd * 2048 + cv * 8);
        }
        #pragma unroll
        for (int i = 0; i < 4; ++i) {
            const int li = i * 256 + tid;
            const int key = li >> 4, c = li & 15;
            *reinterpret_cast<bf16x8*>(KlB + key * 256 + ((c ^ (key & 7)) << 4)) = kr[i];
            const int dd = li >> 3, cv = li & 7;
            *reinterpret_cast<bf16x8*>(VlB + dd * 128 + ((cv ^ (dd & 7)) << 4)) = vr[i];
        }
        __syncthreads();
    }

    for (int t = 0; t < ntiles; ++t) {
        // issue next tile's global loads (latency hides under compute below)
        if (t + 1 < ntiles) {
            const int j0n = (t + 1) * 64;
            #pragma unroll
            for (int i = 0; i < 4; ++i) {
                const int li = i * 256 + tid;
                const int key = li >> 4, c = li & 15;
                kr[i] = *reinterpret_cast<const bf16x8*>(kbase + (size_t)(j0n + key) * 128 + c * 8);
                const int dd = li >> 3, cv = li & 7;
                vr[i] = *reinterpret_cast<const bf16x8*>(vbase + (size_t)dd * 2048 + j0n + cv * 8);
            }
        }
        const int j0 = t * 64;

        // S = Q K^T  (scale folded into Q)
        f32x4 s[4];
        for (int n = 0; n < 4; ++n) s[n] = f32x4{0.f, 0.f, 0.f, 0.f};
        __builtin_amdgcn_s_setprio(1);
        #pragma unroll
        for (int kk = 0; kk < 4; ++kk)
            #pragma unroll
            for (int n = 0; n < 4; ++n) {
                const int row = n * 16 + ll;
                bf16x8 kf = *reinterpret_cast<const bf16x8*>(
                    KlB + row * 256 + (((kk * 4 + lg) ^ (ll & 7)) << 4));
                s[n] = __builtin_amdgcn_mfma_f32_16x16x32_bf16(qf[kk], kf, s[n], 0, 0, 0);
            }
        __builtin_amdgcn_s_setprio(0);

        // causal mask only on the diagonal tile
        if (t == qb) {
            #pragma unroll
            for (int r = 0; r < 4; ++r) {
                const int qrow = q0 + lg * 4 + r;
                #pragma unroll
                for (int n = 0; n < 4; ++n) {
                    const int col = j0 + n * 16 + ll;
                    if (col > qrow) s[n][r] = -3e38f;
                }
            }
        }

        // online softmax with defer-max (THR=8)
        #pragma unroll
        for (int r = 0; r < 4; ++r) {
            float tmax = fmaxf(fmaxf(s[0][r], s[1][r]), fmaxf(s[2][r], s[3][r]));
            #pragma unroll
            for (int off = 1; off < 16; off <<= 1)
                tmax = fmaxf(tmax, __shfl_xor(tmax, off));
            if (tmax > mrow[r] + 8.f) {
                const float scl = __expf(mrow[r] - tmax);
                mrow[r] = tmax;
                srow[r] *= scl;
                #pragma unroll
                for (int nd = 0; nd < 8; ++nd) o[nd][r] *= scl;
            }
            float rs = 0.f;
            #pragma unroll
            for (int n = 0; n < 4; ++n) {
                const float p = __expf(s[n][r] - mrow[r]);
                s[n][r] = p;
                rs += p;
            }
            #pragma unroll
            for (int off = 1; off < 16; off <<= 1)
                rs += __shfl_xor(rs, off);
            srow[r] += rs;
        }

        // P -> per-wave LDS (swizzled, wave-private so no barrier)
        #pragma unroll
        for (int n = 0; n < 4; ++n)
            #pragma unroll
            for (int r = 0; r < 4; ++r) {
                const int row = lg * 4 + r, col = n * 16 + ll;
                *reinterpret_cast<__bf16*>(
                    PlB + row * 128 +
                    ((((col >> 3) ^ (row & 7) ^ ((row >> 3) << 1))) << 4) + (col & 7) * 2)
                    = (__bf16)s[n][r];
            }

        // O += P V
        __builtin_amdgcn_s_setprio(1);
        #pragma unroll
        for (int kk = 0; kk < 2; ++kk) {
            bf16x8 pf = *reinterpret_cast<const bf16x8*>(
                PlB + ll * 128 + (((kk * 4 + lg) ^ (ll & 7) ^ ((ll >> 3) << 1)) << 4));
            #pragma unroll
            for (int nd = 0; nd < 8; ++nd) {
                const int row = nd * 16 + ll;
                bf16x8 vf = *reinterpret_cast<const bf16x8*>(
                    VlB + row * 128 + (((kk * 4 + lg) ^ (ll & 7)) << 4));
                o[nd] = __builtin_amdgcn_mfma_f32_16x16x32_bf16(pf, vf, o[nd], 0, 0, 0);
            }
        }
        __builtin_amdgcn_s_setprio(0);

        __syncthreads();   // all waves done reading Kl/Vl
        if (t + 1 < ntiles) {
            #pragma unroll
            for (int i = 0; i < 4; ++i) {
                const int li = i * 256 + tid;
                const int key = li >> 4, c = li & 15;
                *reinterpret_cast<bf16x8*>(KlB + key * 256 + ((c ^ (key & 7)) << 4)) = kr[i];
                const int dd = li >> 3, cv = li & 7;
                *reinterpret_cast<bf16x8*>(VlB + dd * 128 + ((cv ^ (dd & 7)) << 4)) = vr[i];
            }
            __syncthreads();
        }
    }

    // epilogue: normalize and store to (B, L, H*D) bf16
    #pragma unroll
    for (int r = 0; r < 4; ++r) {
        const int qrow = q0 + lg * 4 + r;
        const float inv = 1.f / srow[r];
        #pragma unroll
        for (int nd = 0; nd < 8; ++nd)
            attnb[((size_t)(b * 2048) + qrow) * 2048 + h * 128 + nd * 16 + ll] = (__bf16)(o[nd][r] * inv);
    }
}

// ---------- host launch ----------
extern "C" void kernel_launch(void* const* d_in, const int* in_sizes, int n_in,
                              void* d_out, int out_size, void* d_ws, size_t ws_size,
                              hipStream_t stream) {
    const float* x    = (const float*)d_in[0];
    const float* cosb = (const float*)d_in[1];
    const float* sinb = (const float*)d_in[2];
    const float* wq   = (const float*)d_in[3];
    const float* bq   = (const float*)d_in[4];
    const float* wk   = (const float*)d_in[5];
    const float* bk   = (const float*)d_in[6];
    const float* wv   = (const float*)d_in[7];
    const float* bv   = (const float*)d_in[8];
    const float* wo   = (const float*)d_in[9];
    float* out = (float*)d_out;

    char* ws = (char*)d_ws;
    __bf16* xb    = (__bf16*)(ws);                         // 16,777,216  (later reused as attnb)
    __bf16* wb    = (__bf16*)(ws + 16777216);              // 10,485,760  (wq|wk|wv rows, 2560x2048)
    __bf16* wob   = (__bf16*)(ws + 27262976);              //  8,388,608
    float*  biasc = (float*) (ws + 35651584);              //     16,384 (2560 used)
    float*  qkvr  = (float*) (ws + 35667968);              // 41,943,040 (4096x2560)
    __bf16* qTp   = (__bf16*)(ws + 77611008);              // 16,777,216
    __bf16* kTp   = (__bf16*)(ws + 94388224);              //  2,097,152
    __bf16* vTp   = (__bf16*)(ws + 96485376);              //  2,097,152

    // 1) convert to bf16
    cvt_f32_bf16<<<8192, 256, 0, stream>>>(x,  xb, 8388608);
    cvt_f32_bf16<<<4096, 256, 0, stream>>>(wq, wb, 4194304);
    cvt_f32_bf16<<<512,  256, 0, stream>>>(wk, wb + 4194304, 524288);
    cvt_f32_bf16<<<512,  256, 0, stream>>>(wv, wb + 4718592, 524288);
    cvt_f32_bf16<<<4096, 256, 0, stream>>>(wo, wob, 4194304);
    concat_bias<<<10, 256, 0, stream>>>(bq, bk, bv, biasc);

    // 2) fused QKV GEMM: (4096x2048) x (2560x2048)^T + bias -> fp32  [640 wg]
    gemm_bt<true><<<640, 256, 0, stream>>>(xb, wb, biasc, qkvr, 2560, 2048, 20);

    // 3) RoPE + layout
    rope_kernel<<<4096, 256, 0, stream>>>(qkvr, cosb, sinb, qTp, kTp, vTp);

    // 4) flash attention -> attnb (reuses xb region, bf16 (B,L,H*D))
    attn_kernel<<<1024, 256, 0, stream>>>(qTp, kTp, vTp, xb);

    // 5) output GEMM: (4096x2048) x (2048x2048)^T -> fp32 d_out  [512 wg]
    gemm_bt<false><<<512, 256, 0, stream>>>(xb, wob, nullptr, out, 2048, 2048, 16);
}

// Round 4
// 260.717 us; speedup vs baseline: 1.2523x; 1.2523x over previous
//
#include <hip/hip_runtime.h>
#include <hip/hip_bf16.h>
#include <cstdint>

// ---------- types ----------
typedef __bf16 bf16x8 __attribute__((ext_vector_type(8)));
typedef __bf16 bf16x4 __attribute__((ext_vector_type(4)));
typedef float  f32x4  __attribute__((ext_vector_type(4)));
typedef __attribute__((address_space(3))) __bf16 lds_bf16;
typedef __attribute__((address_space(1))) const __bf16 gl_bf16;

// ---------- fp32 -> bf16 convert (vectorized) ----------
__global__ void cvt_f32_bf16(const float* __restrict__ src, __bf16* __restrict__ dst, int n) {
    int i = (blockIdx.x * blockDim.x + threadIdx.x) * 4;
    if (i + 3 < n) {
        float4 v = *reinterpret_cast<const float4*>(src + i);
        bf16x4 o;
        o.x = (__bf16)v.x; o.y = (__bf16)v.y; o.z = (__bf16)v.z; o.w = (__bf16)v.w;
        *reinterpret_cast<bf16x4*>(dst + i) = o;
    }
}

// ---------- concat bq|bk|bv into one 2560-float buffer ----------
__global__ void concat_bias(const float* __restrict__ bq, const float* __restrict__ bk,
                            const float* __restrict__ bv, float* __restrict__ dst) {
    int t = blockIdx.x * blockDim.x + threadIdx.x;
    if (t < 2048)      dst[t] = bq[t];
    else if (t < 2304) dst[t] = bk[t - 2048];
    else if (t < 2560) dst[t] = bv[t - 2304];
}

// ---------- out-proj GEMM: C[m,n] = sum_k A[m,k]*B[n,k], bf16 in / fp32 out ----------
// m97 structure: 128x128 tile, BK=32, 4 waves (2x2), global_load_lds width-16.
__global__ __launch_bounds__(256)
void gemm_bt(const __bf16* __restrict__ A, const __bf16* __restrict__ B,
             float* __restrict__ C, int N, int K, int NBN) {
    __shared__ __align__(16) __bf16 As[128 * 32];
    __shared__ __align__(16) __bf16 Bs[128 * 32];
    const int tid  = threadIdx.x;
    const int wave = tid >> 6, lane = tid & 63, lg = lane >> 4, ll = lane & 15;
    const int wr = wave >> 1, wc = wave & 1;

    const int nwg  = gridDim.x;
    const int cpx  = nwg >> 3;
    const int orig = blockIdx.x;
    const int wg   = (orig & 7) * cpx + (orig >> 3);
    const int bm = wg / NBN, bn = wg - bm * NBN;

    const __bf16* Ab = A + (size_t)bm * 128 * K;
    const __bf16* Bb = B + (size_t)bn * 128 * K;

    lds_bf16* AsL = (lds_bf16*)As;
    lds_bf16* BsL = (lds_bf16*)Bs;

    f32x4 acc[4][4];
    for (int m = 0; m < 4; ++m)
        for (int n = 0; n < 4; ++n)
            acc[m][n] = f32x4{0.f, 0.f, 0.f, 0.f};

    const int row0 = tid >> 2;
    const int cs   = (tid & 3) * 8;
    const size_t rstride = (size_t)row0 * K + cs;

    for (int k0 = 0; k0 < K; k0 += 32) {
        __syncthreads();
        const __bf16* ga = Ab + rstride + k0;
        const __bf16* gb = Bb + rstride + k0;
        __builtin_amdgcn_global_load_lds((gl_bf16*)ga,                  AsL + wave * 512,        16, 0, 0);
        __builtin_amdgcn_global_load_lds((gl_bf16*)(ga + (size_t)64*K), AsL + 2048 + wave * 512, 16, 0, 0);
        __builtin_amdgcn_global_load_lds((gl_bf16*)gb,                  BsL + wave * 512,        16, 0, 0);
        __builtin_amdgcn_global_load_lds((gl_bf16*)(gb + (size_t)64*K), BsL + 2048 + wave * 512, 16, 0, 0);
        __syncthreads();

        bf16x8 af[4], bfr[4];
        for (int m = 0; m < 4; ++m)
            af[m] = *reinterpret_cast<const bf16x8*>(&As[(wr * 64 + m * 16 + ll) * 32 + lg * 8]);
        for (int n = 0; n < 4; ++n)
            bfr[n] = *reinterpret_cast<const bf16x8*>(&Bs[(wc * 64 + n * 16 + ll) * 32 + lg * 8]);
        for (int m = 0; m < 4; ++m)
            for (int n = 0; n < 4; ++n)
                acc[m][n] = __builtin_amdgcn_mfma_f32_16x16x32_bf16(af[m], bfr[n], acc[m][n], 0, 0, 0);
    }

    for (int m = 0; m < 4; ++m)
        for (int n = 0; n < 4; ++n) {
            const int col = bn * 128 + wc * 64 + n * 16 + ll;
            for (int r = 0; r < 4; ++r) {
                const int rowg = bm * 128 + wr * 64 + m * 16 + lg * 4 + r;
                C[(size_t)rowg * N + col] = acc[m][n][r];
            }
        }
}

// ---------- QKV GEMM with fused bias + RoPE + layout epilogue ----------
// A (4096x2048) bf16, B (2560x2048) bf16 rows = wq|wk|wv. Tile 128x128; each
// col-tile is exactly one head-slot (0-15 Q, 16-17 K, 18-19 V). RoPE partner
// (d^64) exchanged through padded LDS per m-chunk. Writes qT/kT/vT directly.
__global__ __launch_bounds__(256)
void gemm_qkv_rope(const __bf16* __restrict__ A, const __bf16* __restrict__ B,
                   const float* __restrict__ bias, const float* __restrict__ cosb,
                   const float* __restrict__ sinb, __bf16* __restrict__ qT,
                   __bf16* __restrict__ kT, __bf16* __restrict__ vT) {
    const int K = 2048, NBN = 20;
    __shared__ __align__(16) __bf16 As[128 * 32];
    __shared__ __align__(16) __bf16 Bs[128 * 32];
    __shared__ float Ex[32][132];   // rope partner exchange, padded stride

    const int tid  = threadIdx.x;
    const int wave = tid >> 6, lane = tid & 63, lg = lane >> 4, ll = lane & 15;
    const int wr = wave >> 1, wc = wave & 1;

    const int nwg  = gridDim.x;
    const int cpx  = nwg >> 3;
    const int orig = blockIdx.x;
    const int wg   = (orig & 7) * cpx + (orig >> 3);
    const int bm = wg / NBN, bn = wg - bm * NBN;

    const __bf16* Ab = A + (size_t)bm * 128 * K;
    const __bf16* Bb = B + (size_t)bn * 128 * K;

    lds_bf16* AsL = (lds_bf16*)As;
    lds_bf16* BsL = (lds_bf16*)Bs;

    f32x4 acc[4][4];
    for (int m = 0; m < 4; ++m)
        for (int n = 0; n < 4; ++n)
            acc[m][n] = f32x4{0.f, 0.f, 0.f, 0.f};

    const int row0 = tid >> 2;
    const int cs   = (tid & 3) * 8;
    const size_t rstride = (size_t)row0 * K + cs;

    for (int k0 = 0; k0 < K; k0 += 32) {
        __syncthreads();
        const __bf16* ga = Ab + rstride + k0;
        const __bf16* gb = Bb + rstride + k0;
        __builtin_amdgcn_global_load_lds((gl_bf16*)ga,                  AsL + wave * 512,        16, 0, 0);
        __builtin_amdgcn_global_load_lds((gl_bf16*)(ga + (size_t)64*K), AsL + 2048 + wave * 512, 16, 0, 0);
        __builtin_amdgcn_global_load_lds((gl_bf16*)gb,                  BsL + wave * 512,        16, 0, 0);
        __builtin_amdgcn_global_load_lds((gl_bf16*)(gb + (size_t)64*K), BsL + 2048 + wave * 512, 16, 0, 0);
        __syncthreads();

        bf16x8 af[4], bfr[4];
        for (int m = 0; m < 4; ++m)
            af[m] = *reinterpret_cast<const bf16x8*>(&As[(wr * 64 + m * 16 + ll) * 32 + lg * 8]);
        for (int n = 0; n < 4; ++n)
            bfr[n] = *reinterpret_cast<const bf16x8*>(&Bs[(wc * 64 + n * 16 + ll) * 32 + lg * 8]);
        for (int m = 0; m < 4; ++m)
            for (int n = 0; n < 4; ++n)
                acc[m][n] = __builtin_amdgcn_mfma_f32_16x16x32_bf16(af[m], bfr[n], acc[m][n], 0, 0, 0);
    }

    // ---- epilogue ----
    if (bn >= 18) {
        // V: bias only, transposed store (b, kv, d, l) with 8B chunks
        const int kvh = bn - 18;
        for (int m = 0; m < 4; ++m)
            for (int n = 0; n < 4; ++n) {
                const int d = wc * 64 + n * 16 + ll;
                const float bv = bias[bn * 128 + d];
                const int rbase = bm * 128 + wr * 64 + m * 16 + lg * 4;
                const int b = rbase >> 11, l0 = rbase & 2047;
                bf16x4 o4;
                for (int r = 0; r < 4; ++r) o4[r] = (__bf16)(acc[m][n][r] + bv);
                *reinterpret_cast<bf16x4*>(&vT[((size_t)(b * 2 + kvh) * 128 + d) * 2048 + l0]) = o4;
            }
    } else {
        // Q/K: bias + RoPE (partner d^64 via LDS), q-scale folded for Q
        const float qsc = (bn < 16) ? 0.08838834764831845f : 1.0f;
        for (int m = 0; m < 4; ++m) {
            __syncthreads();   // previous m's Ex reads done
            for (int n = 0; n < 4; ++n) {
                const int col = wc * 64 + n * 16 + ll;
                const float bv = bias[bn * 128 + col];
                for (int r = 0; r < 4; ++r)
                    Ex[wr * 16 + lg * 4 + r][col] = acc[m][n][r] + bv;
            }
            __syncthreads();
            for (int n = 0; n < 4; ++n) {
                const int col = wc * 64 + n * 16 + ll;
                const float sgn = (col < 64) ? -1.f : 1.f;
                for (int r = 0; r < 4; ++r) {
                    const int er = wr * 16 + lg * 4 + r;
                    const float self = Ex[er][col];
                    const float part = Ex[er][col ^ 64];
                    const int rowg = bm * 128 + wr * 64 + m * 16 + lg * 4 + r;
                    const int b = rowg >> 11, l = rowg & 2047;
                    const float c = cosb[l * 128 + col], s = sinb[l * 128 + col];
                    const float val = (self * c + sgn * part * s) * qsc;
                    if (bn < 16)
                        qT[(((size_t)(b * 16 + bn)) * 2048 + l) * 128 + col] = (__bf16)val;
                    else
                        kT[(((size_t)(b * 2 + (bn - 16))) * 2048 + l) * 128 + col] = (__bf16)val;
                }
            }
        }
    }
}

// ---------- causal GQA flash attention (r2-proven structure + T5 setprio) ----------
// 1024 blocks, heavy (large-qb) first. 4 waves x 16 q rows, KV tile = 64.
// XOR-swizzled unpadded LDS tiles (40 KB -> 4 blocks/CU). Reg prefetch of
// next K/V tile. 2 barriers per tile.
__global__ __launch_bounds__(256)
void attn_kernel(const __bf16* __restrict__ qT, const __bf16* __restrict__ kT,
                 const __bf16* __restrict__ vT, __bf16* __restrict__ attnb) {
    const int bx = blockIdx.x;
    const int qb = 31 - (bx >> 5);       // heavy blocks first
    const int hb = bx & 31;
    const int h = hb >> 1, b = hb & 1;
    const int kv = h >> 3;               // G = 8
    const int tid = threadIdx.x, wave = tid >> 6, lane = tid & 63, lg = lane >> 4, ll = lane & 15;

    __shared__ __align__(16) __bf16 Kl[64 * 128];     // [key][d], chunk^=(key&7)
    __shared__ __align__(16) __bf16 Vl[128 * 64];     // [d][key], chunk^=(d&7)
    __shared__ __align__(16) __bf16 Pl[4][16 * 64];   // per-wave [qrow][key], chunk^=(row&7)

    const int q0 = qb * 64 + wave * 16;
    const __bf16* qbase = qT + ((size_t)((b * 16 + h) * 2048) + q0 + ll) * 128;
    bf16x8 qf[4];
    for (int kk = 0; kk < 4; ++kk)
        qf[kk] = *reinterpret_cast<const bf16x8*>(qbase + kk * 32 + lg * 8);

    f32x4 o[8];
    for (int nd = 0; nd < 8; ++nd) o[nd] = f32x4{0.f, 0.f, 0.f, 0.f};
    float mrow[4] = {-3e38f, -3e38f, -3e38f, -3e38f};
    float srow[4] = {0.f, 0.f, 0.f, 0.f};

    const __bf16* kbase = kT + (size_t)((b * 2 + kv) * 2048) * 128;
    const __bf16* vbase = vT + (size_t)((b * 2 + kv) * 128) * 2048;
    const int ntiles = qb + 1;

    char* KlB = (char*)Kl;
    char* VlB = (char*)Vl;
    char* PlB = (char*)&Pl[wave][0];

    bf16x8 kr[4], vr[4];
    // prologue: load tile 0 and store to LDS
    {
        #pragma unroll
        for (int i = 0; i < 4; ++i) {
            const int li = i * 256 + tid;
            const int key = li >> 4, c = li & 15;
            kr[i] = *reinterpret_cast<const bf16x8*>(kbase + (size_t)key * 128 + c * 8);
            const int dd = li >> 3, cv = li & 7;
            vr[i] = *reinterpret_cast<const bf16x8*>(vbase + (size_t)dd * 2048 + cv * 8);
        }
        #pragma unroll
        for (int i = 0; i < 4; ++i) {
            const int li = i * 256 + tid;
            const int key = li >> 4, c = li & 15;
            *reinterpret_cast<bf16x8*>(KlB + key * 256 + ((c ^ (key & 7)) << 4)) = kr[i];
            const int dd = li >> 3, cv = li & 7;
            *reinterpret_cast<bf16x8*>(VlB + dd * 128 + ((cv ^ (dd & 7)) << 4)) = vr[i];
        }
        __syncthreads();
    }

    for (int t = 0; t < ntiles; ++t) {
        // issue next tile's global loads (latency hides under compute below)
        if (t + 1 < ntiles) {
            const int j0n = (t + 1) * 64;
            #pragma unroll
            for (int i = 0; i < 4; ++i) {
                const int li = i * 256 + tid;
                const int key = li >> 4, c = li & 15;
                kr[i] = *reinterpret_cast<const bf16x8*>(kbase + (size_t)(j0n + key) * 128 + c * 8);
                const int dd = li >> 3, cv = li & 7;
                vr[i] = *reinterpret_cast<const bf16x8*>(vbase + (size_t)dd * 2048 + j0n + cv * 8);
            }
        }
        const int j0 = t * 64;

        // S = Q K^T  (scale folded into Q)
        f32x4 s[4];
        for (int n = 0; n < 4; ++n) s[n] = f32x4{0.f, 0.f, 0.f, 0.f};
        __builtin_amdgcn_s_setprio(1);
        #pragma unroll
        for (int kk = 0; kk < 4; ++kk)
            #pragma unroll
            for (int n = 0; n < 4; ++n) {
                const int row = n * 16 + ll;
                bf16x8 kf = *reinterpret_cast<const bf16x8*>(
                    KlB + row * 256 + (((kk * 4 + lg) ^ (ll & 7)) << 4));
                s[n] = __builtin_amdgcn_mfma_f32_16x16x32_bf16(qf[kk], kf, s[n], 0, 0, 0);
            }
        __builtin_amdgcn_s_setprio(0);

        // causal mask + online softmax (rows live across 16-lane groups)
        #pragma unroll
        for (int r = 0; r < 4; ++r) {
            const int qrow = q0 + lg * 4 + r;
            float tmax = -3e38f;
            #pragma unroll
            for (int n = 0; n < 4; ++n) {
                const int col = j0 + n * 16 + ll;
                float v = s[n][r];
                v = (col > qrow) ? -3e38f : v;
                s[n][r] = v;
                tmax = fmaxf(tmax, v);
            }
            #pragma unroll
            for (int off = 1; off < 16; off <<= 1)
                tmax = fmaxf(tmax, __shfl_xor(tmax, off));
            const float mnew = fmaxf(mrow[r], tmax);
            const float scl = __expf(mrow[r] - mnew);
            mrow[r] = mnew;
            float rs = 0.f;
            #pragma unroll
            for (int n = 0; n < 4; ++n) {
                const float p = __expf(s[n][r] - mnew);
                s[n][r] = p;
                rs += p;
            }
            #pragma unroll
            for (int off = 1; off < 16; off <<= 1)
                rs += __shfl_xor(rs, off);
            srow[r] = srow[r] * scl + rs;
            for (int nd = 0; nd < 8; ++nd) o[nd][r] *= scl;
        }

        // P -> per-wave LDS (swizzled); no barrier needed (wave-private)
        #pragma unroll
        for (int n = 0; n < 4; ++n)
            #pragma unroll
            for (int r = 0; r < 4; ++r) {
                const int row = lg * 4 + r, col = n * 16 + ll;
                *reinterpret_cast<__bf16*>(
                    PlB + row * 128 + (((col >> 3) ^ (row & 7)) << 4) + (col & 7) * 2)
                    = (__bf16)s[n][r];
            }

        // O += P V
        __builtin_amdgcn_s_setprio(1);
        #pragma unroll
        for (int kk = 0; kk < 2; ++kk) {
            bf16x8 pf = *reinterpret_cast<const bf16x8*>(
                PlB + ll * 128 + (((kk * 4 + lg) ^ (ll & 7)) << 4));
            #pragma unroll
            for (int nd = 0; nd < 8; ++nd) {
                const int row = nd * 16 + ll;
                bf16x8 vf = *reinterpret_cast<const bf16x8*>(
                    VlB + row * 128 + (((kk * 4 + lg) ^ (ll & 7)) << 4));
                o[nd] = __builtin_amdgcn_mfma_f32_16x16x32_bf16(pf, vf, o[nd], 0, 0, 0);
            }
        }
        __builtin_amdgcn_s_setprio(0);

        __syncthreads();   // all waves done reading Kl/Vl
        if (t + 1 < ntiles) {
            #pragma unroll
            for (int i = 0; i < 4; ++i) {
                const int li = i * 256 + tid;
                const int key = li >> 4, c = li & 15;
                *reinterpret_cast<bf16x8*>(KlB + key * 256 + ((c ^ (key & 7)) << 4)) = kr[i];
                const int dd = li >> 3, cv = li & 7;
                *reinterpret_cast<bf16x8*>(VlB + dd * 128 + ((cv ^ (dd & 7)) << 4)) = vr[i];
            }
            __syncthreads();
        }
    }

    // epilogue: normalize and store to (B, L, H*D) bf16
    #pragma unroll
    for (int r = 0; r < 4; ++r) {
        const int qrow = q0 + lg * 4 + r;
        const float inv = 1.f / srow[r];
        #pragma unroll
        for (int nd = 0; nd < 8; ++nd)
            attnb[((size_t)(b * 2048) + qrow) * 2048 + h * 128 + nd * 16 + ll] = (__bf16)(o[nd][r] * inv);
    }
}

// ---------- host launch ----------
extern "C" void kernel_launch(void* const* d_in, const int* in_sizes, int n_in,
                              void* d_out, int out_size, void* d_ws, size_t ws_size,
                              hipStream_t stream) {
    const float* x    = (const float*)d_in[0];
    const float* cosb = (const float*)d_in[1];
    const float* sinb = (const float*)d_in[2];
    const float* wq   = (const float*)d_in[3];
    const float* bq   = (const float*)d_in[4];
    const float* wk   = (const float*)d_in[5];
    const float* bk   = (const float*)d_in[6];
    const float* wv   = (const float*)d_in[7];
    const float* bv   = (const float*)d_in[8];
    const float* wo   = (const float*)d_in[9];
    float* out = (float*)d_out;

    char* ws = (char*)d_ws;
    __bf16* xb    = (__bf16*)(ws);                         // 16,777,216  (later reused as attnb)
    __bf16* wb    = (__bf16*)(ws + 16777216);              // 10,485,760  (wq|wk|wv rows, 2560x2048)
    __bf16* wob   = (__bf16*)(ws + 27262976);              //  8,388,608
    float*  biasc = (float*) (ws + 35651584);              //     16,384 (2560 used)
    __bf16* qTp   = (__bf16*)(ws + 77611008);              // 16,777,216
    __bf16* kTp   = (__bf16*)(ws + 94388224);              //  2,097,152
    __bf16* vTp   = (__bf16*)(ws + 96485376);              //  2,097,152

    // 1) convert to bf16
    cvt_f32_bf16<<<8192, 256, 0, stream>>>(x,  xb, 8388608);
    cvt_f32_bf16<<<4096, 256, 0, stream>>>(wq, wb, 4194304);
    cvt_f32_bf16<<<512,  256, 0, stream>>>(wk, wb + 4194304, 524288);
    cvt_f32_bf16<<<512,  256, 0, stream>>>(wv, wb + 4718592, 524288);
    cvt_f32_bf16<<<4096, 256, 0, stream>>>(wo, wob, 4194304);
    concat_bias<<<10, 256, 0, stream>>>(bq, bk, bv, biasc);

    // 2) fused QKV GEMM + bias + RoPE + layout  [640 wg]
    gemm_qkv_rope<<<640, 256, 0, stream>>>(xb, wb, biasc, cosb, sinb, qTp, kTp, vTp);

    // 3) flash attention -> attnb (reuses xb region, bf16 (B,L,H*D))
    attn_kernel<<<1024, 256, 0, stream>>>(qTp, kTp, vTp, xb);

    // 4) output GEMM: (4096x2048) x (2048x2048)^T -> fp32 d_out  [512 wg]
    gemm_bt<<<512, 256, 0, stream>>>(xb, wob, out, 2048, 2048, 16);
}

// Round 5
// 237.414 us; speedup vs baseline: 1.3752x; 1.0982x over previous
//
#include <hip/hip_runtime.h>
#include <hip/hip_bf16.h>
#include <cstdint>

// ---------- types ----------
typedef __bf16 bf16x8 __attribute__((ext_vector_type(8)));
typedef __bf16 bf16x4 __attribute__((ext_vector_type(4)));
typedef __bf16 bf16x2 __attribute__((ext_vector_type(2)));
typedef float  f32x4  __attribute__((ext_vector_type(4)));
typedef __attribute__((address_space(3))) __bf16 lds_bf16;
typedef __attribute__((address_space(1))) const __bf16 gl_bf16;

// ---------- merged fp32 -> bf16 convert (5 segments, one launch) ----------
__global__ void cvt_all(const float* __restrict__ s0, __bf16* __restrict__ d0, int n0,
                        const float* __restrict__ s1, __bf16* __restrict__ d1, int n1,
                        const float* __restrict__ s2, __bf16* __restrict__ d2, int n2,
                        const float* __restrict__ s3, __bf16* __restrict__ d3, int n3,
                        const float* __restrict__ s4, __bf16* __restrict__ d4, int n4) {
    const float* s; __bf16* d; int n;
    switch (blockIdx.y) {
        case 0: s = s0; d = d0; n = n0; break;
        case 1: s = s1; d = d1; n = n1; break;
        case 2: s = s2; d = d2; n = n2; break;
        case 3: s = s3; d = d3; n = n3; break;
        default: s = s4; d = d4; n = n4; break;
    }
    int i = (blockIdx.x * blockDim.x + threadIdx.x) * 4;
    if (i + 3 < n) {
        float4 v = *reinterpret_cast<const float4*>(s + i);
        bf16x4 o;
        o.x = (__bf16)v.x; o.y = (__bf16)v.y; o.z = (__bf16)v.z; o.w = (__bf16)v.w;
        *reinterpret_cast<bf16x4*>(d + i) = o;
    }
}

// ---------- concat bq|bk|bv into one 2560-float buffer ----------
__global__ void concat_bias(const float* __restrict__ bq, const float* __restrict__ bk,
                            const float* __restrict__ bv, float* __restrict__ dst) {
    int t = blockIdx.x * blockDim.x + threadIdx.x;
    if (t < 2048)      dst[t] = bq[t];
    else if (t < 2304) dst[t] = bk[t - 2048];
    else if (t < 2560) dst[t] = bv[t - 2304];
}

// ---------- out-proj GEMM: C[m,n] = sum_k A[m,k]*B[n,k], bf16 in / fp32 out ----------
__global__ __launch_bounds__(256)
void gemm_bt(const __bf16* __restrict__ A, const __bf16* __restrict__ B,
             float* __restrict__ C, int N, int K, int NBN) {
    __shared__ __align__(16) __bf16 As[128 * 32];
    __shared__ __align__(16) __bf16 Bs[128 * 32];
    const int tid  = threadIdx.x;
    const int wave = tid >> 6, lane = tid & 63, lg = lane >> 4, ll = lane & 15;
    const int wr = wave >> 1, wc = wave & 1;

    const int nwg  = gridDim.x;
    const int cpx  = nwg >> 3;
    const int orig = blockIdx.x;
    const int wg   = (orig & 7) * cpx + (orig >> 3);
    const int bm = wg / NBN, bn = wg - bm * NBN;

    const __bf16* Ab = A + (size_t)bm * 128 * K;
    const __bf16* Bb = B + (size_t)bn * 128 * K;

    lds_bf16* AsL = (lds_bf16*)As;
    lds_bf16* BsL = (lds_bf16*)Bs;

    f32x4 acc[4][4];
    for (int m = 0; m < 4; ++m)
        for (int n = 0; n < 4; ++n)
            acc[m][n] = f32x4{0.f, 0.f, 0.f, 0.f};

    const int row0 = tid >> 2;
    const int cs   = (tid & 3) * 8;
    const size_t rstride = (size_t)row0 * K + cs;

    for (int k0 = 0; k0 < K; k0 += 32) {
        __syncthreads();
        const __bf16* ga = Ab + rstride + k0;
        const __bf16* gb = Bb + rstride + k0;
        __builtin_amdgcn_global_load_lds((gl_bf16*)ga,                  AsL + wave * 512,        16, 0, 0);
        __builtin_amdgcn_global_load_lds((gl_bf16*)(ga + (size_t)64*K), AsL + 2048 + wave * 512, 16, 0, 0);
        __builtin_amdgcn_global_load_lds((gl_bf16*)gb,                  BsL + wave * 512,        16, 0, 0);
        __builtin_amdgcn_global_load_lds((gl_bf16*)(gb + (size_t)64*K), BsL + 2048 + wave * 512, 16, 0, 0);
        __syncthreads();

        bf16x8 af[4], bfr[4];
        for (int m = 0; m < 4; ++m)
            af[m] = *reinterpret_cast<const bf16x8*>(&As[(wr * 64 + m * 16 + ll) * 32 + lg * 8]);
        for (int n = 0; n < 4; ++n)
            bfr[n] = *reinterpret_cast<const bf16x8*>(&Bs[(wc * 64 + n * 16 + ll) * 32 + lg * 8]);
        for (int m = 0; m < 4; ++m)
            for (int n = 0; n < 4; ++n)
                acc[m][n] = __builtin_amdgcn_mfma_f32_16x16x32_bf16(af[m], bfr[n], acc[m][n], 0, 0, 0);
    }

    for (int m = 0; m < 4; ++m)
        for (int n = 0; n < 4; ++n) {
            const int col = bn * 128 + wc * 64 + n * 16 + ll;
            for (int r = 0; r < 4; ++r) {
                const int rowg = bm * 128 + wr * 64 + m * 16 + lg * 4 + r;
                C[(size_t)rowg * N + col] = acc[m][n][r];
            }
        }
}

// ---------- QKV GEMM with fused bias + RoPE + layout epilogue ----------
// Q is additionally scaled by (1/sqrt(D)) * log2(e) so attention can use
// exp2 directly.
__global__ __launch_bounds__(256)
void gemm_qkv_rope(const __bf16* __restrict__ A, const __bf16* __restrict__ B,
                   const float* __restrict__ bias, const float* __restrict__ cosb,
                   const float* __restrict__ sinb, __bf16* __restrict__ qT,
                   __bf16* __restrict__ kT, __bf16* __restrict__ vT) {
    const int K = 2048, NBN = 20;
    __shared__ __align__(16) __bf16 As[128 * 32];
    __shared__ __align__(16) __bf16 Bs[128 * 32];
    __shared__ float Ex[32][132];   // rope partner exchange, padded stride

    const int tid  = threadIdx.x;
    const int wave = tid >> 6, lane = tid & 63, lg = lane >> 4, ll = lane & 15;
    const int wr = wave >> 1, wc = wave & 1;

    const int nwg  = gridDim.x;
    const int cpx  = nwg >> 3;
    const int orig = blockIdx.x;
    const int wg   = (orig & 7) * cpx + (orig >> 3);
    const int bm = wg / NBN, bn = wg - bm * NBN;

    const __bf16* Ab = A + (size_t)bm * 128 * K;
    const __bf16* Bb = B + (size_t)bn * 128 * K;

    lds_bf16* AsL = (lds_bf16*)As;
    lds_bf16* BsL = (lds_bf16*)Bs;

    f32x4 acc[4][4];
    for (int m = 0; m < 4; ++m)
        for (int n = 0; n < 4; ++n)
            acc[m][n] = f32x4{0.f, 0.f, 0.f, 0.f};

    const int row0 = tid >> 2;
    const int cs   = (tid & 3) * 8;
    const size_t rstride = (size_t)row0 * K + cs;

    for (int k0 = 0; k0 < K; k0 += 32) {
        __syncthreads();
        const __bf16* ga = Ab + rstride + k0;
        const __bf16* gb = Bb + rstride + k0;
        __builtin_amdgcn_global_load_lds((gl_bf16*)ga,                  AsL + wave * 512,        16, 0, 0);
        __builtin_amdgcn_global_load_lds((gl_bf16*)(ga + (size_t)64*K), AsL + 2048 + wave * 512, 16, 0, 0);
        __builtin_amdgcn_global_load_lds((gl_bf16*)gb,                  BsL + wave * 512,        16, 0, 0);
        __builtin_amdgcn_global_load_lds((gl_bf16*)(gb + (size_t)64*K), BsL + 2048 + wave * 512, 16, 0, 0);
        __syncthreads();

        bf16x8 af[4], bfr[4];
        for (int m = 0; m < 4; ++m)
            af[m] = *reinterpret_cast<const bf16x8*>(&As[(wr * 64 + m * 16 + ll) * 32 + lg * 8]);
        for (int n = 0; n < 4; ++n)
            bfr[n] = *reinterpret_cast<const bf16x8*>(&Bs[(wc * 64 + n * 16 + ll) * 32 + lg * 8]);
        for (int m = 0; m < 4; ++m)
            for (int n = 0; n < 4; ++n)
                acc[m][n] = __builtin_amdgcn_mfma_f32_16x16x32_bf16(af[m], bfr[n], acc[m][n], 0, 0, 0);
    }

    // ---- epilogue ----
    if (bn >= 18) {
        const int kvh = bn - 18;
        for (int m = 0; m < 4; ++m)
            for (int n = 0; n < 4; ++n) {
                const int d = wc * 64 + n * 16 + ll;
                const float bv = bias[bn * 128 + d];
                const int rbase = bm * 128 + wr * 64 + m * 16 + lg * 4;
                const int b = rbase >> 11, l0 = rbase & 2047;
                bf16x4 o4;
                for (int r = 0; r < 4; ++r) o4[r] = (__bf16)(acc[m][n][r] + bv);
                *reinterpret_cast<bf16x4*>(&vT[((size_t)(b * 2 + kvh) * 128 + d) * 2048 + l0]) = o4;
            }
    } else {
        // Q/K: bias + RoPE; Q gets (1/sqrt(D))*log2(e) folded in
        const float qsc = (bn < 16) ? 0.08838834764831845f * 1.4426950408889634f : 1.0f;
        for (int m = 0; m < 4; ++m) {
            __syncthreads();
            for (int n = 0; n < 4; ++n) {
                const int col = wc * 64 + n * 16 + ll;
                const float bv = bias[bn * 128 + col];
                for (int r = 0; r < 4; ++r)
                    Ex[wr * 16 + lg * 4 + r][col] = acc[m][n][r] + bv;
            }
            __syncthreads();
            for (int n = 0; n < 4; ++n) {
                const int col = wc * 64 + n * 16 + ll;
                const float sgn = (col < 64) ? -1.f : 1.f;
                for (int r = 0; r < 4; ++r) {
                    const int er = wr * 16 + lg * 4 + r;
                    const float self = Ex[er][col];
                    const float part = Ex[er][col ^ 64];
                    const int rowg = bm * 128 + wr * 64 + m * 16 + lg * 4 + r;
                    const int b = rowg >> 11, l = rowg & 2047;
                    const float c = cosb[l * 128 + col], s = sinb[l * 128 + col];
                    const float val = (self * c + sgn * part * s) * qsc;
                    if (bn < 16)
                        qT[(((size_t)(b * 16 + bn)) * 2048 + l) * 128 + col] = (__bf16)val;
                    else
                        kT[(((size_t)(b * 2 + (bn - 16))) * 2048 + l) * 128 + col] = (__bf16)val;
                }
            }
        }
    }
}

// ---------- causal GQA flash attention: swapped QK^T, lane-local softmax ----------
// S^T = mfma(K_frag, Q_frag): lane holds 16 scores of ONE q-row (col=lane&15).
// Softmax: in-lane trees + 2 shfl_xor per reduce; exp2 (log2e folded into Q).
// Everything else identical to the proven r4 structure.
__global__ __launch_bounds__(256)
void attn_kernel(const __bf16* __restrict__ qT, const __bf16* __restrict__ kT,
                 const __bf16* __restrict__ vT, __bf16* __restrict__ attnb) {
    const int bx = blockIdx.x;
    const int qb = 31 - (bx >> 5);       // heavy blocks first
    const int hb = bx & 31;
    const int h = hb >> 1, b = hb & 1;
    const int kv = h >> 3;               // G = 8
    const int tid = threadIdx.x, wave = tid >> 6, lane = tid & 63, lg = lane >> 4, ll = lane & 15;

    __shared__ __align__(16) __bf16 Kl[64 * 128];     // [key][d], chunk^=(key&7)
    __shared__ __align__(16) __bf16 Vl[128 * 64];     // [d][key], chunk^=(d&7)
    __shared__ __align__(16) __bf16 Pl[4][16 * 64];   // per-wave [qrow][key], chunk^=(row&7)

    const int q0 = qb * 64 + wave * 16;
    const __bf16* qbase = qT + ((size_t)((b * 16 + h) * 2048) + q0 + ll) * 128;
    bf16x8 qf[4];
    for (int kk = 0; kk < 4; ++kk)
        qf[kk] = *reinterpret_cast<const bf16x8*>(qbase + kk * 32 + lg * 8);

    f32x4 o[8];
    for (int nd = 0; nd < 8; ++nd) o[nd] = f32x4{0.f, 0.f, 0.f, 0.f};
    float mrow = -3e38f;     // running max (log2 units) for q-row (lane&15)
    float srow = 0.f;        // running denom for q-row (lane&15)

    const __bf16* kbase = kT + (size_t)((b * 2 + kv) * 2048) * 128;
    const __bf16* vbase = vT + (size_t)((b * 2 + kv) * 128) * 2048;
    const int ntiles = qb + 1;

    char* KlB = (char*)Kl;
    char* VlB = (char*)Vl;
    char* PlB = (char*)&Pl[wave][0];

    bf16x8 kr[4], vr[4];
    // prologue: load tile 0 and store to LDS
    {
        #pragma unroll
        for (int i = 0; i < 4; ++i) {
            const int li = i * 256 + tid;
            const int key = li >> 4, c = li & 15;
            kr[i] = *reinterpret_cast<const bf16x8*>(kbase + (size_t)key * 128 + c * 8);
            const int dd = li >> 3, cv = li & 7;
            vr[i] = *reinterpret_cast<const bf16x8*>(vbase + (size_t)dd * 2048 + cv * 8);
        }
        #pragma unroll
        for (int i = 0; i < 4; ++i) {
            const int li = i * 256 + tid;
            const int key = li >> 4, c = li & 15;
            *reinterpret_cast<bf16x8*>(KlB + key * 256 + ((c ^ (key & 7)) << 4)) = kr[i];
            const int dd = li >> 3, cv = li & 7;
            *reinterpret_cast<bf16x8*>(VlB + dd * 128 + ((cv ^ (dd & 7)) << 4)) = vr[i];
        }
        __syncthreads();
    }

    for (int t = 0; t < ntiles; ++t) {
        if (t + 1 < ntiles) {
            const int j0n = (t + 1) * 64;
            #pragma unroll
            for (int i = 0; i < 4; ++i) {
                const int li = i * 256 + tid;
                const int key = li >> 4, c = li & 15;
                kr[i] = *reinterpret_cast<const bf16x8*>(kbase + (size_t)(j0n + key) * 128 + c * 8);
                const int dd = li >> 3, cv = li & 7;
                vr[i] = *reinterpret_cast<const bf16x8*>(vbase + (size_t)dd * 2048 + j0n + cv * 8);
            }
        }

        // S^T = K Q^T : s[n][r] = S[key = t*64 + n*16 + lg*4 + r][qrow = q0 + ll]
        f32x4 s[4];
        for (int n = 0; n < 4; ++n) s[n] = f32x4{0.f, 0.f, 0.f, 0.f};
        __builtin_amdgcn_s_setprio(1);
        #pragma unroll
        for (int kk = 0; kk < 4; ++kk)
            #pragma unroll
            for (int n = 0; n < 4; ++n) {
                const int row = n * 16 + ll;
                bf16x8 kf = *reinterpret_cast<const bf16x8*>(
                    KlB + row * 256 + (((kk * 4 + lg) ^ (ll & 7)) << 4));
                s[n] = __builtin_amdgcn_mfma_f32_16x16x32_bf16(kf, qf[kk], s[n], 0, 0, 0);
            }
        __builtin_amdgcn_s_setprio(0);

        // causal mask: only the diagonal tile needs it (uniform branch)
        if (t == qb) {
            const int qloc = wave * 16 + ll;
            #pragma unroll
            for (int n = 0; n < 4; ++n)
                #pragma unroll
                for (int r = 0; r < 4; ++r)
                    if (n * 16 + lg * 4 + r > qloc) s[n][r] = -3e38f;
        }

        // lane-local online softmax (values in log2 units)
        float tmax = s[0][0];
        #pragma unroll
        for (int n = 0; n < 4; ++n)
            #pragma unroll
            for (int r = 0; r < 4; ++r) tmax = fmaxf(tmax, s[n][r]);
        tmax = fmaxf(tmax, __shfl_xor(tmax, 16));
        tmax = fmaxf(tmax, __shfl_xor(tmax, 32));
        const float mnew = fmaxf(mrow, tmax);
        const float scl = __builtin_amdgcn_exp2f(mrow - mnew);
        mrow = mnew;
        float rs = 0.f;
        #pragma unroll
        for (int n = 0; n < 4; ++n)
            #pragma unroll
            for (int r = 0; r < 4; ++r) {
                const float p = __builtin_amdgcn_exp2f(s[n][r] - mnew);
                s[n][r] = p;
                rs += p;
            }
        rs += __shfl_xor(rs, 16);
        rs += __shfl_xor(rs, 32);
        srow = srow * scl + rs;

        // rescale O: o-row = lg*4+r; its scl lives in lanes with (lane&15)==lg*4+r
        #pragma unroll
        for (int r = 0; r < 4; ++r) {
            const float sr = __shfl(scl, (lane & 48) | ((lane >> 4) << 2) | r);
            #pragma unroll
            for (int nd = 0; nd < 8; ++nd) o[nd][r] *= sr;
        }

        // P -> per-wave LDS: row = ll (qrow), cols n*16+lg*4+{0..3}, packed pairs
        #pragma unroll
        for (int n = 0; n < 4; ++n)
            #pragma unroll
            for (int rp = 0; rp < 2; ++rp) {
                const int col = n * 16 + lg * 4 + rp * 2;
                bf16x2 pk;
                pk.x = (__bf16)s[n][rp * 2];
                pk.y = (__bf16)s[n][rp * 2 + 1];
                *reinterpret_cast<bf16x2*>(
                    PlB + ll * 128 + (((col >> 3) ^ (ll & 7)) << 4) + (col & 7) * 2) = pk;
            }

        // O += P V
        __builtin_amdgcn_s_setprio(1);
        #pragma unroll
        for (int kk = 0; kk < 2; ++kk) {
            bf16x8 pf = *reinterpret_cast<const bf16x8*>(
                PlB + ll * 128 + (((kk * 4 + lg) ^ (ll & 7)) << 4));
            #pragma unroll
            for (int nd = 0; nd < 8; ++nd) {
                const int row = nd * 16 + ll;
                bf16x8 vf = *reinterpret_cast<const bf16x8*>(
                    VlB + row * 128 + (((kk * 4 + lg) ^ (ll & 7)) << 4));
                o[nd] = __builtin_amdgcn_mfma_f32_16x16x32_bf16(pf, vf, o[nd], 0, 0, 0);
            }
        }
        __builtin_amdgcn_s_setprio(0);

        __syncthreads();
        if (t + 1 < ntiles) {
            #pragma unroll
            for (int i = 0; i < 4; ++i) {
                const int li = i * 256 + tid;
                const int key = li >> 4, c = li & 15;
                *reinterpret_cast<bf16x8*>(KlB + key * 256 + ((c ^ (key & 7)) << 4)) = kr[i];
                const int dd = li >> 3, cv = li & 7;
                *reinterpret_cast<bf16x8*>(VlB + dd * 128 + ((cv ^ (dd & 7)) << 4)) = vr[i];
            }
            __syncthreads();
        }
    }

    // epilogue: normalize and store
    const float inv = __builtin_amdgcn_rcpf(srow);
    #pragma unroll
    for (int r = 0; r < 4; ++r) {
        const float invr = __shfl(inv, (lane & 48) | ((lane >> 4) << 2) | r);
        const int qrow = q0 + lg * 4 + r;
        #pragma unroll
        for (int nd = 0; nd < 8; ++nd)
            attnb[((size_t)(b * 2048) + qrow) * 2048 + h * 128 + nd * 16 + ll] = (__bf16)(o[nd][r] * invr);
    }
}

// ---------- host launch ----------
extern "C" void kernel_launch(void* const* d_in, const int* in_sizes, int n_in,
                              void* d_out, int out_size, void* d_ws, size_t ws_size,
                              hipStream_t stream) {
    const float* x    = (const float*)d_in[0];
    const float* cosb = (const float*)d_in[1];
    const float* sinb = (const float*)d_in[2];
    const float* wq   = (const float*)d_in[3];
    const float* bq   = (const float*)d_in[4];
    const float* wk   = (const float*)d_in[5];
    const float* bk   = (const float*)d_in[6];
    const float* wv   = (const float*)d_in[7];
    const float* bv   = (const float*)d_in[8];
    const float* wo   = (const float*)d_in[9];
    float* out = (float*)d_out;

    char* ws = (char*)d_ws;
    __bf16* xb    = (__bf16*)(ws);                         // 16,777,216  (later reused as attnb)
    __bf16* wb    = (__bf16*)(ws + 16777216);              // 10,485,760  (wq|wk|wv rows, 2560x2048)
    __bf16* wob   = (__bf16*)(ws + 27262976);              //  8,388,608
    float*  biasc = (float*) (ws + 35651584);              //     16,384 (2560 used)
    __bf16* qTp   = (__bf16*)(ws + 77611008);              // 16,777,216
    __bf16* kTp   = (__bf16*)(ws + 94388224);              //  2,097,152
    __bf16* vTp   = (__bf16*)(ws + 96485376);              //  2,097,152

    // 1) convert all fp32 inputs to bf16 (one launch)
    cvt_all<<<dim3(8192, 5), 256, 0, stream>>>(
        x,  xb,            8388608,
        wq, wb,            4194304,
        wk, wb + 4194304,  524288,
        wv, wb + 4718592,  524288,
        wo, wob,           4194304);
    concat_bias<<<10, 256, 0, stream>>>(bq, bk, bv, biasc);

    // 2) fused QKV GEMM + bias + RoPE + layout  [640 wg]
    gemm_qkv_rope<<<640, 256, 0, stream>>>(xb, wb, biasc, cosb, sinb, qTp, kTp, vTp);

    // 3) flash attention -> attnb (reuses xb region, bf16 (B,L,H*D))
    attn_kernel<<<1024, 256, 0, stream>>>(qTp, kTp, vTp, xb);

    // 4) output GEMM: (4096x2048) x (2048x2048)^T -> fp32 d_out  [512 wg]
    gemm_bt<<<512, 256, 0, stream>>>(xb, wob, out, 2048, 2048, 16);
}

// Round 6
// 215.015 us; speedup vs baseline: 1.5184x; 1.1042x over previous
//
#include <hip/hip_runtime.h>
#include <hip/hip_bf16.h>
#include <cstdint>

// ---------- types ----------
typedef __bf16 bf16x8 __attribute__((ext_vector_type(8)));
typedef __bf16 bf16x4 __attribute__((ext_vector_type(4)));
typedef __bf16 bf16x2 __attribute__((ext_vector_type(2)));
typedef float  f32x4  __attribute__((ext_vector_type(4)));
typedef __attribute__((address_space(3))) __bf16 lds_bf16;
typedef __attribute__((address_space(1))) const __bf16 gl_bf16;

// ---------- merged fp32 -> bf16 convert (5 segments, one launch) ----------
__global__ void cvt_all(const float* __restrict__ s0, __bf16* __restrict__ d0, int n0,
                        const float* __restrict__ s1, __bf16* __restrict__ d1, int n1,
                        const float* __restrict__ s2, __bf16* __restrict__ d2, int n2,
                        const float* __restrict__ s3, __bf16* __restrict__ d3, int n3,
                        const float* __restrict__ s4, __bf16* __restrict__ d4, int n4) {
    const float* s; __bf16* d; int n;
    switch (blockIdx.y) {
        case 0: s = s0; d = d0; n = n0; break;
        case 1: s = s1; d = d1; n = n1; break;
        case 2: s = s2; d = d2; n = n2; break;
        case 3: s = s3; d = d3; n = n3; break;
        default: s = s4; d = d4; n = n4; break;
    }
    int i = (blockIdx.x * blockDim.x + threadIdx.x) * 4;
    if (i + 3 < n) {
        float4 v = *reinterpret_cast<const float4*>(s + i);
        bf16x4 o;
        o.x = (__bf16)v.x; o.y = (__bf16)v.y; o.z = (__bf16)v.z; o.w = (__bf16)v.w;
        *reinterpret_cast<bf16x4*>(d + i) = o;
    }
}

// ---------- concat bq|bk|bv into one 2560-float buffer ----------
__global__ void concat_bias(const float* __restrict__ bq, const float* __restrict__ bk,
                            const float* __restrict__ bv, float* __restrict__ dst) {
    int t = blockIdx.x * blockDim.x + threadIdx.x;
    if (t < 2048)      dst[t] = bq[t];
    else if (t < 2304) dst[t] = bk[t - 2048];
    else if (t < 2560) dst[t] = bv[t - 2304];
}

// ---------- out-proj GEMM (unchanged r5): 128x128 tile, m97 structure ----------
__global__ __launch_bounds__(256)
void gemm_bt(const __bf16* __restrict__ A, const __bf16* __restrict__ B,
             float* __restrict__ C, int N, int K, int NBN) {
    __shared__ __align__(16) __bf16 As[128 * 32];
    __shared__ __align__(16) __bf16 Bs[128 * 32];
    const int tid  = threadIdx.x;
    const int wave = tid >> 6, lane = tid & 63, lg = lane >> 4, ll = lane & 15;
    const int wr = wave >> 1, wc = wave & 1;

    const int nwg  = gridDim.x;
    const int cpx  = nwg >> 3;
    const int orig = blockIdx.x;
    const int wg   = (orig & 7) * cpx + (orig >> 3);
    const int bm = wg / NBN, bn = wg - bm * NBN;

    const __bf16* Ab = A + (size_t)bm * 128 * K;
    const __bf16* Bb = B + (size_t)bn * 128 * K;

    lds_bf16* AsL = (lds_bf16*)As;
    lds_bf16* BsL = (lds_bf16*)Bs;

    f32x4 acc[4][4];
    for (int m = 0; m < 4; ++m)
        for (int n = 0; n < 4; ++n)
            acc[m][n] = f32x4{0.f, 0.f, 0.f, 0.f};

    const int row0 = tid >> 2;
    const int cs   = (tid & 3) * 8;
    const size_t rstride = (size_t)row0 * K + cs;

    for (int k0 = 0; k0 < K; k0 += 32) {
        __syncthreads();
        const __bf16* ga = Ab + rstride + k0;
        const __bf16* gb = Bb + rstride + k0;
        __builtin_amdgcn_global_load_lds((gl_bf16*)ga,                  AsL + wave * 512,        16, 0, 0);
        __builtin_amdgcn_global_load_lds((gl_bf16*)(ga + (size_t)64*K), AsL + 2048 + wave * 512, 16, 0, 0);
        __builtin_amdgcn_global_load_lds((gl_bf16*)gb,                  BsL + wave * 512,        16, 0, 0);
        __builtin_amdgcn_global_load_lds((gl_bf16*)(gb + (size_t)64*K), BsL + 2048 + wave * 512, 16, 0, 0);
        __syncthreads();

        bf16x8 af[4], bfr[4];
        for (int m = 0; m < 4; ++m)
            af[m] = *reinterpret_cast<const bf16x8*>(&As[(wr * 64 + m * 16 + ll) * 32 + lg * 8]);
        for (int n = 0; n < 4; ++n)
            bfr[n] = *reinterpret_cast<const bf16x8*>(&Bs[(wc * 64 + n * 16 + ll) * 32 + lg * 8]);
        for (int m = 0; m < 4; ++m)
            for (int n = 0; n < 4; ++n)
                acc[m][n] = __builtin_amdgcn_mfma_f32_16x16x32_bf16(af[m], bfr[n], acc[m][n], 0, 0, 0);
    }

    for (int m = 0; m < 4; ++m)
        for (int n = 0; n < 4; ++n) {
            const int col = bn * 128 + wc * 64 + n * 16 + ll;
            for (int r = 0; r < 4; ++r) {
                const int rowg = bm * 128 + wr * 64 + m * 16 + lg * 4 + r;
                C[(size_t)rowg * N + col] = acc[m][n][r];
            }
        }
}

// ---------- stage one 128x64 half-tile: 2 global_load_lds per thread ----------
// LDS layout linear [row][chunk] with content pre-swizzled: slot (row, c) holds
// global chunk (c ^ (row & 7)).  row = (j*512+tid)>>3, row&7 == (tid>>3)&7.
__device__ __forceinline__ void stage_half(const __bf16* __restrict__ gbase, int K, int k0,
                                           lds_bf16* lbase, int tid) {
    const int cc = (tid & 7) ^ ((tid >> 3) & 7);
    const __bf16* s0 = gbase + (size_t)(tid >> 3) * K + k0 + cc * 8;
    __builtin_amdgcn_global_load_lds((gl_bf16*)s0, lbase + (tid >> 6) * 512, 16, 0, 0);
    const __bf16* s1 = gbase + (size_t)(64 + (tid >> 3)) * K + k0 + cc * 8;
    __builtin_amdgcn_global_load_lds((gl_bf16*)s1, lbase + 4096 + (tid >> 6) * 512, 16, 0, 0);
}

// ---------- QKV GEMM 256x256, 8 waves, deep pipeline, fused bias+RoPE ----------
// A (4096x2048), B rows wq|wk|wv (2560x2048). Tile grid 16x10 = 160 wg.
// Double-buffered 128 KB LDS, counted vmcnt(8) (next tile's 8 loads in flight
// across the barrier), chunk-XOR swizzle, raw s_barrier (2/tile), setprio MFMA.
// bn 0-7: Q (2 heads/tile, rope+scale), bn 8: K (rope), bn 9: V (transpose).
__global__ __launch_bounds__(512, 2)
void gemm_qkv_rope(const __bf16* __restrict__ A, const __bf16* __restrict__ B,
                   const float* __restrict__ bias, const float* __restrict__ cosb,
                   const float* __restrict__ sinb, __bf16* __restrict__ qT,
                   __bf16* __restrict__ kT, __bf16* __restrict__ vT) {
    const int K = 2048, NBN = 10, NT = 32;   // 32 K-tiles of BK=64
    __shared__ __align__(16) char smem[131072];   // As: [0,64K) Bs: [64K,128K)

    const int tid  = threadIdx.x;
    const int wave = tid >> 6, lane = tid & 63, lg = lane >> 4, ll = lane & 15;
    const int wr = wave >> 2, wc = wave & 3;       // 2 x 4 wave grid

    const int nwg  = gridDim.x;                    // 160, %8 == 0
    const int cpx  = nwg >> 3;
    const int orig = blockIdx.x;
    const int wg   = (orig & 7) * cpx + (orig >> 3);
    const int bm = wg / NBN, bn = wg - bm * NBN;

    const __bf16* Atile = A + (size_t)(bm * 256) * K;
    const __bf16* Btile = B + (size_t)(bn * 256) * K;

    lds_bf16* AsL = (lds_bf16*)smem;               // [buf][half][8192] elems
    lds_bf16* BsL = (lds_bf16*)(smem + 65536);

    f32x4 acc[8][4];
    #pragma unroll
    for (int m = 0; m < 8; ++m)
        #pragma unroll
        for (int n = 0; n < 4; ++n)
            acc[m][n] = f32x4{0.f, 0.f, 0.f, 0.f};

    // prologue: stage tile 0 into buf 0 (order B0,A0,A1,B1)
    stage_half(Btile,                 K, 0, BsL,        tid);
    stage_half(Atile,                 K, 0, AsL,        tid);
    stage_half(Atile + (size_t)128*K, K, 0, AsL + 8192, tid);
    stage_half(Btile + (size_t)128*K, K, 0, BsL + 8192, tid);

    const char* smB = (const char*)smem;
    for (int t = 0; t < NT; ++t) {
        const int c  = t & 1;
        const int tn = (t + 1 < NT) ? t + 1 : NT - 1;   // clamp keeps vmcnt counts uniform
        const int bfn = (t + 1) & 1;
        const int k0n = tn * 64;
        // issue next tile's 8 loads (into the other buffer)
        stage_half(Btile,                 K, k0n, BsL + bfn * 16384,        tid);
        stage_half(Atile,                 K, k0n, AsL + bfn * 16384,        tid);
        stage_half(Atile + (size_t)128*K, K, k0n, AsL + bfn * 16384 + 8192, tid);
        stage_half(Btile + (size_t)128*K, K, k0n, BsL + bfn * 16384 + 8192, tid);
        // counted wait: drain THIS tile's 8 loads, keep next tile's 8 in flight
        asm volatile("s_waitcnt vmcnt(8)" ::: "memory");
        __builtin_amdgcn_s_barrier();
        asm volatile("" ::: "memory");

        const char* AbB = smB + c * 32768 + wr * 16384;
        const char* BbB = smB + 65536 + c * 32768 + (wc >> 1) * 16384;
        __builtin_amdgcn_s_setprio(1);
        #pragma unroll
        for (int kk = 0; kk < 2; ++kk) {
            bf16x8 bfr[4];
            #pragma unroll
            for (int n = 0; n < 4; ++n) {
                const int row = (wc & 1) * 64 + n * 16 + ll;
                bfr[n] = *reinterpret_cast<const bf16x8*>(
                    BbB + row * 128 + (((kk * 4 + lg) ^ (ll & 7)) << 4));
            }
            #pragma unroll
            for (int m = 0; m < 8; ++m) {
                const int row = m * 16 + ll;
                bf16x8 af = *reinterpret_cast<const bf16x8*>(
                    AbB + row * 128 + (((kk * 4 + lg) ^ (ll & 7)) << 4));
                #pragma unroll
                for (int n = 0; n < 4; ++n)
                    acc[m][n] = __builtin_amdgcn_mfma_f32_16x16x32_bf16(af, bfr[n], acc[m][n], 0, 0, 0);
            }
        }
        __builtin_amdgcn_s_setprio(0);
        asm volatile("" ::: "memory");
        __builtin_amdgcn_s_barrier();   // protect buf c from next iteration's stage
        asm volatile("" ::: "memory");
    }

    // drain stray prefetch before reusing LDS
    asm volatile("s_waitcnt vmcnt(0)" ::: "memory");
    __syncthreads();

    // ---- epilogue ----
    if (bn == 9) {
        // V: bias only, transposed store (b, kv, d, l), 4 l per 8B chunk
        #pragma unroll
        for (int m = 0; m < 8; ++m)
            #pragma unroll
            for (int n = 0; n < 4; ++n) {
                const int col = wc * 64 + n * 16 + ll;       // 0..255
                const int kvh = col >> 7, d = col & 127;
                const float bv = bias[2304 + col];
                const int rbase = bm * 256 + wr * 128 + m * 16 + lg * 4;
                const int b = rbase >> 11, l0 = rbase & 2047;
                bf16x4 o4;
                #pragma unroll
                for (int r = 0; r < 4; ++r) o4[r] = (__bf16)(acc[m][n][r] + bv);
                *reinterpret_cast<bf16x4*>(&vT[((size_t)(b * 2 + kvh) * 128 + d) * 2048 + l0]) = o4;
            }
    } else {
        // Q (bn<8) / K (bn==8): bias + RoPE via LDS exchange (partner col^64)
        const bool isQ = (bn < 8);
        const float qsc = isQ ? 0.08838834764831845f * 1.4426950408889634f : 1.0f;
        float* Ex = (float*)smem;    // [32][260] fp32, overlays dead A buffers
        float bvr[4];
        #pragma unroll
        for (int n = 0; n < 4; ++n) bvr[n] = bias[bn * 256 + wc * 64 + n * 16 + ll];
        for (int m = 0; m < 8; ++m) {
            #pragma unroll
            for (int n = 0; n < 4; ++n) {
                const int col = wc * 64 + n * 16 + ll;
                #pragma unroll
                for (int r = 0; r < 4; ++r)
                    Ex[(wr * 16 + lg * 4 + r) * 260 + col] = acc[m][n][r] + bvr[n];
            }
            __syncthreads();
            #pragma unroll
            for (int n = 0; n < 4; ++n) {
                const int col = wc * 64 + n * 16 + ll;
                const int d = col & 127;
                const float sgn = (d < 64) ? -1.f : 1.f;
                #pragma unroll
                for (int r = 0; r < 4; ++r) {
                    const int er = wr * 16 + lg * 4 + r;
                    const float self = Ex[er * 260 + col];
                    const float part = Ex[er * 260 + (col ^ 64)];
                    const int rowg = bm * 256 + wr * 128 + m * 16 + lg * 4 + r;
                    const int b = rowg >> 11, l = rowg & 2047;
                    const float cc = cosb[l * 128 + d], ss = sinb[l * 128 + d];
                    const float val = (self * cc + sgn * part * ss) * qsc;
                    if (isQ) {
                        const int h = bn * 2 + (col >> 7);
                        qT[(((size_t)(b * 16 + h)) * 2048 + l) * 128 + d] = (__bf16)val;
                    } else {
                        const int kvh = col >> 7;
                        kT[(((size_t)(b * 2 + kvh)) * 2048 + l) * 128 + d] = (__bf16)val;
                    }
                }
            }
            __syncthreads();
        }
    }
}

// ---------- causal GQA flash attention (unchanged r5) ----------
__global__ __launch_bounds__(256)
void attn_kernel(const __bf16* __restrict__ qT, const __bf16* __restrict__ kT,
                 const __bf16* __restrict__ vT, __bf16* __restrict__ attnb) {
    const int bx = blockIdx.x;
    const int qb = 31 - (bx >> 5);       // heavy blocks first
    const int hb = bx & 31;
    const int h = hb >> 1, b = hb & 1;
    const int kv = h >> 3;               // G = 8
    const int tid = threadIdx.x, wave = tid >> 6, lane = tid & 63, lg = lane >> 4, ll = lane & 15;

    __shared__ __align__(16) __bf16 Kl[64 * 128];
    __shared__ __align__(16) __bf16 Vl[128 * 64];
    __shared__ __align__(16) __bf16 Pl[4][16 * 64];

    const int q0 = qb * 64 + wave * 16;
    const __bf16* qbase = qT + ((size_t)((b * 16 + h) * 2048) + q0 + ll) * 128;
    bf16x8 qf[4];
    for (int kk = 0; kk < 4; ++kk)
        qf[kk] = *reinterpret_cast<const bf16x8*>(qbase + kk * 32 + lg * 8);

    f32x4 o[8];
    for (int nd = 0; nd < 8; ++nd) o[nd] = f32x4{0.f, 0.f, 0.f, 0.f};
    float mrow = -3e38f;
    float srow = 0.f;

    const __bf16* kbase = kT + (size_t)((b * 2 + kv) * 2048) * 128;
    const __bf16* vbase = vT + (size_t)((b * 2 + kv) * 128) * 2048;
    const int ntiles = qb + 1;

    char* KlB = (char*)Kl;
    char* VlB = (char*)Vl;
    char* PlB = (char*)&Pl[wave][0];

    bf16x8 kr[4], vr[4];
    {
        #pragma unroll
        for (int i = 0; i < 4; ++i) {
            const int li = i * 256 + tid;
            const int key = li >> 4, c = li & 15;
            kr[i] = *reinterpret_cast<const bf16x8*>(kbase + (size_t)key * 128 + c * 8);
            const int dd = li >> 3, cv = li & 7;
            vr[i] = *reinterpret_cast<const bf16x8*>(vbase + (size_t)dd * 2048 + cv * 8);
        }
        #pragma unroll
        for (int i = 0; i < 4; ++i) {
            const int li = i * 256 + tid;
            const int key = li >> 4, c = li & 15;
            *reinterpret_cast<bf16x8*>(KlB + key * 256 + ((c ^ (key & 7)) << 4)) = kr[i];
            const int dd = li >> 3, cv = li & 7;
            *reinterpret_cast<bf16x8*>(VlB + dd * 128 + ((cv ^ (dd & 7)) << 4)) = vr[i];
        }
        __syncthreads();
    }

    for (int t = 0; t < ntiles; ++t) {
        if (t + 1 < ntiles) {
            const int j0n = (t + 1) * 64;
            #pragma unroll
            for (int i = 0; i < 4; ++i) {
                const int li = i * 256 + tid;
                const int key = li >> 4, c = li & 15;
                kr[i] = *reinterpret_cast<const bf16x8*>(kbase + (size_t)(j0n + key) * 128 + c * 8);
                const int dd = li >> 3, cv = li & 7;
                vr[i] = *reinterpret_cast<const bf16x8*>(vbase + (size_t)dd * 2048 + j0n + cv * 8);
            }
        }

        f32x4 s[4];
        for (int n = 0; n < 4; ++n) s[n] = f32x4{0.f, 0.f, 0.f, 0.f};
        __builtin_amdgcn_s_setprio(1);
        #pragma unroll
        for (int kk = 0; kk < 4; ++kk)
            #pragma unroll
            for (int n = 0; n < 4; ++n) {
                const int row = n * 16 + ll;
                bf16x8 kf = *reinterpret_cast<const bf16x8*>(
                    KlB + row * 256 + (((kk * 4 + lg) ^ (ll & 7)) << 4));
                s[n] = __builtin_amdgcn_mfma_f32_16x16x32_bf16(kf, qf[kk], s[n], 0, 0, 0);
            }
        __builtin_amdgcn_s_setprio(0);

        if (t == qb) {
            const int qloc = wave * 16 + ll;
            #pragma unroll
            for (int n = 0; n < 4; ++n)
                #pragma unroll
                for (int r = 0; r < 4; ++r)
                    if (n * 16 + lg * 4 + r > qloc) s[n][r] = -3e38f;
        }

        float tmax = s[0][0];
        #pragma unroll
        for (int n = 0; n < 4; ++n)
            #pragma unroll
            for (int r = 0; r < 4; ++r) tmax = fmaxf(tmax, s[n][r]);
        tmax = fmaxf(tmax, __shfl_xor(tmax, 16));
        tmax = fmaxf(tmax, __shfl_xor(tmax, 32));
        const float mnew = fmaxf(mrow, tmax);
        const float scl = __builtin_amdgcn_exp2f(mrow - mnew);
        mrow = mnew;
        float rs = 0.f;
        #pragma unroll
        for (int n = 0; n < 4; ++n)
            #pragma unroll
            for (int r = 0; r < 4; ++r) {
                const float p = __builtin_amdgcn_exp2f(s[n][r] - mnew);
                s[n][r] = p;
                rs += p;
            }
        rs += __shfl_xor(rs, 16);
        rs += __shfl_xor(rs, 32);
        srow = srow * scl + rs;

        #pragma unroll
        for (int r = 0; r < 4; ++r) {
            const float sr = __shfl(scl, (lane & 48) | ((lane >> 4) << 2) | r);
            #pragma unroll
            for (int nd = 0; nd < 8; ++nd) o[nd][r] *= sr;
        }

        #pragma unroll
        for (int n = 0; n < 4; ++n)
            #pragma unroll
            for (int rp = 0; rp < 2; ++rp) {
                const int col = n * 16 + lg * 4 + rp * 2;
                bf16x2 pk;
                pk.x = (__bf16)s[n][rp * 2];
                pk.y = (__bf16)s[n][rp * 2 + 1];
                *reinterpret_cast<bf16x2*>(
                    PlB + ll * 128 + (((col >> 3) ^ (ll & 7)) << 4) + (col & 7) * 2) = pk;
            }

        __builtin_amdgcn_s_setprio(1);
        #pragma unroll
        for (int kk = 0; kk < 2; ++kk) {
            bf16x8 pf = *reinterpret_cast<const bf16x8*>(
                PlB + ll * 128 + (((kk * 4 + lg) ^ (ll & 7)) << 4));
            #pragma unroll
            for (int nd = 0; nd < 8; ++nd) {
                const int row = nd * 16 + ll;
                bf16x8 vf = *reinterpret_cast<const bf16x8*>(
                    VlB + row * 128 + (((kk * 4 + lg) ^ (ll & 7)) << 4));
                o[nd] = __builtin_amdgcn_mfma_f32_16x16x32_bf16(pf, vf, o[nd], 0, 0, 0);
            }
        }
        __builtin_amdgcn_s_setprio(0);

        __syncthreads();
        if (t + 1 < ntiles) {
            #pragma unroll
            for (int i = 0; i < 4; ++i) {
                const int li = i * 256 + tid;
                const int key = li >> 4, c = li & 15;
                *reinterpret_cast<bf16x8*>(KlB + key * 256 + ((c ^ (key & 7)) << 4)) = kr[i];
                const int dd = li >> 3, cv = li & 7;
                *reinterpret_cast<bf16x8*>(VlB + dd * 128 + ((cv ^ (dd & 7)) << 4)) = vr[i];
            }
            __syncthreads();
        }
    }

    const float inv = __builtin_amdgcn_rcpf(srow);
    #pragma unroll
    for (int r = 0; r < 4; ++r) {
        const float invr = __shfl(inv, (lane & 48) | ((lane >> 4) << 2) | r);
        const int qrow = q0 + lg * 4 + r;
        #pragma unroll
        for (int nd = 0; nd < 8; ++nd)
            attnb[((size_t)(b * 2048) + qrow) * 2048 + h * 128 + nd * 16 + ll] = (__bf16)(o[nd][r] * invr);
    }
}

// ---------- host launch ----------
extern "C" void kernel_launch(void* const* d_in, const int* in_sizes, int n_in,
                              void* d_out, int out_size, void* d_ws, size_t ws_size,
                              hipStream_t stream) {
    const float* x    = (const float*)d_in[0];
    const float* cosb = (const float*)d_in[1];
    const float* sinb = (const float*)d_in[2];
    const float* wq   = (const float*)d_in[3];
    const float* bq   = (const float*)d_in[4];
    const float* wk   = (const float*)d_in[5];
    const float* bk   = (const float*)d_in[6];
    const float* wv   = (const float*)d_in[7];
    const float* bv   = (const float*)d_in[8];
    const float* wo   = (const float*)d_in[9];
    float* out = (float*)d_out;

    char* ws = (char*)d_ws;
    __bf16* xb    = (__bf16*)(ws);                         // 16,777,216  (later reused as attnb)
    __bf16* wb    = (__bf16*)(ws + 16777216);              // 10,485,760  (wq|wk|wv rows, 2560x2048)
    __bf16* wob   = (__bf16*)(ws + 27262976);              //  8,388,608
    float*  biasc = (float*) (ws + 35651584);              //     16,384 (2560 used)
    __bf16* qTp   = (__bf16*)(ws + 77611008);              // 16,777,216
    __bf16* kTp   = (__bf16*)(ws + 94388224);              //  2,097,152
    __bf16* vTp   = (__bf16*)(ws + 96485376);              //  2,097,152

    // 1) convert all fp32 inputs to bf16 (one launch)
    cvt_all<<<dim3(8192, 5), 256, 0, stream>>>(
        x,  xb,            8388608,
        wq, wb,            4194304,
        wk, wb + 4194304,  524288,
        wv, wb + 4718592,  524288,
        wo, wob,           4194304);
    concat_bias<<<10, 256, 0, stream>>>(bq, bk, bv, biasc);

    // 2) fused QKV GEMM + bias + RoPE + layout  [160 wg, 512 thr, 128 KB LDS]
    gemm_qkv_rope<<<160, 512, 0, stream>>>(xb, wb, biasc, cosb, sinb, qTp, kTp, vTp);

    // 3) flash attention -> attnb (reuses xb region, bf16 (B,L,H*D))
    attn_kernel<<<1024, 256, 0, stream>>>(qTp, kTp, vTp, xb);

    // 4) output GEMM: (4096x2048) x (2048x2048)^T -> fp32 d_out  [512 wg]
    gemm_bt<<<512, 256, 0, stream>>>(xb, wob, out, 2048, 2048, 16);
}

// Round 8
// 208.186 us; speedup vs baseline: 1.5682x; 1.0328x over previous
//
#include <hip/hip_runtime.h>
#include <hip/hip_bf16.h>
#include <cstdint>

// ---------- types ----------
typedef __bf16 bf16x8 __attribute__((ext_vector_type(8)));
typedef __bf16 bf16x4 __attribute__((ext_vector_type(4)));
typedef __bf16 bf16x2 __attribute__((ext_vector_type(2)));
typedef float  f32x4  __attribute__((ext_vector_type(4)));
typedef __attribute__((address_space(3))) __bf16 lds_bf16;
typedef __attribute__((address_space(1))) const __bf16 gl_bf16;

// ---------- merged fp32 -> bf16 convert (5 segments, one launch) ----------
__global__ void cvt_all(const float* __restrict__ s0, __bf16* __restrict__ d0, int n0,
                        const float* __restrict__ s1, __bf16* __restrict__ d1, int n1,
                        const float* __restrict__ s2, __bf16* __restrict__ d2, int n2,
                        const float* __restrict__ s3, __bf16* __restrict__ d3, int n3,
                        const float* __restrict__ s4, __bf16* __restrict__ d4, int n4) {
    const float* s; __bf16* d; int n;
    switch (blockIdx.y) {
        case 0: s = s0; d = d0; n = n0; break;
        case 1: s = s1; d = d1; n = n1; break;
        case 2: s = s2; d = d2; n = n2; break;
        case 3: s = s3; d = d3; n = n3; break;
        default: s = s4; d = d4; n = n4; break;
    }
    int i = (blockIdx.x * blockDim.x + threadIdx.x) * 4;
    if (i + 3 < n) {
        float4 v = *reinterpret_cast<const float4*>(s + i);
        bf16x4 o;
        o.x = (__bf16)v.x; o.y = (__bf16)v.y; o.z = (__bf16)v.z; o.w = (__bf16)v.w;
        *reinterpret_cast<bf16x4*>(d + i) = o;
    }
}

// ---------- concat bq|bk|bv into one 2560-float buffer ----------
__global__ void concat_bias(const float* __restrict__ bq, const float* __restrict__ bk,
                            const float* __restrict__ bv, float* __restrict__ dst) {
    int t = blockIdx.x * blockDim.x + threadIdx.x;
    if (t < 2048)      dst[t] = bq[t];
    else if (t < 2304) dst[t] = bk[t - 2048];
    else if (t < 2560) dst[t] = bv[t - 2304];
}

// ---------- out-proj GEMM (unchanged): 128x128 tile, m97 structure ----------
__global__ __launch_bounds__(256)
void gemm_bt(const __bf16* __restrict__ A, const __bf16* __restrict__ B,
             float* __restrict__ C, int N, int K, int NBN) {
    __shared__ __align__(16) __bf16 As[128 * 32];
    __shared__ __align__(16) __bf16 Bs[128 * 32];
    const int tid  = threadIdx.x;
    const int wave = tid >> 6, lane = tid & 63, lg = lane >> 4, ll = lane & 15;
    const int wr = wave >> 1, wc = wave & 1;

    const int nwg  = gridDim.x;
    const int cpx  = nwg >> 3;
    const int orig = blockIdx.x;
    const int wg   = (orig & 7) * cpx + (orig >> 3);
    const int bm = wg / NBN, bn = wg - bm * NBN;

    const __bf16* Ab = A + (size_t)bm * 128 * K;
    const __bf16* Bb = B + (size_t)bn * 128 * K;

    lds_bf16* AsL = (lds_bf16*)As;
    lds_bf16* BsL = (lds_bf16*)Bs;

    f32x4 acc[4][4];
    for (int m = 0; m < 4; ++m)
        for (int n = 0; n < 4; ++n)
            acc[m][n] = f32x4{0.f, 0.f, 0.f, 0.f};

    const int row0 = tid >> 2;
    const int cs   = (tid & 3) * 8;
    const size_t rstride = (size_t)row0 * K + cs;

    for (int k0 = 0; k0 < K; k0 += 32) {
        __syncthreads();
        const __bf16* ga = Ab + rstride + k0;
        const __bf16* gb = Bb + rstride + k0;
        __builtin_amdgcn_global_load_lds((gl_bf16*)ga,                  AsL + wave * 512,        16, 0, 0);
        __builtin_amdgcn_global_load_lds((gl_bf16*)(ga + (size_t)64*K), AsL + 2048 + wave * 512, 16, 0, 0);
        __builtin_amdgcn_global_load_lds((gl_bf16*)gb,                  BsL + wave * 512,        16, 0, 0);
        __builtin_amdgcn_global_load_lds((gl_bf16*)(gb + (size_t)64*K), BsL + 2048 + wave * 512, 16, 0, 0);
        __syncthreads();

        bf16x8 af[4], bfr[4];
        for (int m = 0; m < 4; ++m)
            af[m] = *reinterpret_cast<const bf16x8*>(&As[(wr * 64 + m * 16 + ll) * 32 + lg * 8]);
        for (int n = 0; n < 4; ++n)
            bfr[n] = *reinterpret_cast<const bf16x8*>(&Bs[(wc * 64 + n * 16 + ll) * 32 + lg * 8]);
        for (int m = 0; m < 4; ++m)
            for (int n = 0; n < 4; ++n)
                acc[m][n] = __builtin_amdgcn_mfma_f32_16x16x32_bf16(af[m], bfr[n], acc[m][n], 0, 0, 0);
    }

    for (int m = 0; m < 4; ++m)
        for (int n = 0; n < 4; ++n) {
            const int col = bn * 128 + wc * 64 + n * 16 + ll;
            for (int r = 0; r < 4; ++r) {
                const int rowg = bm * 128 + wr * 64 + m * 16 + lg * 4 + r;
                C[(size_t)rowg * N + col] = acc[m][n][r];
            }
        }
}

// ---------- stage one 128x64 half-tile (QKV GEMM) ----------
__device__ __forceinline__ void stage_half(const __bf16* __restrict__ gbase, int K, int k0,
                                           lds_bf16* lbase, int tid) {
    const int cc = (tid & 7) ^ ((tid >> 3) & 7);
    const __bf16* s0 = gbase + (size_t)(tid >> 3) * K + k0 + cc * 8;
    __builtin_amdgcn_global_load_lds((gl_bf16*)s0, lbase + (tid >> 6) * 512, 16, 0, 0);
    const __bf16* s1 = gbase + (size_t)(64 + (tid >> 3)) * K + k0 + cc * 8;
    __builtin_amdgcn_global_load_lds((gl_bf16*)s1, lbase + 4096 + (tid >> 6) * 512, 16, 0, 0);
}

// ---------- QKV GEMM 256x256, 8 waves, deep pipeline, fused bias+RoPE (unchanged) ----------
__global__ __launch_bounds__(512, 2)
void gemm_qkv_rope(const __bf16* __restrict__ A, const __bf16* __restrict__ B,
                   const float* __restrict__ bias, const float* __restrict__ cosb,
                   const float* __restrict__ sinb, __bf16* __restrict__ qT,
                   __bf16* __restrict__ kT, __bf16* __restrict__ vT) {
    const int K = 2048, NBN = 10, NT = 32;
    __shared__ __align__(16) char smem[131072];

    const int tid  = threadIdx.x;
    const int wave = tid >> 6, lane = tid & 63, lg = lane >> 4, ll = lane & 15;
    const int wr = wave >> 2, wc = wave & 3;

    const int nwg  = gridDim.x;
    const int cpx  = nwg >> 3;
    const int orig = blockIdx.x;
    const int wg   = (orig & 7) * cpx + (orig >> 3);
    const int bm = wg / NBN, bn = wg - bm * NBN;

    const __bf16* Atile = A + (size_t)(bm * 256) * K;
    const __bf16* Btile = B + (size_t)(bn * 256) * K;

    lds_bf16* AsL = (lds_bf16*)smem;
    lds_bf16* BsL = (lds_bf16*)(smem + 65536);

    f32x4 acc[8][4];
    #pragma unroll
    for (int m = 0; m < 8; ++m)
        #pragma unroll
        for (int n = 0; n < 4; ++n)
            acc[m][n] = f32x4{0.f, 0.f, 0.f, 0.f};

    stage_half(Btile,                 K, 0, BsL,        tid);
    stage_half(Atile,                 K, 0, AsL,        tid);
    stage_half(Atile + (size_t)128*K, K, 0, AsL + 8192, tid);
    stage_half(Btile + (size_t)128*K, K, 0, BsL + 8192, tid);

    const char* smB = (const char*)smem;
    for (int t = 0; t < NT; ++t) {
        const int c  = t & 1;
        const int tn = (t + 1 < NT) ? t + 1 : NT - 1;
        const int bfn = (t + 1) & 1;
        const int k0n = tn * 64;
        stage_half(Btile,                 K, k0n, BsL + bfn * 16384,        tid);
        stage_half(Atile,                 K, k0n, AsL + bfn * 16384,        tid);
        stage_half(Atile + (size_t)128*K, K, k0n, AsL + bfn * 16384 + 8192, tid);
        stage_half(Btile + (size_t)128*K, K, k0n, BsL + bfn * 16384 + 8192, tid);
        asm volatile("s_waitcnt vmcnt(8)" ::: "memory");
        __builtin_amdgcn_s_barrier();
        asm volatile("" ::: "memory");

        const char* AbB = smB + c * 32768 + wr * 16384;
        const char* BbB = smB + 65536 + c * 32768 + (wc >> 1) * 16384;
        __builtin_amdgcn_s_setprio(1);
        #pragma unroll
        for (int kk = 0; kk < 2; ++kk) {
            bf16x8 bfr[4];
            #pragma unroll
            for (int n = 0; n < 4; ++n) {
                const int row = (wc & 1) * 64 + n * 16 + ll;
                bfr[n] = *reinterpret_cast<const bf16x8*>(
                    BbB + row * 128 + (((kk * 4 + lg) ^ (ll & 7)) << 4));
            }
            #pragma unroll
            for (int m = 0; m < 8; ++m) {
                const int row = m * 16 + ll;
                bf16x8 af = *reinterpret_cast<const bf16x8*>(
                    AbB + row * 128 + (((kk * 4 + lg) ^ (ll & 7)) << 4));
                #pragma unroll
                for (int n = 0; n < 4; ++n)
                    acc[m][n] = __builtin_amdgcn_mfma_f32_16x16x32_bf16(af, bfr[n], acc[m][n], 0, 0, 0);
            }
        }
        __builtin_amdgcn_s_setprio(0);
        asm volatile("" ::: "memory");
        __builtin_amdgcn_s_barrier();
        asm volatile("" ::: "memory");
    }

    asm volatile("s_waitcnt vmcnt(0)" ::: "memory");
    __syncthreads();

    if (bn == 9) {
        #pragma unroll
        for (int m = 0; m < 8; ++m)
            #pragma unroll
            for (int n = 0; n < 4; ++n) {
                const int col = wc * 64 + n * 16 + ll;
                const int kvh = col >> 7, d = col & 127;
                const float bv = bias[2304 + col];
                const int rbase = bm * 256 + wr * 128 + m * 16 + lg * 4;
                const int b = rbase >> 11, l0 = rbase & 2047;
                bf16x4 o4;
                #pragma unroll
                for (int r = 0; r < 4; ++r) o4[r] = (__bf16)(acc[m][n][r] + bv);
                *reinterpret_cast<bf16x4*>(&vT[((size_t)(b * 2 + kvh) * 128 + d) * 2048 + l0]) = o4;
            }
    } else {
        const bool isQ = (bn < 8);
        const float qsc = isQ ? 0.08838834764831845f * 1.4426950408889634f : 1.0f;
        float* Ex = (float*)smem;
        float bvr[4];
        #pragma unroll
        for (int n = 0; n < 4; ++n) bvr[n] = bias[bn * 256 + wc * 64 + n * 16 + ll];
        for (int m = 0; m < 8; ++m) {
            #pragma unroll
            for (int n = 0; n < 4; ++n) {
                const int col = wc * 64 + n * 16 + ll;
                #pragma unroll
                for (int r = 0; r < 4; ++r)
                    Ex[(wr * 16 + lg * 4 + r) * 260 + col] = acc[m][n][r] + bvr[n];
            }
            __syncthreads();
            #pragma unroll
            for (int n = 0; n < 4; ++n) {
                const int col = wc * 64 + n * 16 + ll;
                const int d = col & 127;
                const float sgn = (d < 64) ? -1.f : 1.f;
                #pragma unroll
                for (int r = 0; r < 4; ++r) {
                    const int er = wr * 16 + lg * 4 + r;
                    const float self = Ex[er * 260 + col];
                    const float part = Ex[er * 260 + (col ^ 64)];
                    const int rowg = bm * 256 + wr * 128 + m * 16 + lg * 4 + r;
                    const int b = rowg >> 11, l = rowg & 2047;
                    const float cc = cosb[l * 128 + d], ss = sinb[l * 128 + d];
                    const float val = (self * cc + sgn * part * ss) * qsc;
                    if (isQ) {
                        const int h = bn * 2 + (col >> 7);
                        qT[(((size_t)(b * 16 + h)) * 2048 + l) * 128 + d] = (__bf16)val;
                    } else {
                        const int kvh = col >> 7;
                        kT[(((size_t)(b * 2 + kvh)) * 2048 + l) * 128 + d] = (__bf16)val;
                    }
                }
            }
            __syncthreads();
        }
    }
}

// ---------- attn: one Q-group step (QK^T swapped, lane-local softmax, swapped PV) ----------
// qloc = wave*16 + ll : this wave's q-row within the 64-row q-block (mask fix).
__device__ __forceinline__ void attn_step(const char* KlB, const char* VlB, char* PlB,
                                          const bf16x8* qf, f32x4* o, float& mrow, float& srow,
                                          bool diag, int lg, int ll, int qloc) {
    f32x4 s[4];
    #pragma unroll
    for (int n = 0; n < 4; ++n) s[n] = f32x4{0.f, 0.f, 0.f, 0.f};
    __builtin_amdgcn_s_setprio(1);
    #pragma unroll
    for (int kk = 0; kk < 4; ++kk)
        #pragma unroll
        for (int n = 0; n < 4; ++n) {
            const int row = n * 16 + ll;
            bf16x8 kf = *reinterpret_cast<const bf16x8*>(
                KlB + row * 256 + (((kk * 4 + lg) ^ (ll & 7)) << 4));
            s[n] = __builtin_amdgcn_mfma_f32_16x16x32_bf16(kf, qf[kk], s[n], 0, 0, 0);
        }
    __builtin_amdgcn_s_setprio(0);

    if (diag) {
        #pragma unroll
        for (int n = 0; n < 4; ++n)
            #pragma unroll
            for (int r = 0; r < 4; ++r)
                if (n * 16 + lg * 4 + r > qloc) s[n][r] = -3e38f;
    }

    float tmax = s[0][0];
    #pragma unroll
    for (int n = 0; n < 4; ++n)
        #pragma unroll
        for (int r = 0; r < 4; ++r) tmax = fmaxf(tmax, s[n][r]);
    tmax = fmaxf(tmax, __shfl_xor(tmax, 16));
    tmax = fmaxf(tmax, __shfl_xor(tmax, 32));
    const float mnew = fmaxf(mrow, tmax);
    const float scl = __builtin_amdgcn_exp2f(mrow - mnew);
    mrow = mnew;
    float rs = 0.f;
    #pragma unroll
    for (int n = 0; n < 4; ++n)
        #pragma unroll
        for (int r = 0; r < 4; ++r) {
            const float p = __builtin_amdgcn_exp2f(s[n][r] - mnew);
            s[n][r] = p;
            rs += p;
        }
    rs += __shfl_xor(rs, 16);
    rs += __shfl_xor(rs, 32);
    srow = srow * scl + rs;

    // rescale O (O^T layout: q = ll is lane-local)
    #pragma unroll
    for (int nd = 0; nd < 8; ++nd)
        #pragma unroll
        for (int r = 0; r < 4; ++r) o[nd][r] *= scl;

    // P -> per-wave LDS: row = ll (q), cols n*16+lg*4+{0..3}, packed pairs
    #pragma unroll
    for (int n = 0; n < 4; ++n)
        #pragma unroll
        for (int rp = 0; rp < 2; ++rp) {
            const int col = n * 16 + lg * 4 + rp * 2;
            bf16x2 pk;
            pk.x = (__bf16)s[n][rp * 2];
            pk.y = (__bf16)s[n][rp * 2 + 1];
            *reinterpret_cast<bf16x2*>(
                PlB + ll * 128 + (((col >> 3) ^ (ll & 7)) << 4) + (col & 7) * 2) = pk;
        }

    // O^T += V^T P^T  (swapped operands: same LDS reads, accumulator q=ll)
    __builtin_amdgcn_s_setprio(1);
    #pragma unroll
    for (int kk = 0; kk < 2; ++kk) {
        bf16x8 pf = *reinterpret_cast<const bf16x8*>(
            PlB + ll * 128 + (((kk * 4 + lg) ^ (ll & 7)) << 4));
        #pragma unroll
        for (int nd = 0; nd < 8; ++nd) {
            const int row = nd * 16 + ll;
            bf16x8 vf = *reinterpret_cast<const bf16x8*>(
                VlB + row * 128 + (((kk * 4 + lg) ^ (ll & 7)) << 4));
            o[nd] = __builtin_amdgcn_mfma_f32_16x16x32_bf16(vf, pf, o[nd], 0, 0, 0);
        }
    }
    __builtin_amdgcn_s_setprio(0);
}

// ---------- causal GQA flash attention: paired Q-tiles, gl_lds staging ----------
// grid 512 = 16 (qp) x 32 (hb). Block handles q-blocks lo=qp and hi=31-qp:
// lo's key range is a prefix of hi's -> shared K/V staging; per-block MFMA
// work = 33 tile-units, exactly uniform. Double-buffered K/V via
// global_load_lds (pre-swizzled source, linear dest), counted vmcnt(8).
__global__ __launch_bounds__(256)
void attn_kernel(const __bf16* __restrict__ qT, const __bf16* __restrict__ kT,
                 const __bf16* __restrict__ vT, __bf16* __restrict__ attnb) {
    const int bx = blockIdx.x;
    const int qp = bx >> 5;
    const int hb = bx & 31;
    const int h = hb >> 1, b = hb & 1;
    const int kv = h >> 3;
    const int lo = qp, hi = 31 - qp;
    const int tid = threadIdx.x, wave = tid >> 6, lane = tid & 63, lg = lane >> 4, ll = lane & 15;
    const int qloc = wave * 16 + ll;   // q-row within the 64-row q-block

    __shared__ __align__(16) char smem[73728];   // 2 x (K 16K + V 16K) + P 8K
    lds_bf16* ldsE = (lds_bf16*)smem;

    const __bf16* kbase = kT + (size_t)((b * 2 + kv) * 2048) * 128;
    const __bf16* vbase = vT + (size_t)((b * 2 + kv) * 128) * 2048;

    bf16x8 qfL[4], qfH[4];
    {
        const __bf16* q0 = qT + ((size_t)((b * 16 + h) * 2048) + lo * 64 + wave * 16 + ll) * 128;
        const __bf16* q1 = qT + ((size_t)((b * 16 + h) * 2048) + hi * 64 + wave * 16 + ll) * 128;
        #pragma unroll
        for (int kk = 0; kk < 4; ++kk) {
            qfL[kk] = *reinterpret_cast<const bf16x8*>(q0 + kk * 32 + lg * 8);
            qfH[kk] = *reinterpret_cast<const bf16x8*>(q1 + kk * 32 + lg * 8);
        }
    }

    f32x4 oL[8], oH[8];
    #pragma unroll
    for (int nd = 0; nd < 8; ++nd) { oL[nd] = f32x4{0.f,0.f,0.f,0.f}; oH[nd] = f32x4{0.f,0.f,0.f,0.f}; }
    float mL = -3e38f, sL = 0.f, mH = -3e38f, sH = 0.f;

    const int ntiles = hi + 1;

    // stage tile j0/64 into buffer buf: linear LDS dest + inverse-swizzled source
    #define STAGE_KV(j0, buf)                                                              \
        do {                                                                               \
            lds_bf16* kl = ldsE + (buf) * 16384;                                           \
            lds_bf16* vl = ldsE + (buf) * 16384 + 8192;                                    \
            _Pragma("unroll")                                                              \
            for (int i = 0; i < 4; ++i) {                                                  \
                const int li = i * 256 + tid;                                              \
                const int key = li >> 4, c = li & 15;                                      \
                const __bf16* src = kbase + (size_t)((j0) + key) * 128 + ((c ^ (key & 7)) * 8); \
                __builtin_amdgcn_global_load_lds((gl_bf16*)src, kl + i * 2048 + wave * 512, 16, 0, 0); \
            }                                                                              \
            _Pragma("unroll")                                                              \
            for (int i = 0; i < 4; ++i) {                                                  \
                const int li = i * 256 + tid;                                              \
                const int dd = li >> 3, cv = li & 7;                                       \
                const __bf16* src = vbase + (size_t)dd * 2048 + (j0) + ((cv ^ (dd & 7)) * 8); \
                __builtin_amdgcn_global_load_lds((gl_bf16*)src, vl + i * 2048 + wave * 512, 16, 0, 0); \
            }                                                                              \
        } while (0)

    STAGE_KV(0, 0);
    char* PlB = smem + 65536 + wave * 2048;

    for (int t = 0; t < ntiles; ++t) {
        const int tn = (t + 1 < ntiles) ? t + 1 : t;   // clamp keeps vmcnt uniform
        STAGE_KV(tn * 64, (t + 1) & 1);
        asm volatile("s_waitcnt vmcnt(8)" ::: "memory");
        __builtin_amdgcn_s_barrier();
        asm volatile("" ::: "memory");

        const char* KlB = smem + (t & 1) * 32768;
        const char* VlB = smem + (t & 1) * 32768 + 16384;

        // HI group (always active)
        attn_step(KlB, VlB, PlB, qfH, oH, mH, sH, t == hi, lg, ll, qloc);
        // LO group (prefix of HI's key range)
        if (t <= lo)
            attn_step(KlB, VlB, PlB, qfL, oL, mL, sL, t == lo, lg, ll, qloc);

        asm volatile("" ::: "memory");
        __builtin_amdgcn_s_barrier();
        asm volatile("" ::: "memory");
    }

    // epilogue: O^T layout -> lane owns q, 4 consecutive d per store
    const float invH = __builtin_amdgcn_rcpf(sH);
    const float invL = __builtin_amdgcn_rcpf(sL);
    const int qHrow = hi * 64 + wave * 16 + ll;
    const int qLrow = lo * 64 + wave * 16 + ll;
    #pragma unroll
    for (int nd = 0; nd < 8; ++nd) {
        bf16x4 aH, aL;
        #pragma unroll
        for (int r = 0; r < 4; ++r) {
            aH[r] = (__bf16)(oH[nd][r] * invH);
            aL[r] = (__bf16)(oL[nd][r] * invL);
        }
        const size_t cb = h * 128 + nd * 16 + lg * 4;
        *reinterpret_cast<bf16x4*>(&attnb[((size_t)(b * 2048) + qHrow) * 2048 + cb]) = aH;
        *reinterpret_cast<bf16x4*>(&attnb[((size_t)(b * 2048) + qLrow) * 2048 + cb]) = aL;
    }
    #undef STAGE_KV
}

// ---------- host launch ----------
extern "C" void kernel_launch(void* const* d_in, const int* in_sizes, int n_in,
                              void* d_out, int out_size, void* d_ws, size_t ws_size,
                              hipStream_t stream) {
    const float* x    = (const float*)d_in[0];
    const float* cosb = (const float*)d_in[1];
    const float* sinb = (const float*)d_in[2];
    const float* wq   = (const float*)d_in[3];
    const float* bq   = (const float*)d_in[4];
    const float* wk   = (const float*)d_in[5];
    const float* bk   = (const float*)d_in[6];
    const float* wv   = (const float*)d_in[7];
    const float* bv   = (const float*)d_in[8];
    const float* wo   = (const float*)d_in[9];
    float* out = (float*)d_out;

    char* ws = (char*)d_ws;
    __bf16* xb    = (__bf16*)(ws);                         // 16,777,216  (later reused as attnb)
    __bf16* wb    = (__bf16*)(ws + 16777216);              // 10,485,760  (wq|wk|wv rows, 2560x2048)
    __bf16* wob   = (__bf16*)(ws + 27262976);              //  8,388,608
    float*  biasc = (float*) (ws + 35651584);              //     16,384 (2560 used)
    __bf16* qTp   = (__bf16*)(ws + 77611008);              // 16,777,216
    __bf16* kTp   = (__bf16*)(ws + 94388224);              //  2,097,152
    __bf16* vTp   = (__bf16*)(ws + 96485376);              //  2,097,152

    // 1) convert all fp32 inputs to bf16 (one launch)
    cvt_all<<<dim3(8192, 5), 256, 0, stream>>>(
        x,  xb,            8388608,
        wq, wb,            4194304,
        wk, wb + 4194304,  524288,
        wv, wb + 4718592,  524288,
        wo, wob,           4194304);
    concat_bias<<<10, 256, 0, stream>>>(bq, bk, bv, biasc);

    // 2) fused QKV GEMM + bias + RoPE + layout  [160 wg, 512 thr, 128 KB LDS]
    gemm_qkv_rope<<<160, 512, 0, stream>>>(xb, wb, biasc, cosb, sinb, qTp, kTp, vTp);

    // 3) flash attention -> attnb (reuses xb region, bf16 (B,L,H*D))
    attn_kernel<<<512, 256, 0, stream>>>(qTp, kTp, vTp, xb);

    // 4) output GEMM: (4096x2048) x (2048x2048)^T -> fp32 d_out  [512 wg]
    gemm_bt<<<512, 256, 0, stream>>>(xb, wob, out, 2048, 2048, 16);
}

// Round 9
// 199.890 us; speedup vs baseline: 1.6333x; 1.0415x over previous
//
#include <hip/hip_runtime.h>
#include <hip/hip_bf16.h>
#include <cstdint>

// ---------- types ----------
typedef __bf16 bf16x8 __attribute__((ext_vector_type(8)));
typedef __bf16 bf16x4 __attribute__((ext_vector_type(4)));
typedef __bf16 bf16x2 __attribute__((ext_vector_type(2)));
typedef float  f32x4  __attribute__((ext_vector_type(4)));
typedef __attribute__((address_space(3))) __bf16 lds_bf16;
typedef __attribute__((address_space(1))) const __bf16 gl_bf16;

// ---------- merged fp32 -> bf16 convert (exact-sized 1-D grid) ----------
// segments: 8192 | 4096 | 512 | 512 | 4096 blocks, 1024 elems/block
__global__ void cvt_all(const float* __restrict__ s0, __bf16* __restrict__ d0,
                        const float* __restrict__ s1, __bf16* __restrict__ d1,
                        const float* __restrict__ s2, __bf16* __restrict__ d2,
                        const float* __restrict__ s3, __bf16* __restrict__ d3,
                        const float* __restrict__ s4, __bf16* __restrict__ d4) {
    const int blk = blockIdx.x;
    const float* s; __bf16* d; int base;
    if (blk < 8192)       { s = s0; d = d0; base = blk; }
    else if (blk < 12288) { s = s1; d = d1; base = blk - 8192; }
    else if (blk < 12800) { s = s2; d = d2; base = blk - 12288; }
    else if (blk < 13312) { s = s3; d = d3; base = blk - 12800; }
    else                  { s = s4; d = d4; base = blk - 13312; }
    const int i = (base * 256 + threadIdx.x) * 4;
    float4 v = *reinterpret_cast<const float4*>(s + i);
    bf16x4 o;
    o.x = (__bf16)v.x; o.y = (__bf16)v.y; o.z = (__bf16)v.z; o.w = (__bf16)v.w;
    *reinterpret_cast<bf16x4*>(d + i) = o;
}

// ---------- concat bq|bk|bv into one 2560-float buffer ----------
__global__ void concat_bias(const float* __restrict__ bq, const float* __restrict__ bk,
                            const float* __restrict__ bv, float* __restrict__ dst) {
    int t = blockIdx.x * blockDim.x + threadIdx.x;
    if (t < 2048)      dst[t] = bq[t];
    else if (t < 2304) dst[t] = bk[t - 2048];
    else if (t < 2560) dst[t] = bv[t - 2304];
}

// ---------- out-proj GEMM (unchanged): 128x128 tile, m97 structure ----------
__global__ __launch_bounds__(256)
void gemm_bt(const __bf16* __restrict__ A, const __bf16* __restrict__ B,
             float* __restrict__ C, int N, int K, int NBN) {
    __shared__ __align__(16) __bf16 As[128 * 32];
    __shared__ __align__(16) __bf16 Bs[128 * 32];
    const int tid  = threadIdx.x;
    const int wave = tid >> 6, lane = tid & 63, lg = lane >> 4, ll = lane & 15;
    const int wr = wave >> 1, wc = wave & 1;

    const int nwg  = gridDim.x;
    const int cpx  = nwg >> 3;
    const int orig = blockIdx.x;
    const int wg   = (orig & 7) * cpx + (orig >> 3);
    const int bm = wg / NBN, bn = wg - bm * NBN;

    const __bf16* Ab = A + (size_t)bm * 128 * K;
    const __bf16* Bb = B + (size_t)bn * 128 * K;

    lds_bf16* AsL = (lds_bf16*)As;
    lds_bf16* BsL = (lds_bf16*)Bs;

    f32x4 acc[4][4];
    for (int m = 0; m < 4; ++m)
        for (int n = 0; n < 4; ++n)
            acc[m][n] = f32x4{0.f, 0.f, 0.f, 0.f};

    const int row0 = tid >> 2;
    const int cs   = (tid & 3) * 8;
    const size_t rstride = (size_t)row0 * K + cs;

    for (int k0 = 0; k0 < K; k0 += 32) {
        __syncthreads();
        const __bf16* ga = Ab + rstride + k0;
        const __bf16* gb = Bb + rstride + k0;
        __builtin_amdgcn_global_load_lds((gl_bf16*)ga,                  AsL + wave * 512,        16, 0, 0);
        __builtin_amdgcn_global_load_lds((gl_bf16*)(ga + (size_t)64*K), AsL + 2048 + wave * 512, 16, 0, 0);
        __builtin_amdgcn_global_load_lds((gl_bf16*)gb,                  BsL + wave * 512,        16, 0, 0);
        __builtin_amdgcn_global_load_lds((gl_bf16*)(gb + (size_t)64*K), BsL + 2048 + wave * 512, 16, 0, 0);
        __syncthreads();

        bf16x8 af[4], bfr[4];
        for (int m = 0; m < 4; ++m)
            af[m] = *reinterpret_cast<const bf16x8*>(&As[(wr * 64 + m * 16 + ll) * 32 + lg * 8]);
        for (int n = 0; n < 4; ++n)
            bfr[n] = *reinterpret_cast<const bf16x8*>(&Bs[(wc * 64 + n * 16 + ll) * 32 + lg * 8]);
        for (int m = 0; m < 4; ++m)
            for (int n = 0; n < 4; ++n)
                acc[m][n] = __builtin_amdgcn_mfma_f32_16x16x32_bf16(af[m], bfr[n], acc[m][n], 0, 0, 0);
    }

    for (int m = 0; m < 4; ++m)
        for (int n = 0; n < 4; ++n) {
            const int col = bn * 128 + wc * 64 + n * 16 + ll;
            for (int r = 0; r < 4; ++r) {
                const int rowg = bm * 128 + wr * 64 + m * 16 + lg * 4 + r;
                C[(size_t)rowg * N + col] = acc[m][n][r];
            }
        }
}

// ---------- stage one 128x64 half-tile: 2 global_load_lds per thread ----------
// LDS linear [row][chunk] with pre-swizzled content: slot (row,c) holds global
// chunk (c ^ (row&7)).
__device__ __forceinline__ void stage_half(const __bf16* __restrict__ gbase, int K, int k0,
                                           lds_bf16* lbase, int tid) {
    const int cc = (tid & 7) ^ ((tid >> 3) & 7);
    const __bf16* s0 = gbase + (size_t)(tid >> 3) * K + k0 + cc * 8;
    __builtin_amdgcn_global_load_lds((gl_bf16*)s0, lbase + (tid >> 6) * 512, 16, 0, 0);
    const __bf16* s1 = gbase + (size_t)(64 + (tid >> 3)) * K + k0 + cc * 8;
    __builtin_amdgcn_global_load_lds((gl_bf16*)s1, lbase + 4096 + (tid >> 6) * 512, 16, 0, 0);
}

// ---------- QKV GEMM 256x256, 8 waves, 4-phase interleaved K-loop ----------
// Per K-tile (BK=64): 4 quadrant phases x 16 MFMA. Stage issues distributed
// (A-lo+B-lo at p0, B-hi+A-hi at p1 -> >=3 phases slack); one counted
// vmcnt(4) per K-tile at p0 (retires exactly the previous tile's 8 loads,
// FIFO-safe), then barrier for cross-wave visibility. Phase-end s_barriers
// give the wave role-split that makes setprio pay (T3->T5).
__global__ __launch_bounds__(512, 2)
void gemm_qkv_rope(const __bf16* __restrict__ A, const __bf16* __restrict__ B,
                   const float* __restrict__ bias, const float* __restrict__ cosb,
                   const float* __restrict__ sinb, __bf16* __restrict__ qT,
                   __bf16* __restrict__ kT, __bf16* __restrict__ vT) {
    const int K = 2048, NBN = 10, NT = 32;
    __shared__ __align__(16) char smem[131072];   // A: [0,64K)  B: [64K,128K)

    const int tid  = threadIdx.x;
    const int wave = tid >> 6, lane = tid & 63, lg = lane >> 4, ll = lane & 15;
    const int wr = wave >> 2, wc = wave & 3;       // 2 x 4 wave grid

    const int nwg  = gridDim.x;                    // 160, %8 == 0
    const int cpx  = nwg >> 3;
    const int orig = blockIdx.x;
    const int wg   = (orig & 7) * cpx + (orig >> 3);
    const int bm = wg / NBN, bn = wg - bm * NBN;

    const __bf16* Atile = A + (size_t)(bm * 256) * K;
    const __bf16* Btile = B + (size_t)(bn * 256) * K;

    lds_bf16* AsL = (lds_bf16*)smem;               // [buf][half][8192] elems
    lds_bf16* BsL = (lds_bf16*)(smem + 65536);

    f32x4 acc[8][4];
    #pragma unroll
    for (int m = 0; m < 8; ++m)
        #pragma unroll
        for (int n = 0; n < 4; ++n)
            acc[m][n] = f32x4{0.f, 0.f, 0.f, 0.f};

    // prologue: tile 0 into buf 0, halves in consume-order A-lo,B-lo,B-hi,A-hi
    stage_half(Atile,                 K, 0, AsL,        tid);
    stage_half(Btile,                 K, 0, BsL,        tid);
    stage_half(Btile + (size_t)128*K, K, 0, BsL + 8192, tid);
    stage_half(Atile + (size_t)128*K, K, 0, AsL + 8192, tid);

    const char* smB = (const char*)smem;
    const int browb = (wc & 1) * 64;   // wave's B row base within its half

    for (int t = 0; t < NT; ++t) {
        const int c   = t & 1;
        const int bfn = c ^ 1;
        const int k0n = ((t + 1 < NT) ? t + 1 : t) * 64;   // clamp keeps counts uniform
        const char* AbB = smB + c * 32768 + wr * 16384;
        const char* BbB = smB + 65536 + c * 32768 + (wc >> 1) * 16384;
        bf16x8 af[4][2], bfq[2][2];

        // ---- phase 0: stage A-lo,B-lo(T+1); vmcnt(4); bar; quad (m0-3, n0-1)
        stage_half(Atile, K, k0n, AsL + bfn * 16384, tid);
        stage_half(Btile, K, k0n, BsL + bfn * 16384, tid);
        asm volatile("s_waitcnt vmcnt(4)" ::: "memory");
        __builtin_amdgcn_s_barrier();
        asm volatile("" ::: "memory");
        #pragma unroll
        for (int kk = 0; kk < 2; ++kk) {
            #pragma unroll
            for (int nn = 0; nn < 2; ++nn)
                bfq[nn][kk] = *reinterpret_cast<const bf16x8*>(
                    BbB + (browb + nn * 16 + ll) * 128 + (((kk * 4 + lg) ^ (ll & 7)) << 4));
            #pragma unroll
            for (int mm = 0; mm < 4; ++mm)
                af[mm][kk] = *reinterpret_cast<const bf16x8*>(
                    AbB + (mm * 16 + ll) * 128 + (((kk * 4 + lg) ^ (ll & 7)) << 4));
        }
        __builtin_amdgcn_s_setprio(1);
        #pragma unroll
        for (int kk = 0; kk < 2; ++kk)
            #pragma unroll
            for (int mm = 0; mm < 4; ++mm)
                #pragma unroll
                for (int nn = 0; nn < 2; ++nn)
                    acc[mm][nn] = __builtin_amdgcn_mfma_f32_16x16x32_bf16(af[mm][kk], bfq[nn][kk], acc[mm][nn], 0, 0, 0);
        __builtin_amdgcn_s_setprio(0);
        asm volatile("" ::: "memory");
        __builtin_amdgcn_s_barrier();
        asm volatile("" ::: "memory");

        // ---- phase 1: stage B-hi,A-hi(T+1); quad (m0-3, n2-3)
        stage_half(Btile + (size_t)128*K, K, k0n, BsL + bfn * 16384 + 8192, tid);
        stage_half(Atile + (size_t)128*K, K, k0n, AsL + bfn * 16384 + 8192, tid);
        #pragma unroll
        for (int kk = 0; kk < 2; ++kk)
            #pragma unroll
            for (int nn = 0; nn < 2; ++nn)
                bfq[nn][kk] = *reinterpret_cast<const bf16x8*>(
                    BbB + (browb + (2 + nn) * 16 + ll) * 128 + (((kk * 4 + lg) ^ (ll & 7)) << 4));
        __builtin_amdgcn_s_setprio(1);
        #pragma unroll
        for (int kk = 0; kk < 2; ++kk)
            #pragma unroll
            for (int mm = 0; mm < 4; ++mm)
                #pragma unroll
                for (int nn = 0; nn < 2; ++nn)
                    acc[mm][2 + nn] = __builtin_amdgcn_mfma_f32_16x16x32_bf16(af[mm][kk], bfq[nn][kk], acc[mm][2 + nn], 0, 0, 0);
        __builtin_amdgcn_s_setprio(0);
        asm volatile("" ::: "memory");
        __builtin_amdgcn_s_barrier();
        asm volatile("" ::: "memory");

        // ---- phase 2: quad (m4-7, n2-3)
        #pragma unroll
        for (int kk = 0; kk < 2; ++kk)
            #pragma unroll
            for (int mm = 0; mm < 4; ++mm)
                af[mm][kk] = *reinterpret_cast<const bf16x8*>(
                    AbB + ((4 + mm) * 16 + ll) * 128 + (((kk * 4 + lg) ^ (ll & 7)) << 4));
        __builtin_amdgcn_s_setprio(1);
        #pragma unroll
        for (int kk = 0; kk < 2; ++kk)
            #pragma unroll
            for (int mm = 0; mm < 4; ++mm)
                #pragma unroll
                for (int nn = 0; nn < 2; ++nn)
                    acc[4 + mm][2 + nn] = __builtin_amdgcn_mfma_f32_16x16x32_bf16(af[mm][kk], bfq[nn][kk], acc[4 + mm][2 + nn], 0, 0, 0);
        __builtin_amdgcn_s_setprio(0);
        asm volatile("" ::: "memory");
        __builtin_amdgcn_s_barrier();
        asm volatile("" ::: "memory");

        // ---- phase 3: re-read B-sub0; quad (m4-7, n0-1); end-of-iter barrier
        #pragma unroll
        for (int kk = 0; kk < 2; ++kk)
            #pragma unroll
            for (int nn = 0; nn < 2; ++nn)
                bfq[nn][kk] = *reinterpret_cast<const bf16x8*>(
                    BbB + (browb + nn * 16 + ll) * 128 + (((kk * 4 + lg) ^ (ll & 7)) << 4));
        __builtin_amdgcn_s_setprio(1);
        #pragma unroll
        for (int kk = 0; kk < 2; ++kk)
            #pragma unroll
            for (int mm = 0; mm < 4; ++mm)
                #pragma unroll
                for (int nn = 0; nn < 2; ++nn)
                    acc[4 + mm][nn] = __builtin_amdgcn_mfma_f32_16x16x32_bf16(af[mm][kk], bfq[nn][kk], acc[4 + mm][nn], 0, 0, 0);
        __builtin_amdgcn_s_setprio(0);
        asm volatile("" ::: "memory");
        __builtin_amdgcn_s_barrier();   // all reads of buf c done before next iter stages it
        asm volatile("" ::: "memory");
    }

    asm volatile("s_waitcnt vmcnt(0)" ::: "memory");
    __syncthreads();

    // ---- epilogue (unchanged from r8) ----
    if (bn == 9) {
        #pragma unroll
        for (int m = 0; m < 8; ++m)
            #pragma unroll
            for (int n = 0; n < 4; ++n) {
                const int col = wc * 64 + n * 16 + ll;
                const int kvh = col >> 7, d = col & 127;
                const float bv = bias[2304 + col];
                const int rbase = bm * 256 + wr * 128 + m * 16 + lg * 4;
                const int b = rbase >> 11, l0 = rbase & 2047;
                bf16x4 o4;
                #pragma unroll
                for (int r = 0; r < 4; ++r) o4[r] = (__bf16)(acc[m][n][r] + bv);
                *reinterpret_cast<bf16x4*>(&vT[((size_t)(b * 2 + kvh) * 128 + d) * 2048 + l0]) = o4;
            }
    } else {
        const bool isQ = (bn < 8);
        const float qsc = isQ ? 0.08838834764831845f * 1.4426950408889634f : 1.0f;
        float* Ex = (float*)smem;
        float bvr[4];
        #pragma unroll
        for (int n = 0; n < 4; ++n) bvr[n] = bias[bn * 256 + wc * 64 + n * 16 + ll];
        for (int m = 0; m < 8; ++m) {
            #pragma unroll
            for (int n = 0; n < 4; ++n) {
                const int col = wc * 64 + n * 16 + ll;
                #pragma unroll
                for (int r = 0; r < 4; ++r)
                    Ex[(wr * 16 + lg * 4 + r) * 260 + col] = acc[m][n][r] + bvr[n];
            }
            __syncthreads();
            #pragma unroll
            for (int n = 0; n < 4; ++n) {
                const int col = wc * 64 + n * 16 + ll;
                const int d = col & 127;
                const float sgn = (d < 64) ? -1.f : 1.f;
                #pragma unroll
                for (int r = 0; r < 4; ++r) {
                    const int er = wr * 16 + lg * 4 + r;
                    const float self = Ex[er * 260 + col];
                    const float part = Ex[er * 260 + (col ^ 64)];
                    const int rowg = bm * 256 + wr * 128 + m * 16 + lg * 4 + r;
                    const int b = rowg >> 11, l = rowg & 2047;
                    const float cc = cosb[l * 128 + d], ss = sinb[l * 128 + d];
                    const float val = (self * cc + sgn * part * ss) * qsc;
                    if (isQ) {
                        const int h = bn * 2 + (col >> 7);
                        qT[(((size_t)(b * 16 + h)) * 2048 + l) * 128 + d] = (__bf16)val;
                    } else {
                        const int kvh = col >> 7;
                        kT[(((size_t)(b * 2 + kvh)) * 2048 + l) * 128 + d] = (__bf16)val;
                    }
                }
            }
            __syncthreads();
        }
    }
}

// ---------- attn: one Q-group step (unchanged from r8) ----------
__device__ __forceinline__ void attn_step(const char* KlB, const char* VlB, char* PlB,
                                          const bf16x8* qf, f32x4* o, float& mrow, float& srow,
                                          bool diag, int lg, int ll, int qloc) {
    f32x4 s[4];
    #pragma unroll
    for (int n = 0; n < 4; ++n) s[n] = f32x4{0.f, 0.f, 0.f, 0.f};
    __builtin_amdgcn_s_setprio(1);
    #pragma unroll
    for (int kk = 0; kk < 4; ++kk)
        #pragma unroll
        for (int n = 0; n < 4; ++n) {
            const int row = n * 16 + ll;
            bf16x8 kf = *reinterpret_cast<const bf16x8*>(
                KlB + row * 256 + (((kk * 4 + lg) ^ (ll & 7)) << 4));
            s[n] = __builtin_amdgcn_mfma_f32_16x16x32_bf16(kf, qf[kk], s[n], 0, 0, 0);
        }
    __builtin_amdgcn_s_setprio(0);

    if (diag) {
        #pragma unroll
        for (int n = 0; n < 4; ++n)
            #pragma unroll
            for (int r = 0; r < 4; ++r)
                if (n * 16 + lg * 4 + r > qloc) s[n][r] = -3e38f;
    }

    float tmax = s[0][0];
    #pragma unroll
    for (int n = 0; n < 4; ++n)
        #pragma unroll
        for (int r = 0; r < 4; ++r) tmax = fmaxf(tmax, s[n][r]);
    tmax = fmaxf(tmax, __shfl_xor(tmax, 16));
    tmax = fmaxf(tmax, __shfl_xor(tmax, 32));
    const float mnew = fmaxf(mrow, tmax);
    const float scl = __builtin_amdgcn_exp2f(mrow - mnew);
    mrow = mnew;
    float rs = 0.f;
    #pragma unroll
    for (int n = 0; n < 4; ++n)
        #pragma unroll
        for (int r = 0; r < 4; ++r) {
            const float p = __builtin_amdgcn_exp2f(s[n][r] - mnew);
            s[n][r] = p;
            rs += p;
        }
    rs += __shfl_xor(rs, 16);
    rs += __shfl_xor(rs, 32);
    srow = srow * scl + rs;

    #pragma unroll
    for (int nd = 0; nd < 8; ++nd)
        #pragma unroll
        for (int r = 0; r < 4; ++r) o[nd][r] *= scl;

    #pragma unroll
    for (int n = 0; n < 4; ++n)
        #pragma unroll
        for (int rp = 0; rp < 2; ++rp) {
            const int col = n * 16 + lg * 4 + rp * 2;
            bf16x2 pk;
            pk.x = (__bf16)s[n][rp * 2];
            pk.y = (__bf16)s[n][rp * 2 + 1];
            *reinterpret_cast<bf16x2*>(
                PlB + ll * 128 + (((col >> 3) ^ (ll & 7)) << 4) + (col & 7) * 2) = pk;
        }

    __builtin_amdgcn_s_setprio(1);
    #pragma unroll
    for (int kk = 0; kk < 2; ++kk) {
        bf16x8 pf = *reinterpret_cast<const bf16x8*>(
            PlB + ll * 128 + (((kk * 4 + lg) ^ (ll & 7)) << 4));
        #pragma unroll
        for (int nd = 0; nd < 8; ++nd) {
            const int row = nd * 16 + ll;
            bf16x8 vf = *reinterpret_cast<const bf16x8*>(
                VlB + row * 128 + (((kk * 4 + lg) ^ (ll & 7)) << 4));
            o[nd] = __builtin_amdgcn_mfma_f32_16x16x32_bf16(vf, pf, o[nd], 0, 0, 0);
        }
    }
    __builtin_amdgcn_s_setprio(0);
}

// ---------- causal GQA flash attention (unchanged from r8) ----------
__global__ __launch_bounds__(256)
void attn_kernel(const __bf16* __restrict__ qT, const __bf16* __restrict__ kT,
                 const __bf16* __restrict__ vT, __bf16* __restrict__ attnb) {
    const int bx = blockIdx.x;
    const int qp = bx >> 5;
    const int hb = bx & 31;
    const int h = hb >> 1, b = hb & 1;
    const int kv = h >> 3;
    const int lo = qp, hi = 31 - qp;
    const int tid = threadIdx.x, wave = tid >> 6, lane = tid & 63, lg = lane >> 4, ll = lane & 15;
    const int qloc = wave * 16 + ll;

    __shared__ __align__(16) char smem[73728];
    lds_bf16* ldsE = (lds_bf16*)smem;

    const __bf16* kbase = kT + (size_t)((b * 2 + kv) * 2048) * 128;
    const __bf16* vbase = vT + (size_t)((b * 2 + kv) * 128) * 2048;

    bf16x8 qfL[4], qfH[4];
    {
        const __bf16* q0 = qT + ((size_t)((b * 16 + h) * 2048) + lo * 64 + wave * 16 + ll) * 128;
        const __bf16* q1 = qT + ((size_t)((b * 16 + h) * 2048) + hi * 64 + wave * 16 + ll) * 128;
        #pragma unroll
        for (int kk = 0; kk < 4; ++kk) {
            qfL[kk] = *reinterpret_cast<const bf16x8*>(q0 + kk * 32 + lg * 8);
            qfH[kk] = *reinterpret_cast<const bf16x8*>(q1 + kk * 32 + lg * 8);
        }
    }

    f32x4 oL[8], oH[8];
    #pragma unroll
    for (int nd = 0; nd < 8; ++nd) { oL[nd] = f32x4{0.f,0.f,0.f,0.f}; oH[nd] = f32x4{0.f,0.f,0.f,0.f}; }
    float mL = -3e38f, sL = 0.f, mH = -3e38f, sH = 0.f;

    const int ntiles = hi + 1;

    #define STAGE_KV(j0, buf)                                                              \
        do {                                                                               \
            lds_bf16* kl = ldsE + (buf) * 16384;                                           \
            lds_bf16* vl = ldsE + (buf) * 16384 + 8192;                                    \
            _Pragma("unroll")                                                              \
            for (int i = 0; i < 4; ++i) {                                                  \
                const int li = i * 256 + tid;                                              \
                const int key = li >> 4, c = li & 15;                                      \
                const __bf16* src = kbase + (size_t)((j0) + key) * 128 + ((c ^ (key & 7)) * 8); \
                __builtin_amdgcn_global_load_lds((gl_bf16*)src, kl + i * 2048 + wave * 512, 16, 0, 0); \
            }                                                                              \
            _Pragma("unroll")                                                              \
            for (int i = 0; i < 4; ++i) {                                                  \
                const int li = i * 256 + tid;                                              \
                const int dd = li >> 3, cv = li & 7;                                       \
                const __bf16* src = vbase + (size_t)dd * 2048 + (j0) + ((cv ^ (dd & 7)) * 8); \
                __builtin_amdgcn_global_load_lds((gl_bf16*)src, vl + i * 2048 + wave * 512, 16, 0, 0); \
            }                                                                              \
        } while (0)

    STAGE_KV(0, 0);
    char* PlB = smem + 65536 + wave * 2048;

    for (int t = 0; t < ntiles; ++t) {
        const int tn = (t + 1 < ntiles) ? t + 1 : t;
        STAGE_KV(tn * 64, (t + 1) & 1);
        asm volatile("s_waitcnt vmcnt(8)" ::: "memory");
        __builtin_amdgcn_s_barrier();
        asm volatile("" ::: "memory");

        const char* KlB = smem + (t & 1) * 32768;
        const char* VlB = smem + (t & 1) * 32768 + 16384;

        attn_step(KlB, VlB, PlB, qfH, oH, mH, sH, t == hi, lg, ll, qloc);
        if (t <= lo)
            attn_step(KlB, VlB, PlB, qfL, oL, mL, sL, t == lo, lg, ll, qloc);

        asm volatile("" ::: "memory");
        __builtin_amdgcn_s_barrier();
        asm volatile("" ::: "memory");
    }

    const float invH = __builtin_amdgcn_rcpf(sH);
    const float invL = __builtin_amdgcn_rcpf(sL);
    const int qHrow = hi * 64 + wave * 16 + ll;
    const int qLrow = lo * 64 + wave * 16 + ll;
    #pragma unroll
    for (int nd = 0; nd < 8; ++nd) {
        bf16x4 aH, aL;
        #pragma unroll
        for (int r = 0; r < 4; ++r) {
            aH[r] = (__bf16)(oH[nd][r] * invH);
            aL[r] = (__bf16)(oL[nd][r] * invL);
        }
        const size_t cb = h * 128 + nd * 16 + lg * 4;
        *reinterpret_cast<bf16x4*>(&attnb[((size_t)(b * 2048) + qHrow) * 2048 + cb]) = aH;
        *reinterpret_cast<bf16x4*>(&attnb[((size_t)(b * 2048) + qLrow) * 2048 + cb]) = aL;
    }
    #undef STAGE_KV
}

// ---------- host launch ----------
extern "C" void kernel_launch(void* const* d_in, const int* in_sizes, int n_in,
                              void* d_out, int out_size, void* d_ws, size_t ws_size,
                              hipStream_t stream) {
    const float* x    = (const float*)d_in[0];
    const float* cosb = (const float*)d_in[1];
    const float* sinb = (const float*)d_in[2];
    const float* wq   = (const float*)d_in[3];
    const float* bq   = (const float*)d_in[4];
    const float* wk   = (const float*)d_in[5];
    const float* bk   = (const float*)d_in[6];
    const float* wv   = (const float*)d_in[7];
    const float* bv   = (const float*)d_in[8];
    const float* wo   = (const float*)d_in[9];
    float* out = (float*)d_out;

    char* ws = (char*)d_ws;
    __bf16* xb    = (__bf16*)(ws);                         // 16,777,216  (later reused as attnb)
    __bf16* wb    = (__bf16*)(ws + 16777216);              // 10,485,760  (wq|wk|wv rows, 2560x2048)
    __bf16* wob   = (__bf16*)(ws + 27262976);              //  8,388,608
    float*  biasc = (float*) (ws + 35651584);              //     16,384 (2560 used)
    __bf16* qTp   = (__bf16*)(ws + 77611008);              // 16,777,216
    __bf16* kTp   = (__bf16*)(ws + 94388224);              //  2,097,152
    __bf16* vTp   = (__bf16*)(ws + 96485376);              //  2,097,152

    // 1) convert all fp32 inputs to bf16 (exact-sized grid: 17408 blocks)
    cvt_all<<<17408, 256, 0, stream>>>(
        x,  xb,
        wq, wb,
        wk, wb + 4194304,
        wv, wb + 4718592,
        wo, wob);
    concat_bias<<<10, 256, 0, stream>>>(bq, bk, bv, biasc);

    // 2) fused QKV GEMM + bias + RoPE + layout  [160 wg, 512 thr, 128 KB LDS]
    gemm_qkv_rope<<<160, 512, 0, stream>>>(xb, wb, biasc, cosb, sinb, qTp, kTp, vTp);

    // 3) flash attention -> attnb (reuses xb region, bf16 (B,L,H*D))
    attn_kernel<<<512, 256, 0, stream>>>(qTp, kTp, vTp, xb);

    // 4) output GEMM: (4096x2048) x (2048x2048)^T -> fp32 d_out  [512 wg]
    gemm_bt<<<512, 256, 0, stream>>>(xb, wob, out, 2048, 2048, 16);
}

// Round 10
// 184.920 us; speedup vs baseline: 1.7656x; 1.0810x over previous
//
#include <hip/hip_runtime.h>
#include <hip/hip_bf16.h>
#include <cstdint>

// ---------- types ----------
typedef __bf16 bf16x8 __attribute__((ext_vector_type(8)));
typedef __bf16 bf16x4 __attribute__((ext_vector_type(4)));
typedef __bf16 bf16x2 __attribute__((ext_vector_type(2)));
typedef float  f32x4  __attribute__((ext_vector_type(4)));
typedef __attribute__((address_space(3))) __bf16 lds_bf16;
typedef __attribute__((address_space(1))) const __bf16 gl_bf16;

// ---------- merged fp32 -> bf16 convert (exact-sized 1-D grid) ----------
__global__ void cvt_all(const float* __restrict__ s0, __bf16* __restrict__ d0,
                        const float* __restrict__ s1, __bf16* __restrict__ d1,
                        const float* __restrict__ s2, __bf16* __restrict__ d2,
                        const float* __restrict__ s3, __bf16* __restrict__ d3,
                        const float* __restrict__ s4, __bf16* __restrict__ d4) {
    const int blk = blockIdx.x;
    const float* s; __bf16* d; int base;
    if (blk < 8192)       { s = s0; d = d0; base = blk; }
    else if (blk < 12288) { s = s1; d = d1; base = blk - 8192; }
    else if (blk < 12800) { s = s2; d = d2; base = blk - 12288; }
    else if (blk < 13312) { s = s3; d = d3; base = blk - 12800; }
    else                  { s = s4; d = d4; base = blk - 13312; }
    const int i = (base * 256 + threadIdx.x) * 4;
    float4 v = *reinterpret_cast<const float4*>(s + i);
    bf16x4 o;
    o.x = (__bf16)v.x; o.y = (__bf16)v.y; o.z = (__bf16)v.z; o.w = (__bf16)v.w;
    *reinterpret_cast<bf16x4*>(d + i) = o;
}

// ---------- concat bq|bk|bv into one 2560-float buffer ----------
__global__ void concat_bias(const float* __restrict__ bq, const float* __restrict__ bk,
                            const float* __restrict__ bv, float* __restrict__ dst) {
    int t = blockIdx.x * blockDim.x + threadIdx.x;
    if (t < 2048)      dst[t] = bq[t];
    else if (t < 2304) dst[t] = bk[t - 2048];
    else if (t < 2560) dst[t] = bv[t - 2304];
}

// ---------- stage one 128x64 half-tile: 2 global_load_lds per thread ----------
// LDS linear [row][chunk], content pre-swizzled: slot (row,c) holds global
// chunk (c ^ (row&7)).
__device__ __forceinline__ void stage_half(const __bf16* __restrict__ gbase, int K, int k0,
                                           lds_bf16* lbase, int tid) {
    const int cc = (tid & 7) ^ ((tid >> 3) & 7);
    const __bf16* s0 = gbase + (size_t)(tid >> 3) * K + k0 + cc * 8;
    __builtin_amdgcn_global_load_lds((gl_bf16*)s0, lbase + (tid >> 6) * 512, 16, 0, 0);
    const __bf16* s1 = gbase + (size_t)(64 + (tid >> 3)) * K + k0 + cc * 8;
    __builtin_amdgcn_global_load_lds((gl_bf16*)s1, lbase + 4096 + (tid >> 6) * 512, 16, 0, 0);
}

// ---------- out-proj GEMM: 256x128 tile, 8 waves, 2-phase pipelined, grid 256 ----------
// Perfect single-round CU fill. Per K-tile: P0 {stage A-halves(next); vmcnt(4);
// bar; frag reads; 16 MFMA (m0-3); bar}  P1 {stage B(next); 16 MFMA (m4-7); bar}.
__global__ __launch_bounds__(512)
void gemm_out(const __bf16* __restrict__ A, const __bf16* __restrict__ B,
              float* __restrict__ C) {
    const int K = 2048, NT = 32;
    __shared__ __align__(16) char smem[98304];   // A: [0,64K) 2 bufs; B: [64K,96K) 2 bufs

    const int tid  = threadIdx.x;
    const int wave = tid >> 6, lane = tid & 63, lg = lane >> 4, ll = lane & 15;
    const int wr = wave >> 2, wc = wave & 3;     // 2M x 4N; per-wave 128x32

    const int orig = blockIdx.x;                 // 256 wg, %8 == 0
    const int wg   = (orig & 7) * 32 + (orig >> 3);
    const int bm = wg >> 4, bn = wg & 15;

    const __bf16* Atile = A + (size_t)(bm * 256) * K;
    const __bf16* Btile = B + (size_t)(bn * 128) * K;

    lds_bf16* AsL = (lds_bf16*)smem;             // per buf: 16384 elems (2 halves)
    lds_bf16* BsL = (lds_bf16*)(smem + 65536);   // per buf: 8192 elems

    f32x4 acc[8][2];
    #pragma unroll
    for (int m = 0; m < 8; ++m)
        #pragma unroll
        for (int n = 0; n < 2; ++n)
            acc[m][n] = f32x4{0.f, 0.f, 0.f, 0.f};

    // prologue: tile 0 -> buf 0 (A-lo, A-hi, B)
    stage_half(Atile,                 K, 0, AsL,        tid);
    stage_half(Atile + (size_t)128*K, K, 0, AsL + 8192, tid);
    stage_half(Btile,                 K, 0, BsL,        tid);

    const char* smB = (const char*)smem;
    for (int t = 0; t < NT; ++t) {
        const int c   = t & 1;
        const int bfn = c ^ 1;
        const int k0n = ((t + 1 < NT) ? t + 1 : t) * 64;   // clamp keeps counts uniform
        const char* AbB = smB + c * 32768 + wr * 16384;
        const char* BbB = smB + 65536 + c * 16384;
        bf16x8 af[8][2], bq[2][2];

        // ---- P0: stage A halves (next), counted wait, frag reads, MFMA m0-3
        stage_half(Atile,                 K, k0n, AsL + bfn * 8192 * 2,        tid);
        stage_half(Atile + (size_t)128*K, K, k0n, AsL + bfn * 8192 * 2 + 8192, tid);
        asm volatile("s_waitcnt vmcnt(4)" ::: "memory");
        __builtin_amdgcn_s_barrier();
        asm volatile("" ::: "memory");
        #pragma unroll
        for (int kk = 0; kk < 2; ++kk) {
            #pragma unroll
            for (int mm = 0; mm < 8; ++mm)
                af[mm][kk] = *reinterpret_cast<const bf16x8*>(
                    AbB + (mm * 16 + ll) * 128 + (((kk * 4 + lg) ^ (ll & 7)) << 4));
            #pragma unroll
            for (int nn = 0; nn < 2; ++nn)
                bq[nn][kk] = *reinterpret_cast<const bf16x8*>(
                    BbB + (wc * 32 + nn * 16 + ll) * 128 + (((kk * 4 + lg) ^ (ll & 7)) << 4));
        }
        __builtin_amdgcn_s_setprio(1);
        #pragma unroll
        for (int kk = 0; kk < 2; ++kk)
            #pragma unroll
            for (int mm = 0; mm < 4; ++mm)
                #pragma unroll
                for (int nn = 0; nn < 2; ++nn)
                    acc[mm][nn] = __builtin_amdgcn_mfma_f32_16x16x32_bf16(af[mm][kk], bq[nn][kk], acc[mm][nn], 0, 0, 0);
        __builtin_amdgcn_s_setprio(0);
        asm volatile("" ::: "memory");
        __builtin_amdgcn_s_barrier();
        asm volatile("" ::: "memory");

        // ---- P1: stage B (next), MFMA m4-7, end-of-iter barrier
        stage_half(Btile, K, k0n, BsL + bfn * 8192, tid);
        __builtin_amdgcn_s_setprio(1);
        #pragma unroll
        for (int kk = 0; kk < 2; ++kk)
            #pragma unroll
            for (int mm = 0; mm < 4; ++mm)
                #pragma unroll
                for (int nn = 0; nn < 2; ++nn)
                    acc[4 + mm][nn] = __builtin_amdgcn_mfma_f32_16x16x32_bf16(af[4 + mm][kk], bq[nn][kk], acc[4 + mm][nn], 0, 0, 0);
        __builtin_amdgcn_s_setprio(0);
        asm volatile("" ::: "memory");
        __builtin_amdgcn_s_barrier();   // all reads of buf c done before next iter stages it
        asm volatile("" ::: "memory");
    }

    asm volatile("s_waitcnt vmcnt(0)" ::: "memory");   // drain clamped tail prefetch

    #pragma unroll
    for (int m = 0; m < 8; ++m)
        #pragma unroll
        for (int n = 0; n < 2; ++n) {
            const int col = bn * 128 + wc * 32 + n * 16 + ll;
            #pragma unroll
            for (int r = 0; r < 4; ++r) {
                const int rowg = bm * 256 + wr * 128 + m * 16 + lg * 4 + r;
                C[(size_t)rowg * 2048 + col] = acc[m][n][r];
            }
        }
}

// ---------- QKV GEMM 256x256, 8 waves, 4-phase K-loop, hoisted frag reads ----------
// P0: stage A-lo,B-lo(next); vmcnt(4); bar; read ALL 24 frags; MFMA Q1; bar.
// P1: stage B-hi,A-hi(next); MFMA Q2; bar.  P2: MFMA Q3; bar.  P3: MFMA Q4; bar.
// Q2-Q4 are pure-MFMA phases; their frag reads overlap Q1's cluster via the
// compiler's counted lgkmcnt.
__global__ __launch_bounds__(512, 2)
void gemm_qkv_rope(const __bf16* __restrict__ A, const __bf16* __restrict__ B,
                   const float* __restrict__ bias, const float* __restrict__ cosb,
                   const float* __restrict__ sinb, __bf16* __restrict__ qT,
                   __bf16* __restrict__ kT, __bf16* __restrict__ vT) {
    const int K = 2048, NBN = 10, NT = 32;
    __shared__ __align__(16) char smem[131072];   // A: [0,64K)  B: [64K,128K)

    const int tid  = threadIdx.x;
    const int wave = tid >> 6, lane = tid & 63, lg = lane >> 4, ll = lane & 15;
    const int wr = wave >> 2, wc = wave & 3;       // 2 x 4 wave grid

    const int nwg  = gridDim.x;                    // 160, %8 == 0
    const int cpx  = nwg >> 3;
    const int orig = blockIdx.x;
    const int wg   = (orig & 7) * cpx + (orig >> 3);
    const int bm = wg / NBN, bn = wg - bm * NBN;

    const __bf16* Atile = A + (size_t)(bm * 256) * K;
    const __bf16* Btile = B + (size_t)(bn * 256) * K;

    lds_bf16* AsL = (lds_bf16*)smem;               // [buf][half][8192] elems
    lds_bf16* BsL = (lds_bf16*)(smem + 65536);

    f32x4 acc[8][4];
    #pragma unroll
    for (int m = 0; m < 8; ++m)
        #pragma unroll
        for (int n = 0; n < 4; ++n)
            acc[m][n] = f32x4{0.f, 0.f, 0.f, 0.f};

    // prologue: tile 0 into buf 0
    stage_half(Atile,                 K, 0, AsL,        tid);
    stage_half(Btile,                 K, 0, BsL,        tid);
    stage_half(Btile + (size_t)128*K, K, 0, BsL + 8192, tid);
    stage_half(Atile + (size_t)128*K, K, 0, AsL + 8192, tid);

    const char* smB = (const char*)smem;
    const int browb = (wc & 1) * 64;   // wave's B row base within its half

    for (int t = 0; t < NT; ++t) {
        const int c   = t & 1;
        const int bfn = c ^ 1;
        const int k0n = ((t + 1 < NT) ? t + 1 : t) * 64;
        const char* AbB = smB + c * 32768 + wr * 16384;
        const char* BbB = smB + 65536 + c * 32768 + (wc >> 1) * 16384;
        bf16x8 af[8][2], bq[4][2];

        // ---- P0: stage A-lo,B-lo(next); vmcnt(4); bar; hoisted reads; MFMA Q1
        stage_half(Atile, K, k0n, AsL + bfn * 16384, tid);
        stage_half(Btile, K, k0n, BsL + bfn * 16384, tid);
        asm volatile("s_waitcnt vmcnt(4)" ::: "memory");
        __builtin_amdgcn_s_barrier();
        asm volatile("" ::: "memory");
        #pragma unroll
        for (int kk = 0; kk < 2; ++kk) {
            #pragma unroll
            for (int mm = 0; mm < 8; ++mm)
                af[mm][kk] = *reinterpret_cast<const bf16x8*>(
                    AbB + (mm * 16 + ll) * 128 + (((kk * 4 + lg) ^ (ll & 7)) << 4));
            #pragma unroll
            for (int nn = 0; nn < 4; ++nn)
                bq[nn][kk] = *reinterpret_cast<const bf16x8*>(
                    BbB + (browb + nn * 16 + ll) * 128 + (((kk * 4 + lg) ^ (ll & 7)) << 4));
        }
        __builtin_amdgcn_s_setprio(1);
        #pragma unroll
        for (int kk = 0; kk < 2; ++kk)
            #pragma unroll
            for (int mm = 0; mm < 4; ++mm)
                #pragma unroll
                for (int nn = 0; nn < 2; ++nn)
                    acc[mm][nn] = __builtin_amdgcn_mfma_f32_16x16x32_bf16(af[mm][kk], bq[nn][kk], acc[mm][nn], 0, 0, 0);
        __builtin_amdgcn_s_setprio(0);
        asm volatile("" ::: "memory");
        __builtin_amdgcn_s_barrier();
        asm volatile("" ::: "memory");

        // ---- P1: stage B-hi,A-hi(next); MFMA Q2 (m0-3, n2-3)
        stage_half(Btile + (size_t)128*K, K, k0n, BsL + bfn * 16384 + 8192, tid);
        stage_half(Atile + (size_t)128*K, K, k0n, AsL + bfn * 16384 + 8192, tid);
        __builtin_amdgcn_s_setprio(1);
        #pragma unroll
        for (int kk = 0; kk < 2; ++kk)
            #pragma unroll
            for (int mm = 0; mm < 4; ++mm)
                #pragma unroll
                for (int nn = 0; nn < 2; ++nn)
                    acc[mm][2 + nn] = __builtin_amdgcn_mfma_f32_16x16x32_bf16(af[mm][kk], bq[2 + nn][kk], acc[mm][2 + nn], 0, 0, 0);
        __builtin_amdgcn_s_setprio(0);
        asm volatile("" ::: "memory");
        __builtin_amdgcn_s_barrier();
        asm volatile("" ::: "memory");

        // ---- P2: MFMA Q3 (m4-7, n2-3)
        __builtin_amdgcn_s_setprio(1);
        #pragma unroll
        for (int kk = 0; kk < 2; ++kk)
            #pragma unroll
            for (int mm = 0; mm < 4; ++mm)
                #pragma unroll
                for (int nn = 0; nn < 2; ++nn)
                    acc[4 + mm][2 + nn] = __builtin_amdgcn_mfma_f32_16x16x32_bf16(af[4 + mm][kk], bq[2 + nn][kk], acc[4 + mm][2 + nn], 0, 0, 0);
        __builtin_amdgcn_s_setprio(0);
        asm volatile("" ::: "memory");
        __builtin_amdgcn_s_barrier();
        asm volatile("" ::: "memory");

        // ---- P3: MFMA Q4 (m4-7, n0-1); end-of-iter barrier
        __builtin_amdgcn_s_setprio(1);
        #pragma unroll
        for (int kk = 0; kk < 2; ++kk)
            #pragma unroll
            for (int mm = 0; mm < 4; ++mm)
                #pragma unroll
                for (int nn = 0; nn < 2; ++nn)
                    acc[4 + mm][nn] = __builtin_amdgcn_mfma_f32_16x16x32_bf16(af[4 + mm][kk], bq[nn][kk], acc[4 + mm][nn], 0, 0, 0);
        __builtin_amdgcn_s_setprio(0);
        asm volatile("" ::: "memory");
        __builtin_amdgcn_s_barrier();   // all reads of buf c done before next iter stages it
        asm volatile("" ::: "memory");
    }

    asm volatile("s_waitcnt vmcnt(0)" ::: "memory");
    __syncthreads();

    // ---- epilogue (unchanged) ----
    if (bn == 9) {
        #pragma unroll
        for (int m = 0; m < 8; ++m)
            #pragma unroll
            for (int n = 0; n < 4; ++n) {
                const int col = wc * 64 + n * 16 + ll;
                const int kvh = col >> 7, d = col & 127;
                const float bv = bias[2304 + col];
                const int rbase = bm * 256 + wr * 128 + m * 16 + lg * 4;
                const int b = rbase >> 11, l0 = rbase & 2047;
                bf16x4 o4;
                #pragma unroll
                for (int r = 0; r < 4; ++r) o4[r] = (__bf16)(acc[m][n][r] + bv);
                *reinterpret_cast<bf16x4*>(&vT[((size_t)(b * 2 + kvh) * 128 + d) * 2048 + l0]) = o4;
            }
    } else {
        const bool isQ = (bn < 8);
        const float qsc = isQ ? 0.08838834764831845f * 1.4426950408889634f : 1.0f;
        float* Ex = (float*)smem;
        float bvr[4];
        #pragma unroll
        for (int n = 0; n < 4; ++n) bvr[n] = bias[bn * 256 + wc * 64 + n * 16 + ll];
        for (int m = 0; m < 8; ++m) {
            #pragma unroll
            for (int n = 0; n < 4; ++n) {
                const int col = wc * 64 + n * 16 + ll;
                #pragma unroll
                for (int r = 0; r < 4; ++r)
                    Ex[(wr * 16 + lg * 4 + r) * 260 + col] = acc[m][n][r] + bvr[n];
            }
            __syncthreads();
            #pragma unroll
            for (int n = 0; n < 4; ++n) {
                const int col = wc * 64 + n * 16 + ll;
                const int d = col & 127;
                const float sgn = (d < 64) ? -1.f : 1.f;
                #pragma unroll
                for (int r = 0; r < 4; ++r) {
                    const int er = wr * 16 + lg * 4 + r;
                    const float self = Ex[er * 260 + col];
                    const float part = Ex[er * 260 + (col ^ 64)];
                    const int rowg = bm * 256 + wr * 128 + m * 16 + lg * 4 + r;
                    const int b = rowg >> 11, l = rowg & 2047;
                    const float cc = cosb[l * 128 + d], ss = sinb[l * 128 + d];
                    const float val = (self * cc + sgn * part * ss) * qsc;
                    if (isQ) {
                        const int h = bn * 2 + (col >> 7);
                        qT[(((size_t)(b * 16 + h)) * 2048 + l) * 128 + d] = (__bf16)val;
                    } else {
                        const int kvh = col >> 7;
                        kT[(((size_t)(b * 2 + kvh)) * 2048 + l) * 128 + d] = (__bf16)val;
                    }
                }
            }
            __syncthreads();
        }
    }
}

// ---------- attn: one Q-group step (unchanged) ----------
__device__ __forceinline__ void attn_step(const char* KlB, const char* VlB, char* PlB,
                                          const bf16x8* qf, f32x4* o, float& mrow, float& srow,
                                          bool diag, int lg, int ll, int qloc) {
    f32x4 s[4];
    #pragma unroll
    for (int n = 0; n < 4; ++n) s[n] = f32x4{0.f, 0.f, 0.f, 0.f};
    __builtin_amdgcn_s_setprio(1);
    #pragma unroll
    for (int kk = 0; kk < 4; ++kk)
        #pragma unroll
        for (int n = 0; n < 4; ++n) {
            const int row = n * 16 + ll;
            bf16x8 kf = *reinterpret_cast<const bf16x8*>(
                KlB + row * 256 + (((kk * 4 + lg) ^ (ll & 7)) << 4));
            s[n] = __builtin_amdgcn_mfma_f32_16x16x32_bf16(kf, qf[kk], s[n], 0, 0, 0);
        }
    __builtin_amdgcn_s_setprio(0);

    if (diag) {
        #pragma unroll
        for (int n = 0; n < 4; ++n)
            #pragma unroll
            for (int r = 0; r < 4; ++r)
                if (n * 16 + lg * 4 + r > qloc) s[n][r] = -3e38f;
    }

    float tmax = s[0][0];
    #pragma unroll
    for (int n = 0; n < 4; ++n)
        #pragma unroll
        for (int r = 0; r < 4; ++r) tmax = fmaxf(tmax, s[n][r]);
    tmax = fmaxf(tmax, __shfl_xor(tmax, 16));
    tmax = fmaxf(tmax, __shfl_xor(tmax, 32));
    const float mnew = fmaxf(mrow, tmax);
    const float scl = __builtin_amdgcn_exp2f(mrow - mnew);
    mrow = mnew;
    float rs = 0.f;
    #pragma unroll
    for (int n = 0; n < 4; ++n)
        #pragma unroll
        for (int r = 0; r < 4; ++r) {
            const float p = __builtin_amdgcn_exp2f(s[n][r] - mnew);
            s[n][r] = p;
            rs += p;
        }
    rs += __shfl_xor(rs, 16);
    rs += __shfl_xor(rs, 32);
    srow = srow * scl + rs;

    #pragma unroll
    for (int nd = 0; nd < 8; ++nd)
        #pragma unroll
        for (int r = 0; r < 4; ++r) o[nd][r] *= scl;

    #pragma unroll
    for (int n = 0; n < 4; ++n)
        #pragma unroll
        for (int rp = 0; rp < 2; ++rp) {
            const int col = n * 16 + lg * 4 + rp * 2;
            bf16x2 pk;
            pk.x = (__bf16)s[n][rp * 2];
            pk.y = (__bf16)s[n][rp * 2 + 1];
            *reinterpret_cast<bf16x2*>(
                PlB + ll * 128 + (((col >> 3) ^ (ll & 7)) << 4) + (col & 7) * 2) = pk;
        }

    __builtin_amdgcn_s_setprio(1);
    #pragma unroll
    for (int kk = 0; kk < 2; ++kk) {
        bf16x8 pf = *reinterpret_cast<const bf16x8*>(
            PlB + ll * 128 + (((kk * 4 + lg) ^ (ll & 7)) << 4));
        #pragma unroll
        for (int nd = 0; nd < 8; ++nd) {
            const int row = nd * 16 + ll;
            bf16x8 vf = *reinterpret_cast<const bf16x8*>(
                VlB + row * 128 + (((kk * 4 + lg) ^ (ll & 7)) << 4));
            o[nd] = __builtin_amdgcn_mfma_f32_16x16x32_bf16(vf, pf, o[nd], 0, 0, 0);
        }
    }
    __builtin_amdgcn_s_setprio(0);
}

// ---------- causal GQA flash attention (unchanged) ----------
__global__ __launch_bounds__(256)
void attn_kernel(const __bf16* __restrict__ qT, const __bf16* __restrict__ kT,
                 const __bf16* __restrict__ vT, __bf16* __restrict__ attnb) {
    const int bx = blockIdx.x;
    const int qp = bx >> 5;
    const int hb = bx & 31;
    const int h = hb >> 1, b = hb & 1;
    const int kv = h >> 3;
    const int lo = qp, hi = 31 - qp;
    const int tid = threadIdx.x, wave = tid >> 6, lane = tid & 63, lg = lane >> 4, ll = lane & 15;
    const int qloc = wave * 16 + ll;

    __shared__ __align__(16) char smem[73728];
    lds_bf16* ldsE = (lds_bf16*)smem;

    const __bf16* kbase = kT + (size_t)((b * 2 + kv) * 2048) * 128;
    const __bf16* vbase = vT + (size_t)((b * 2 + kv) * 128) * 2048;

    bf16x8 qfL[4], qfH[4];
    {
        const __bf16* q0 = qT + ((size_t)((b * 16 + h) * 2048) + lo * 64 + wave * 16 + ll) * 128;
        const __bf16* q1 = qT + ((size_t)((b * 16 + h) * 2048) + hi * 64 + wave * 16 + ll) * 128;
        #pragma unroll
        for (int kk = 0; kk < 4; ++kk) {
            qfL[kk] = *reinterpret_cast<const bf16x8*>(q0 + kk * 32 + lg * 8);
            qfH[kk] = *reinterpret_cast<const bf16x8*>(q1 + kk * 32 + lg * 8);
        }
    }

    f32x4 oL[8], oH[8];
    #pragma unroll
    for (int nd = 0; nd < 8; ++nd) { oL[nd] = f32x4{0.f,0.f,0.f,0.f}; oH[nd] = f32x4{0.f,0.f,0.f,0.f}; }
    float mL = -3e38f, sL = 0.f, mH = -3e38f, sH = 0.f;

    const int ntiles = hi + 1;

    #define STAGE_KV(j0, buf)                                                              \
        do {                                                                               \
            lds_bf16* kl = ldsE + (buf) * 16384;                                           \
            lds_bf16* vl = ldsE + (buf) * 16384 + 8192;                                    \
            _Pragma("unroll")                                                              \
            for (int i = 0; i < 4; ++i) {                                                  \
                const int li = i * 256 + tid;                                              \
                const int key = li >> 4, c = li & 15;                                      \
                const __bf16* src = kbase + (size_t)((j0) + key) * 128 + ((c ^ (key & 7)) * 8); \
                __builtin_amdgcn_global_load_lds((gl_bf16*)src, kl + i * 2048 + wave * 512, 16, 0, 0); \
            }                                                                              \
            _Pragma("unroll")                                                              \
            for (int i = 0; i < 4; ++i) {                                                  \
                const int li = i * 256 + tid;                                              \
                const int dd = li >> 3, cv = li & 7;                                       \
                const __bf16* src = vbase + (size_t)dd * 2048 + (j0) + ((cv ^ (dd & 7)) * 8); \
                __builtin_amdgcn_global_load_lds((gl_bf16*)src, vl + i * 2048 + wave * 512, 16, 0, 0); \
            }                                                                              \
        } while (0)

    STAGE_KV(0, 0);
    char* PlB = smem + 65536 + wave * 2048;

    for (int t = 0; t < ntiles; ++t) {
        const int tn = (t + 1 < ntiles) ? t + 1 : t;
        STAGE_KV(tn * 64, (t + 1) & 1);
        asm volatile("s_waitcnt vmcnt(8)" ::: "memory");
        __builtin_amdgcn_s_barrier();
        asm volatile("" ::: "memory");

        const char* KlB = smem + (t & 1) * 32768;
        const char* VlB = smem + (t & 1) * 32768 + 16384;

        attn_step(KlB, VlB, PlB, qfH, oH, mH, sH, t == hi, lg, ll, qloc);
        if (t <= lo)
            attn_step(KlB, VlB, PlB, qfL, oL, mL, sL, t == lo, lg, ll, qloc);

        asm volatile("" ::: "memory");
        __builtin_amdgcn_s_barrier();
        asm volatile("" ::: "memory");
    }

    const float invH = __builtin_amdgcn_rcpf(sH);
    const float invL = __builtin_amdgcn_rcpf(sL);
    const int qHrow = hi * 64 + wave * 16 + ll;
    const int qLrow = lo * 64 + wave * 16 + ll;
    #pragma unroll
    for (int nd = 0; nd < 8; ++nd) {
        bf16x4 aH, aL;
        #pragma unroll
        for (int r = 0; r < 4; ++r) {
            aH[r] = (__bf16)(oH[nd][r] * invH);
            aL[r] = (__bf16)(oL[nd][r] * invL);
        }
        const size_t cb = h * 128 + nd * 16 + lg * 4;
        *reinterpret_cast<bf16x4*>(&attnb[((size_t)(b * 2048) + qHrow) * 2048 + cb]) = aH;
        *reinterpret_cast<bf16x4*>(&attnb[((size_t)(b * 2048) + qLrow) * 2048 + cb]) = aL;
    }
    #undef STAGE_KV
}

// ---------- host launch ----------
extern "C" void kernel_launch(void* const* d_in, const int* in_sizes, int n_in,
                              void* d_out, int out_size, void* d_ws, size_t ws_size,
                              hipStream_t stream) {
    const float* x    = (const float*)d_in[0];
    const float* cosb = (const float*)d_in[1];
    const float* sinb = (const float*)d_in[2];
    const float* wq   = (const float*)d_in[3];
    const float* bq   = (const float*)d_in[4];
    const float* wk   = (const float*)d_in[5];
    const float* bk   = (const float*)d_in[6];
    const float* wv   = (const float*)d_in[7];
    const float* bv   = (const float*)d_in[8];
    const float* wo   = (const float*)d_in[9];
    float* out = (float*)d_out;

    char* ws = (char*)d_ws;
    __bf16* xb    = (__bf16*)(ws);                         // 16,777,216  (later reused as attnb)
    __bf16* wb    = (__bf16*)(ws + 16777216);              // 10,485,760  (wq|wk|wv rows, 2560x2048)
    __bf16* wob   = (__bf16*)(ws + 27262976);              //  8,388,608
    float*  biasc = (float*) (ws + 35651584);              //     16,384 (2560 used)
    __bf16* qTp   = (__bf16*)(ws + 77611008);              // 16,777,216
    __bf16* kTp   = (__bf16*)(ws + 94388224);              //  2,097,152
    __bf16* vTp   = (__bf16*)(ws + 96485376);              //  2,097,152

    // 1) convert all fp32 inputs to bf16 (exact-sized grid: 17408 blocks)
    cvt_all<<<17408, 256, 0, stream>>>(
        x,  xb,
        wq, wb,
        wk, wb + 4194304,
        wv, wb + 4718592,
        wo, wob);
    concat_bias<<<10, 256, 0, stream>>>(bq, bk, bv, biasc);

    // 2) fused QKV GEMM + bias + RoPE + layout  [160 wg, 512 thr, 128 KB LDS]
    gemm_qkv_rope<<<160, 512, 0, stream>>>(xb, wb, biasc, cosb, sinb, qTp, kTp, vTp);

    // 3) flash attention -> attnb (reuses xb region, bf16 (B,L,H*D))
    attn_kernel<<<512, 256, 0, stream>>>(qTp, kTp, vTp, xb);

    // 4) output GEMM: 256x128 tiles, grid 256 (perfect fill), pipelined
    gemm_out<<<256, 512, 0, stream>>>(xb, wob, out);
}

// Round 11
// 184.713 us; speedup vs baseline: 1.7675x; 1.0011x over previous
//
#include <hip/hip_runtime.h>
#include <hip/hip_bf16.h>
#include <cstdint>

// ---------- types ----------
typedef __bf16 bf16x8 __attribute__((ext_vector_type(8)));
typedef __bf16 bf16x4 __attribute__((ext_vector_type(4)));
typedef __bf16 bf16x2 __attribute__((ext_vector_type(2)));
typedef float  f32x4  __attribute__((ext_vector_type(4)));
typedef __attribute__((address_space(3))) __bf16 lds_bf16;
typedef __attribute__((address_space(1))) const __bf16 gl_bf16;

// ---------- merged fp32 -> bf16 convert (exact-sized 1-D grid) ----------
__global__ void cvt_all(const float* __restrict__ s0, __bf16* __restrict__ d0,
                        const float* __restrict__ s1, __bf16* __restrict__ d1,
                        const float* __restrict__ s2, __bf16* __restrict__ d2,
                        const float* __restrict__ s3, __bf16* __restrict__ d3,
                        const float* __restrict__ s4, __bf16* __restrict__ d4) {
    const int blk = blockIdx.x;
    const float* s; __bf16* d; int base;
    if (blk < 8192)       { s = s0; d = d0; base = blk; }
    else if (blk < 12288) { s = s1; d = d1; base = blk - 8192; }
    else if (blk < 12800) { s = s2; d = d2; base = blk - 12288; }
    else if (blk < 13312) { s = s3; d = d3; base = blk - 12800; }
    else                  { s = s4; d = d4; base = blk - 13312; }
    const int i = (base * 256 + threadIdx.x) * 4;
    float4 v = *reinterpret_cast<const float4*>(s + i);
    bf16x4 o;
    o.x = (__bf16)v.x; o.y = (__bf16)v.y; o.z = (__bf16)v.z; o.w = (__bf16)v.w;
    *reinterpret_cast<bf16x4*>(d + i) = o;
}

// ---------- concat bq|bk|bv into one 2560-float buffer ----------
__global__ void concat_bias(const float* __restrict__ bq, const float* __restrict__ bk,
                            const float* __restrict__ bv, float* __restrict__ dst) {
    int t = blockIdx.x * blockDim.x + threadIdx.x;
    if (t < 2048)      dst[t] = bq[t];
    else if (t < 2304) dst[t] = bk[t - 2048];
    else if (t < 2560) dst[t] = bv[t - 2304];
}

// ---------- stage one 128x64 half-tile: 2 global_load_lds per thread ----------
// LDS linear [row][chunk], content pre-swizzled: slot (row,c) holds global
// chunk (c ^ (row&7)).
__device__ __forceinline__ void stage_half(const __bf16* __restrict__ gbase, int K, int k0,
                                           lds_bf16* lbase, int tid) {
    const int cc = (tid & 7) ^ ((tid >> 3) & 7);
    const __bf16* s0 = gbase + (size_t)(tid >> 3) * K + k0 + cc * 8;
    __builtin_amdgcn_global_load_lds((gl_bf16*)s0, lbase + (tid >> 6) * 512, 16, 0, 0);
    const __bf16* s1 = gbase + (size_t)(64 + (tid >> 3)) * K + k0 + cc * 8;
    __builtin_amdgcn_global_load_lds((gl_bf16*)s1, lbase + 4096 + (tid >> 6) * 512, 16, 0, 0);
}

// ---------- out-proj GEMM (unchanged r10): 256x128 tile, grid 256 ----------
__global__ __launch_bounds__(512)
void gemm_out(const __bf16* __restrict__ A, const __bf16* __restrict__ B,
              float* __restrict__ C) {
    const int K = 2048, NT = 32;
    __shared__ __align__(16) char smem[98304];

    const int tid  = threadIdx.x;
    const int wave = tid >> 6, lane = tid & 63, lg = lane >> 4, ll = lane & 15;
    const int wr = wave >> 2, wc = wave & 3;

    const int orig = blockIdx.x;
    const int wg   = (orig & 7) * 32 + (orig >> 3);
    const int bm = wg >> 4, bn = wg & 15;

    const __bf16* Atile = A + (size_t)(bm * 256) * K;
    const __bf16* Btile = B + (size_t)(bn * 128) * K;

    lds_bf16* AsL = (lds_bf16*)smem;
    lds_bf16* BsL = (lds_bf16*)(smem + 65536);

    f32x4 acc[8][2];
    #pragma unroll
    for (int m = 0; m < 8; ++m)
        #pragma unroll
        for (int n = 0; n < 2; ++n)
            acc[m][n] = f32x4{0.f, 0.f, 0.f, 0.f};

    stage_half(Atile,                 K, 0, AsL,        tid);
    stage_half(Atile + (size_t)128*K, K, 0, AsL + 8192, tid);
    stage_half(Btile,                 K, 0, BsL,        tid);

    const char* smB = (const char*)smem;
    for (int t = 0; t < NT; ++t) {
        const int c   = t & 1;
        const int bfn = c ^ 1;
        const int k0n = ((t + 1 < NT) ? t + 1 : t) * 64;
        const char* AbB = smB + c * 32768 + wr * 16384;
        const char* BbB = smB + 65536 + c * 16384;
        bf16x8 af[8][2], bq[2][2];

        stage_half(Atile,                 K, k0n, AsL + bfn * 8192 * 2,        tid);
        stage_half(Atile + (size_t)128*K, K, k0n, AsL + bfn * 8192 * 2 + 8192, tid);
        asm volatile("s_waitcnt vmcnt(4)" ::: "memory");
        __builtin_amdgcn_s_barrier();
        asm volatile("" ::: "memory");
        #pragma unroll
        for (int kk = 0; kk < 2; ++kk) {
            #pragma unroll
            for (int mm = 0; mm < 8; ++mm)
                af[mm][kk] = *reinterpret_cast<const bf16x8*>(
                    AbB + (mm * 16 + ll) * 128 + (((kk * 4 + lg) ^ (ll & 7)) << 4));
            #pragma unroll
            for (int nn = 0; nn < 2; ++nn)
                bq[nn][kk] = *reinterpret_cast<const bf16x8*>(
                    BbB + (wc * 32 + nn * 16 + ll) * 128 + (((kk * 4 + lg) ^ (ll & 7)) << 4));
        }
        __builtin_amdgcn_s_setprio(1);
        #pragma unroll
        for (int kk = 0; kk < 2; ++kk)
            #pragma unroll
            for (int mm = 0; mm < 4; ++mm)
                #pragma unroll
                for (int nn = 0; nn < 2; ++nn)
                    acc[mm][nn] = __builtin_amdgcn_mfma_f32_16x16x32_bf16(af[mm][kk], bq[nn][kk], acc[mm][nn], 0, 0, 0);
        __builtin_amdgcn_s_setprio(0);
        asm volatile("" ::: "memory");
        __builtin_amdgcn_s_barrier();
        asm volatile("" ::: "memory");

        stage_half(Btile, K, k0n, BsL + bfn * 8192, tid);
        __builtin_amdgcn_s_setprio(1);
        #pragma unroll
        for (int kk = 0; kk < 2; ++kk)
            #pragma unroll
            for (int mm = 0; mm < 4; ++mm)
                #pragma unroll
                for (int nn = 0; nn < 2; ++nn)
                    acc[4 + mm][nn] = __builtin_amdgcn_mfma_f32_16x16x32_bf16(af[4 + mm][kk], bq[nn][kk], acc[4 + mm][nn], 0, 0, 0);
        __builtin_amdgcn_s_setprio(0);
        asm volatile("" ::: "memory");
        __builtin_amdgcn_s_barrier();
        asm volatile("" ::: "memory");
    }

    asm volatile("s_waitcnt vmcnt(0)" ::: "memory");

    #pragma unroll
    for (int m = 0; m < 8; ++m)
        #pragma unroll
        for (int n = 0; n < 2; ++n) {
            const int col = bn * 128 + wc * 32 + n * 16 + ll;
            #pragma unroll
            for (int r = 0; r < 4; ++r) {
                const int rowg = bm * 256 + wr * 128 + m * 16 + lg * 4 + r;
                C[(size_t)rowg * 2048 + col] = acc[m][n][r];
            }
        }
}

// ---------- QKV GEMM 256x256, m201-style phases: reads BEFORE the barrier ----------
// Per K-tile, 4 phases: {ds_read Qp frags; stage; s_barrier; setprio; 16 MFMA;
// setprio; s_barrier}. Reads fly across the open-barrier (overlap other waves'
// previous MFMA cluster). Stage: A-lo+B-lo at P0, B-hi+A-hi at P1. One
// vmcnt(0) per K-tile, after P3's MFMA (>=2.5 phases slack on every half).
__global__ __launch_bounds__(512, 2)
void gemm_qkv_rope(const __bf16* __restrict__ A, const __bf16* __restrict__ B,
                   const float* __restrict__ bias, const float* __restrict__ cosb,
                   const float* __restrict__ sinb, __bf16* __restrict__ qT,
                   __bf16* __restrict__ kT, __bf16* __restrict__ vT) {
    const int K = 2048, NBN = 10, NT = 32;
    __shared__ __align__(16) char smem[131072];   // A: [0,64K)  B: [64K,128K)

    const int tid  = threadIdx.x;
    const int wave = tid >> 6, lane = tid & 63, lg = lane >> 4, ll = lane & 15;
    const int wr = wave >> 2, wc = wave & 3;       // 2 x 4 wave grid

    const int nwg  = gridDim.x;                    // 160, %8 == 0
    const int cpx  = nwg >> 3;
    const int orig = blockIdx.x;
    const int wg   = (orig & 7) * cpx + (orig >> 3);
    const int bm = wg / NBN, bn = wg - bm * NBN;

    const __bf16* Atile = A + (size_t)(bm * 256) * K;
    const __bf16* Btile = B + (size_t)(bn * 256) * K;

    lds_bf16* AsL = (lds_bf16*)smem;               // [buf][half][8192] elems
    lds_bf16* BsL = (lds_bf16*)(smem + 65536);

    f32x4 acc[8][4];
    #pragma unroll
    for (int m = 0; m < 8; ++m)
        #pragma unroll
        for (int n = 0; n < 4; ++n)
            acc[m][n] = f32x4{0.f, 0.f, 0.f, 0.f};

    // prologue: tile 0 into buf 0, drain, barrier
    stage_half(Atile,                 K, 0, AsL,        tid);
    stage_half(Btile,                 K, 0, BsL,        tid);
    stage_half(Btile + (size_t)128*K, K, 0, BsL + 8192, tid);
    stage_half(Atile + (size_t)128*K, K, 0, AsL + 8192, tid);
    asm volatile("s_waitcnt vmcnt(0)" ::: "memory");
    __syncthreads();

    const char* smB = (const char*)smem;
    const int browb = (wc & 1) * 64;   // wave's B row base within its half

    for (int t = 0; t < NT; ++t) {
        const int c   = t & 1;
        const int bfn = c ^ 1;
        const int k0n = ((t + 1 < NT) ? t + 1 : t) * 64;
        const char* AbB = smB + c * 32768 + wr * 16384;
        const char* BbB = smB + 65536 + c * 32768 + (wc >> 1) * 16384;
        bf16x8 af03[4][2], af47[4][2], bq01[2][2], bq23[2][2];

        // ==== P0: reads Q1 (af0-3, bq0-1); stage A-lo,B-lo(t+1); bar; MFMA Q1; bar
        #pragma unroll
        for (int kk = 0; kk < 2; ++kk) {
            #pragma unroll
            for (int mm = 0; mm < 4; ++mm)
                af03[mm][kk] = *reinterpret_cast<const bf16x8*>(
                    AbB + (mm * 16 + ll) * 128 + (((kk * 4 + lg) ^ (ll & 7)) << 4));
            #pragma unroll
            for (int nn = 0; nn < 2; ++nn)
                bq01[nn][kk] = *reinterpret_cast<const bf16x8*>(
                    BbB + (browb + nn * 16 + ll) * 128 + (((kk * 4 + lg) ^ (ll & 7)) << 4));
        }
        asm volatile("" ::: "memory");
        stage_half(Atile, K, k0n, AsL + bfn * 16384, tid);
        stage_half(Btile, K, k0n, BsL + bfn * 16384, tid);
        asm volatile("" ::: "memory");
        __builtin_amdgcn_s_barrier();
        __builtin_amdgcn_s_setprio(1);
        #pragma unroll
        for (int kk = 0; kk < 2; ++kk)
            #pragma unroll
            for (int mm = 0; mm < 4; ++mm)
                #pragma unroll
                for (int nn = 0; nn < 2; ++nn)
                    acc[mm][nn] = __builtin_amdgcn_mfma_f32_16x16x32_bf16(af03[mm][kk], bq01[nn][kk], acc[mm][nn], 0, 0, 0);
        __builtin_amdgcn_s_setprio(0);
        asm volatile("" ::: "memory");
        __builtin_amdgcn_s_barrier();

        // ==== P1: reads bq2-3; stage B-hi,A-hi(t+1); bar; MFMA Q2 (af03 x bq23); bar
        #pragma unroll
        for (int kk = 0; kk < 2; ++kk)
            #pragma unroll
            for (int nn = 0; nn < 2; ++nn)
                bq23[nn][kk] = *reinterpret_cast<const bf16x8*>(
                    BbB + (browb + (2 + nn) * 16 + ll) * 128 + (((kk * 4 + lg) ^ (ll & 7)) << 4));
        asm volatile("" ::: "memory");
        stage_half(Btile + (size_t)128*K, K, k0n, BsL + bfn * 16384 + 8192, tid);
        stage_half(Atile + (size_t)128*K, K, k0n, AsL + bfn * 16384 + 8192, tid);
        asm volatile("" ::: "memory");
        __builtin_amdgcn_s_barrier();
        __builtin_amdgcn_s_setprio(1);
        #pragma unroll
        for (int kk = 0; kk < 2; ++kk)
            #pragma unroll
            for (int mm = 0; mm < 4; ++mm)
                #pragma unroll
                for (int nn = 0; nn < 2; ++nn)
                    acc[mm][2 + nn] = __builtin_amdgcn_mfma_f32_16x16x32_bf16(af03[mm][kk], bq23[nn][kk], acc[mm][2 + nn], 0, 0, 0);
        __builtin_amdgcn_s_setprio(0);
        asm volatile("" ::: "memory");
        __builtin_amdgcn_s_barrier();

        // ==== P2: reads af4-7; bar; MFMA Q3 (af47 x bq23); bar
        #pragma unroll
        for (int kk = 0; kk < 2; ++kk)
            #pragma unroll
            for (int mm = 0; mm < 4; ++mm)
                af47[mm][kk] = *reinterpret_cast<const bf16x8*>(
                    AbB + ((4 + mm) * 16 + ll) * 128 + (((kk * 4 + lg) ^ (ll & 7)) << 4));
        asm volatile("" ::: "memory");
        __builtin_amdgcn_s_barrier();
        __builtin_amdgcn_s_setprio(1);
        #pragma unroll
        for (int kk = 0; kk < 2; ++kk)
            #pragma unroll
            for (int mm = 0; mm < 4; ++mm)
                #pragma unroll
                for (int nn = 0; nn < 2; ++nn)
                    acc[4 + mm][2 + nn] = __builtin_amdgcn_mfma_f32_16x16x32_bf16(af47[mm][kk], bq23[nn][kk], acc[4 + mm][2 + nn], 0, 0, 0);
        __builtin_amdgcn_s_setprio(0);
        asm volatile("" ::: "memory");
        __builtin_amdgcn_s_barrier();

        // ==== P3: MFMA Q4 (af47 x bq01); vmcnt(0) for tile t+1; closing bar
        __builtin_amdgcn_s_setprio(1);
        #pragma unroll
        for (int kk = 0; kk < 2; ++kk)
            #pragma unroll
            for (int mm = 0; mm < 4; ++mm)
                #pragma unroll
                for (int nn = 0; nn < 2; ++nn)
                    acc[4 + mm][nn] = __builtin_amdgcn_mfma_f32_16x16x32_bf16(af47[mm][kk], bq01[nn][kk], acc[4 + mm][nn], 0, 0, 0);
        __builtin_amdgcn_s_setprio(0);
        asm volatile("s_waitcnt vmcnt(0)" ::: "memory");
        __builtin_amdgcn_s_barrier();
        asm volatile("" ::: "memory");
    }

    __syncthreads();

    // ---- epilogue (unchanged) ----
    if (bn == 9) {
        #pragma unroll
        for (int m = 0; m < 8; ++m)
            #pragma unroll
            for (int n = 0; n < 4; ++n) {
                const int col = wc * 64 + n * 16 + ll;
                const int kvh = col >> 7, d = col & 127;
                const float bv = bias[2304 + col];
                const int rbase = bm * 256 + wr * 128 + m * 16 + lg * 4;
                const int b = rbase >> 11, l0 = rbase & 2047;
                bf16x4 o4;
                #pragma unroll
                for (int r = 0; r < 4; ++r) o4[r] = (__bf16)(acc[m][n][r] + bv);
                *reinterpret_cast<bf16x4*>(&vT[((size_t)(b * 2 + kvh) * 128 + d) * 2048 + l0]) = o4;
            }
    } else {
        const bool isQ = (bn < 8);
        const float qsc = isQ ? 0.08838834764831845f * 1.4426950408889634f : 1.0f;
        float* Ex = (float*)smem;
        float bvr[4];
        #pragma unroll
        for (int n = 0; n < 4; ++n) bvr[n] = bias[bn * 256 + wc * 64 + n * 16 + ll];
        for (int m = 0; m < 8; ++m) {
            #pragma unroll
            for (int n = 0; n < 4; ++n) {
                const int col = wc * 64 + n * 16 + ll;
                #pragma unroll
                for (int r = 0; r < 4; ++r)
                    Ex[(wr * 16 + lg * 4 + r) * 260 + col] = acc[m][n][r] + bvr[n];
            }
            __syncthreads();
            #pragma unroll
            for (int n = 0; n < 4; ++n) {
                const int col = wc * 64 + n * 16 + ll;
                const int d = col & 127;
                const float sgn = (d < 64) ? -1.f : 1.f;
                #pragma unroll
                for (int r = 0; r < 4; ++r) {
                    const int er = wr * 16 + lg * 4 + r;
                    const float self = Ex[er * 260 + col];
                    const float part = Ex[er * 260 + (col ^ 64)];
                    const int rowg = bm * 256 + wr * 128 + m * 16 + lg * 4 + r;
                    const int b = rowg >> 11, l = rowg & 2047;
                    const float cc = cosb[l * 128 + d], ss = sinb[l * 128 + d];
                    const float val = (self * cc + sgn * part * ss) * qsc;
                    if (isQ) {
                        const int h = bn * 2 + (col >> 7);
                        qT[(((size_t)(b * 16 + h)) * 2048 + l) * 128 + d] = (__bf16)val;
                    } else {
                        const int kvh = col >> 7;
                        kT[(((size_t)(b * 2 + kvh)) * 2048 + l) * 128 + d] = (__bf16)val;
                    }
                }
            }
            __syncthreads();
        }
    }
}

// ---------- attn: one Q-group step (unchanged) ----------
__device__ __forceinline__ void attn_step(const char* KlB, const char* VlB, char* PlB,
                                          const bf16x8* qf, f32x4* o, float& mrow, float& srow,
                                          bool diag, int lg, int ll, int qloc) {
    f32x4 s[4];
    #pragma unroll
    for (int n = 0; n < 4; ++n) s[n] = f32x4{0.f, 0.f, 0.f, 0.f};
    __builtin_amdgcn_s_setprio(1);
    #pragma unroll
    for (int kk = 0; kk < 4; ++kk)
        #pragma unroll
        for (int n = 0; n < 4; ++n) {
            const int row = n * 16 + ll;
            bf16x8 kf = *reinterpret_cast<const bf16x8*>(
                KlB + row * 256 + (((kk * 4 + lg) ^ (ll & 7)) << 4));
            s[n] = __builtin_amdgcn_mfma_f32_16x16x32_bf16(kf, qf[kk], s[n], 0, 0, 0);
        }
    __builtin_amdgcn_s_setprio(0);

    if (diag) {
        #pragma unroll
        for (int n = 0; n < 4; ++n)
            #pragma unroll
            for (int r = 0; r < 4; ++r)
                if (n * 16 + lg * 4 + r > qloc) s[n][r] = -3e38f;
    }

    float tmax = s[0][0];
    #pragma unroll
    for (int n = 0; n < 4; ++n)
        #pragma unroll
        for (int r = 0; r < 4; ++r) tmax = fmaxf(tmax, s[n][r]);
    tmax = fmaxf(tmax, __shfl_xor(tmax, 16));
    tmax = fmaxf(tmax, __shfl_xor(tmax, 32));
    const float mnew = fmaxf(mrow, tmax);
    const float scl = __builtin_amdgcn_exp2f(mrow - mnew);
    mrow = mnew;
    float rs = 0.f;
    #pragma unroll
    for (int n = 0; n < 4; ++n)
        #pragma unroll
        for (int r = 0; r < 4; ++r) {
            const float p = __builtin_amdgcn_exp2f(s[n][r] - mnew);
            s[n][r] = p;
            rs += p;
        }
    rs += __shfl_xor(rs, 16);
    rs += __shfl_xor(rs, 32);
    srow = srow * scl + rs;

    #pragma unroll
    for (int nd = 0; nd < 8; ++nd)
        #pragma unroll
        for (int r = 0; r < 4; ++r) o[nd][r] *= scl;

    #pragma unroll
    for (int n = 0; n < 4; ++n)
        #pragma unroll
        for (int rp = 0; rp < 2; ++rp) {
            const int col = n * 16 + lg * 4 + rp * 2;
            bf16x2 pk;
            pk.x = (__bf16)s[n][rp * 2];
            pk.y = (__bf16)s[n][rp * 2 + 1];
            *reinterpret_cast<bf16x2*>(
                PlB + ll * 128 + (((col >> 3) ^ (ll & 7)) << 4) + (col & 7) * 2) = pk;
        }

    __builtin_amdgcn_s_setprio(1);
    #pragma unroll
    for (int kk = 0; kk < 2; ++kk) {
        bf16x8 pf = *reinterpret_cast<const bf16x8*>(
            PlB + ll * 128 + (((kk * 4 + lg) ^ (ll & 7)) << 4));
        #pragma unroll
        for (int nd = 0; nd < 8; ++nd) {
            const int row = nd * 16 + ll;
            bf16x8 vf = *reinterpret_cast<const bf16x8*>(
                VlB + row * 128 + (((kk * 4 + lg) ^ (ll & 7)) << 4));
            o[nd] = __builtin_amdgcn_mfma_f32_16x16x32_bf16(vf, pf, o[nd], 0, 0, 0);
        }
    }
    __builtin_amdgcn_s_setprio(0);
}

// ---------- causal GQA flash attention (unchanged) ----------
__global__ __launch_bounds__(256)
void attn_kernel(const __bf16* __restrict__ qT, const __bf16* __restrict__ kT,
                 const __bf16* __restrict__ vT, __bf16* __restrict__ attnb) {
    const int bx = blockIdx.x;
    const int qp = bx >> 5;
    const int hb = bx & 31;
    const int h = hb >> 1, b = hb & 1;
    const int kv = h >> 3;
    const int lo = qp, hi = 31 - qp;
    const int tid = threadIdx.x, wave = tid >> 6, lane = tid & 63, lg = lane >> 4, ll = lane & 15;
    const int qloc = wave * 16 + ll;

    __shared__ __align__(16) char smem[73728];
    lds_bf16* ldsE = (lds_bf16*)smem;

    const __bf16* kbase = kT + (size_t)((b * 2 + kv) * 2048) * 128;
    const __bf16* vbase = vT + (size_t)((b * 2 + kv) * 128) * 2048;

    bf16x8 qfL[4], qfH[4];
    {
        const __bf16* q0 = qT + ((size_t)((b * 16 + h) * 2048) + lo * 64 + wave * 16 + ll) * 128;
        const __bf16* q1 = qT + ((size_t)((b * 16 + h) * 2048) + hi * 64 + wave * 16 + ll) * 128;
        #pragma unroll
        for (int kk = 0; kk < 4; ++kk) {
            qfL[kk] = *reinterpret_cast<const bf16x8*>(q0 + kk * 32 + lg * 8);
            qfH[kk] = *reinterpret_cast<const bf16x8*>(q1 + kk * 32 + lg * 8);
        }
    }

    f32x4 oL[8], oH[8];
    #pragma unroll
    for (int nd = 0; nd < 8; ++nd) { oL[nd] = f32x4{0.f,0.f,0.f,0.f}; oH[nd] = f32x4{0.f,0.f,0.f,0.f}; }
    float mL = -3e38f, sL = 0.f, mH = -3e38f, sH = 0.f;

    const int ntiles = hi + 1;

    #define STAGE_KV(j0, buf)                                                              \
        do {                                                                               \
            lds_bf16* kl = ldsE + (buf) * 16384;                                           \
            lds_bf16* vl = ldsE + (buf) * 16384 + 8192;                                    \
            _Pragma("unroll")                                                              \
            for (int i = 0; i < 4; ++i) {                                                  \
                const int li = i * 256 + tid;                                              \
                const int key = li >> 4, c = li & 15;                                      \
                const __bf16* src = kbase + (size_t)((j0) + key) * 128 + ((c ^ (key & 7)) * 8); \
                __builtin_amdgcn_global_load_lds((gl_bf16*)src, kl + i * 2048 + wave * 512, 16, 0, 0); \
            }                                                                              \
            _Pragma("unroll")                                                              \
            for (int i = 0; i < 4; ++i) {                                                  \
                const int li = i * 256 + tid;                                              \
                const int dd = li >> 3, cv = li & 7;                                       \
                const __bf16* src = vbase + (size_t)dd * 2048 + (j0) + ((cv ^ (dd & 7)) * 8); \
                __builtin_amdgcn_global_load_lds((gl_bf16*)src, vl + i * 2048 + wave * 512, 16, 0, 0); \
            }                                                                              \
        } while (0)

    STAGE_KV(0, 0);
    char* PlB = smem + 65536 + wave * 2048;

    for (int t = 0; t < ntiles; ++t) {
        const int tn = (t + 1 < ntiles) ? t + 1 : t;
        STAGE_KV(tn * 64, (t + 1) & 1);
        asm volatile("s_waitcnt vmcnt(8)" ::: "memory");
        __builtin_amdgcn_s_barrier();
        asm volatile("" ::: "memory");

        const char* KlB = smem + (t & 1) * 32768;
        const char* VlB = smem + (t & 1) * 32768 + 16384;

        attn_step(KlB, VlB, PlB, qfH, oH, mH, sH, t == hi, lg, ll, qloc);
        if (t <= lo)
            attn_step(KlB, VlB, PlB, qfL, oL, mL, sL, t == lo, lg, ll, qloc);

        asm volatile("" ::: "memory");
        __builtin_amdgcn_s_barrier();
        asm volatile("" ::: "memory");
    }

    const float invH = __builtin_amdgcn_rcpf(sH);
    const float invL = __builtin_amdgcn_rcpf(sL);
    const int qHrow = hi * 64 + wave * 16 + ll;
    const int qLrow = lo * 64 + wave * 16 + ll;
    #pragma unroll
    for (int nd = 0; nd < 8; ++nd) {
        bf16x4 aH, aL;
        #pragma unroll
        for (int r = 0; r < 4; ++r) {
            aH[r] = (__bf16)(oH[nd][r] * invH);
            aL[r] = (__bf16)(oL[nd][r] * invL);
        }
        const size_t cb = h * 128 + nd * 16 + lg * 4;
        *reinterpret_cast<bf16x4*>(&attnb[((size_t)(b * 2048) + qHrow) * 2048 + cb]) = aH;
        *reinterpret_cast<bf16x4*>(&attnb[((size_t)(b * 2048) + qLrow) * 2048 + cb]) = aL;
    }
    #undef STAGE_KV
}

// ---------- host launch ----------
extern "C" void kernel_launch(void* const* d_in, const int* in_sizes, int n_in,
                              void* d_out, int out_size, void* d_ws, size_t ws_size,
                              hipStream_t stream) {
    const float* x    = (const float*)d_in[0];
    const float* cosb = (const float*)d_in[1];
    const float* sinb = (const float*)d_in[2];
    const float* wq   = (const float*)d_in[3];
    const float* bq   = (const float*)d_in[4];
    const float* wk   = (const float*)d_in[5];
    const float* bk   = (const float*)d_in[6];
    const float* wv   = (const float*)d_in[7];
    const float* bv   = (const float*)d_in[8];
    const float* wo   = (const float*)d_in[9];
    float* out = (float*)d_out;

    char* ws = (char*)d_ws;
    __bf16* xb    = (__bf16*)(ws);                         // 16,777,216  (later reused as attnb)
    __bf16* wb    = (__bf16*)(ws + 16777216);              // 10,485,760  (wq|wk|wv rows, 2560x2048)
    __bf16* wob   = (__bf16*)(ws + 27262976);              //  8,388,608
    float*  biasc = (float*) (ws + 35651584);              //     16,384 (2560 used)
    __bf16* qTp   = (__bf16*)(ws + 77611008);              // 16,777,216
    __bf16* kTp   = (__bf16*)(ws + 94388224);              //  2,097,152
    __bf16* vTp   = (__bf16*)(ws + 96485376);              //  2,097,152

    // 1) convert all fp32 inputs to bf16 (exact-sized grid: 17408 blocks)
    cvt_all<<<17408, 256, 0, stream>>>(
        x,  xb,
        wq, wb,
        wk, wb + 4194304,
        wv, wb + 4718592,
        wo, wob);
    concat_bias<<<10, 256, 0, stream>>>(bq, bk, bv, biasc);

    // 2) fused QKV GEMM + bias + RoPE + layout  [160 wg, 512 thr, 128 KB LDS]
    gemm_qkv_rope<<<160, 512, 0, stream>>>(xb, wb, biasc, cosb, sinb, qTp, kTp, vTp);

    // 3) flash attention -> attnb (reuses xb region, bf16 (B,L,H*D))
    attn_kernel<<<512, 256, 0, stream>>>(qTp, kTp, vTp, xb);

    // 4) output GEMM: 256x128 tiles, grid 256 (perfect fill), pipelined
    gemm_out<<<256, 512, 0, stream>>>(xb, wob, out);
}

// Round 12
// 177.797 us; speedup vs baseline: 1.8363x; 1.0389x over previous
//
#include <hip/hip_runtime.h>
#include <hip/hip_bf16.h>
#include <cstdint>

// ---------- types ----------
typedef __bf16 bf16x8 __attribute__((ext_vector_type(8)));
typedef __bf16 bf16x4 __attribute__((ext_vector_type(4)));
typedef __bf16 bf16x2 __attribute__((ext_vector_type(2)));
typedef float  f32x4  __attribute__((ext_vector_type(4)));
typedef __attribute__((address_space(3))) __bf16 lds_bf16;
typedef __attribute__((address_space(1))) const __bf16 gl_bf16;

// ---------- merged fp32 -> bf16 convert (exact-sized 1-D grid) ----------
// wq/wk segments are written ROW-PERMUTED: within each 128-row head,
// original row d -> ((d&63)<<1) + (d>>6)  (pair-interleave: RoPE partner
// d^64 becomes the adjacent row). Inverse applied in the GEMM epilogue.
__global__ void cvt_all(const float* __restrict__ s0, __bf16* __restrict__ d0,
                        const float* __restrict__ s1, __bf16* __restrict__ d1,
                        const float* __restrict__ s2, __bf16* __restrict__ d2,
                        const float* __restrict__ s3, __bf16* __restrict__ d3,
                        const float* __restrict__ s4, __bf16* __restrict__ d4) {
    const int blk = blockIdx.x;
    const float* s; __bf16* d; int base; bool perm = false;
    if (blk < 8192)       { s = s0; d = d0; base = blk; }
    else if (blk < 12288) { s = s1; d = d1; base = blk - 8192;  perm = true; }
    else if (blk < 12800) { s = s2; d = d2; base = blk - 12288; perm = true; }
    else if (blk < 13312) { s = s3; d = d3; base = blk - 12800; }
    else                  { s = s4; d = d4; base = blk - 13312; }
    const int i = (base * 256 + threadIdx.x) * 4;
    float4 v = *reinterpret_cast<const float4*>(s + i);
    bf16x4 o;
    o.x = (__bf16)v.x; o.y = (__bf16)v.y; o.z = (__bf16)v.z; o.w = (__bf16)v.w;
    int iout = i;
    if (perm) {
        const int row = base >> 1;                 // 1024 elems = half row of 2048
        const int h = row >> 7, dd = row & 127;
        const int pr = (h << 7) + ((dd & 63) << 1) + (dd >> 6);
        iout = pr * 2048 + (base & 1) * 1024 + threadIdx.x * 4;
    }
    *reinterpret_cast<bf16x4*>(d + iout) = o;
}

// ---------- concat bq|bk|bv (Q/K parts pair-interleave-permuted) ----------
__global__ void concat_bias(const float* __restrict__ bq, const float* __restrict__ bk,
                            const float* __restrict__ bv, float* __restrict__ dst) {
    int t = blockIdx.x * blockDim.x + threadIdx.x;
    if (t < 2048) {
        const int h = t >> 7, d = t & 127;
        dst[(h << 7) + ((d & 63) << 1) + (d >> 6)] = bq[t];
    } else if (t < 2304) {
        const int u = t - 2048, kvh = u >> 7, d = u & 127;
        dst[2048 + (kvh << 7) + ((d & 63) << 1) + (d >> 6)] = bk[u];
    } else if (t < 2560) {
        dst[t] = bv[t - 2304];
    }
}

// ---------- stage one 128x64 half-tile: 2 global_load_lds per thread ----------
// LDS linear [row][chunk], content pre-swizzled: slot (row,c) holds global
// chunk (c ^ (row&7)).
__device__ __forceinline__ void stage_half(const __bf16* __restrict__ gbase, int K, int k0,
                                           lds_bf16* lbase, int tid) {
    const int cc = (tid & 7) ^ ((tid >> 3) & 7);
    const __bf16* s0 = gbase + (size_t)(tid >> 3) * K + k0 + cc * 8;
    __builtin_amdgcn_global_load_lds((gl_bf16*)s0, lbase + (tid >> 6) * 512, 16, 0, 0);
    const __bf16* s1 = gbase + (size_t)(64 + (tid >> 3)) * K + k0 + cc * 8;
    __builtin_amdgcn_global_load_lds((gl_bf16*)s1, lbase + 4096 + (tid >> 6) * 512, 16, 0, 0);
}

// ---------- stage a 320x64 B-tile: 5 stripes of 64 rows ----------
__device__ __forceinline__ void stage_B5(const __bf16* __restrict__ gbase, int K, int k0,
                                         lds_bf16* lbase, int tid) {
    const int cc = (tid & 7) ^ ((tid >> 3) & 7);
    #pragma unroll
    for (int s = 0; s < 5; ++s) {
        const __bf16* src = gbase + (size_t)(s * 64 + (tid >> 3)) * K + k0 + cc * 8;
        __builtin_amdgcn_global_load_lds((gl_bf16*)src, lbase + s * 4096 + (tid >> 6) * 512, 16, 0, 0);
    }
}

// ---------- out-proj GEMM (unchanged r10): 256x128 tile, grid 256 ----------
__global__ __launch_bounds__(512)
void gemm_out(const __bf16* __restrict__ A, const __bf16* __restrict__ B,
              float* __restrict__ C) {
    const int K = 2048, NT = 32;
    __shared__ __align__(16) char smem[98304];

    const int tid  = threadIdx.x;
    const int wave = tid >> 6, lane = tid & 63, lg = lane >> 4, ll = lane & 15;
    const int wr = wave >> 2, wc = wave & 3;

    const int orig = blockIdx.x;
    const int wg   = (orig & 7) * 32 + (orig >> 3);
    const int bm = wg >> 4, bn = wg & 15;

    const __bf16* Atile = A + (size_t)(bm * 256) * K;
    const __bf16* Btile = B + (size_t)(bn * 128) * K;

    lds_bf16* AsL = (lds_bf16*)smem;
    lds_bf16* BsL = (lds_bf16*)(smem + 65536);

    f32x4 acc[8][2];
    #pragma unroll
    for (int m = 0; m < 8; ++m)
        #pragma unroll
        for (int n = 0; n < 2; ++n)
            acc[m][n] = f32x4{0.f, 0.f, 0.f, 0.f};

    stage_half(Atile,                 K, 0, AsL,        tid);
    stage_half(Atile + (size_t)128*K, K, 0, AsL + 8192, tid);
    stage_half(Btile,                 K, 0, BsL,        tid);

    const char* smB = (const char*)smem;
    for (int t = 0; t < NT; ++t) {
        const int c   = t & 1;
        const int bfn = c ^ 1;
        const int k0n = ((t + 1 < NT) ? t + 1 : t) * 64;
        const char* AbB = smB + c * 32768 + wr * 16384;
        const char* BbB = smB + 65536 + c * 16384;
        bf16x8 af[8][2], bq[2][2];

        stage_half(Atile,                 K, k0n, AsL + bfn * 8192 * 2,        tid);
        stage_half(Atile + (size_t)128*K, K, k0n, AsL + bfn * 8192 * 2 + 8192, tid);
        asm volatile("s_waitcnt vmcnt(4)" ::: "memory");
        __builtin_amdgcn_s_barrier();
        asm volatile("" ::: "memory");
        #pragma unroll
        for (int kk = 0; kk < 2; ++kk) {
            #pragma unroll
            for (int mm = 0; mm < 8; ++mm)
                af[mm][kk] = *reinterpret_cast<const bf16x8*>(
                    AbB + (mm * 16 + ll) * 128 + (((kk * 4 + lg) ^ (ll & 7)) << 4));
            #pragma unroll
            for (int nn = 0; nn < 2; ++nn)
                bq[nn][kk] = *reinterpret_cast<const bf16x8*>(
                    BbB + (wc * 32 + nn * 16 + ll) * 128 + (((kk * 4 + lg) ^ (ll & 7)) << 4));
        }
        __builtin_amdgcn_s_setprio(1);
        #pragma unroll
        for (int kk = 0; kk < 2; ++kk)
            #pragma unroll
            for (int mm = 0; mm < 4; ++mm)
                #pragma unroll
                for (int nn = 0; nn < 2; ++nn)
                    acc[mm][nn] = __builtin_amdgcn_mfma_f32_16x16x32_bf16(af[mm][kk], bq[nn][kk], acc[mm][nn], 0, 0, 0);
        __builtin_amdgcn_s_setprio(0);
        asm volatile("" ::: "memory");
        __builtin_amdgcn_s_barrier();
        asm volatile("" ::: "memory");

        stage_half(Btile, K, k0n, BsL + bfn * 8192, tid);
        __builtin_amdgcn_s_setprio(1);
        #pragma unroll
        for (int kk = 0; kk < 2; ++kk)
            #pragma unroll
            for (int mm = 0; mm < 4; ++mm)
                #pragma unroll
                for (int nn = 0; nn < 2; ++nn)
                    acc[4 + mm][nn] = __builtin_amdgcn_mfma_f32_16x16x32_bf16(af[4 + mm][kk], bq[nn][kk], acc[4 + mm][nn], 0, 0, 0);
        __builtin_amdgcn_s_setprio(0);
        asm volatile("" ::: "memory");
        __builtin_amdgcn_s_barrier();
        asm volatile("" ::: "memory");
    }

    asm volatile("s_waitcnt vmcnt(0)" ::: "memory");

    #pragma unroll
    for (int m = 0; m < 8; ++m)
        #pragma unroll
        for (int n = 0; n < 2; ++n) {
            const int col = bn * 128 + wc * 32 + n * 16 + ll;
            #pragma unroll
            for (int r = 0; r < 4; ++r) {
                const int rowg = bm * 256 + wr * 128 + m * 16 + lg * 4 + r;
                C[(size_t)rowg * 2048 + col] = acc[m][n][r];
            }
        }
}

// ---------- QKV GEMM 128x320, grid 256 (FULL CU FILL), fused bias+RoPE ----------
// B rows pair-interleaved (cvt_all perm) -> RoPE partner = adjacent lane,
// exchanged via shfl_xor(.,1); no LDS epilogue exchange. Proven r8 2-phase
// schedule: issue 7 loads for t+1, vmcnt(7), bar, 18 frag reads, 40 MFMA, bar.
__global__ __launch_bounds__(512)
void gemm_qkv_rope(const __bf16* __restrict__ A, const __bf16* __restrict__ B,
                   const float* __restrict__ bias, const float* __restrict__ cosb,
                   const float* __restrict__ sinb, __bf16* __restrict__ qT,
                   __bf16* __restrict__ kT, __bf16* __restrict__ vT) {
    const int K = 2048, NT = 32;
    __shared__ __align__(16) char smem[114688];   // A: 2x16KB [0,32K); B: 2x40KB [32K,112K)

    const int tid  = threadIdx.x;
    const int wave = tid >> 6, lane = tid & 63, lg = lane >> 4, ll = lane & 15;
    const int wr = wave >> 2, wc = wave & 3;       // 2M x 4N; per-wave 64 x 80

    const int orig = blockIdx.x;                   // 256 wg, %8 == 0
    const int wg   = (orig & 7) * 32 + (orig >> 3);
    const int bm = wg >> 3, bn = wg & 7;           // 32 x 8

    const __bf16* Atile = A + (size_t)(bm * 128) * K;
    const __bf16* Btile = B + (size_t)(bn * 320) * K;

    lds_bf16* AsL = (lds_bf16*)smem;               // per buf 8192 elems
    lds_bf16* BsL = (lds_bf16*)(smem + 32768);     // per buf 20480 elems

    f32x4 acc[4][5];
    #pragma unroll
    for (int m = 0; m < 4; ++m)
        #pragma unroll
        for (int n = 0; n < 5; ++n)
            acc[m][n] = f32x4{0.f, 0.f, 0.f, 0.f};

    // prologue: tile 0 -> buf 0
    stage_half(Atile, K, 0, AsL, tid);
    stage_B5 (Btile, K, 0, BsL, tid);
    asm volatile("s_waitcnt vmcnt(0)" ::: "memory");
    __syncthreads();

    const char* smB = (const char*)smem;
    for (int t = 0; t < NT; ++t) {
        const int c   = t & 1;
        const int bfn = c ^ 1;
        const int k0n = ((t + 1 < NT) ? t + 1 : t) * 64;   // clamp keeps counts uniform

        // issue next tile's 7 loads
        stage_half(Atile, K, k0n, AsL + bfn * 8192,  tid);
        stage_B5 (Btile, K, k0n, BsL + bfn * 20480, tid);
        asm volatile("s_waitcnt vmcnt(7)" ::: "memory");   // retire THIS tile's 7
        __builtin_amdgcn_s_barrier();
        asm volatile("" ::: "memory");

        const char* AbB = smB + c * 16384 + wr * 8192;
        const char* BbB = smB + 32768 + c * 40960;
        bf16x8 af[4][2], bq[5][2];
        #pragma unroll
        for (int kk = 0; kk < 2; ++kk) {
            #pragma unroll
            for (int mm = 0; mm < 4; ++mm)
                af[mm][kk] = *reinterpret_cast<const bf16x8*>(
                    AbB + (mm * 16 + ll) * 128 + (((kk * 4 + lg) ^ (ll & 7)) << 4));
            #pragma unroll
            for (int nn = 0; nn < 5; ++nn)
                bq[nn][kk] = *reinterpret_cast<const bf16x8*>(
                    BbB + (wc * 80 + nn * 16 + ll) * 128 + (((kk * 4 + lg) ^ (ll & 7)) << 4));
        }
        __builtin_amdgcn_s_setprio(1);
        #pragma unroll
        for (int kk = 0; kk < 2; ++kk)
            #pragma unroll
            for (int mm = 0; mm < 4; ++mm)
                #pragma unroll
                for (int nn = 0; nn < 5; ++nn)
                    acc[mm][nn] = __builtin_amdgcn_mfma_f32_16x16x32_bf16(af[mm][kk], bq[nn][kk], acc[mm][nn], 0, 0, 0);
        __builtin_amdgcn_s_setprio(0);
        asm volatile("" ::: "memory");
        __builtin_amdgcn_s_barrier();
        asm volatile("" ::: "memory");
    }

    asm volatile("s_waitcnt vmcnt(0)" ::: "memory");   // drain clamped tail prefetch

    // ---- epilogue: per-section (uniform per 16-lane group) ----
    const float qscale = 0.08838834764831845f * 1.4426950408889634f;
    #pragma unroll
    for (int n = 0; n < 5; ++n) {
        const int scol = bn * 320 + wc * 80 + n * 16;   // 16-aligned section base
        const int gcol = scol + ll;
        if (scol >= 2304) {
            // V: bias only, transposed store (b, kv, d, l)
            const int kvh = (gcol - 2304) >> 7, d = (gcol - 2304) & 127;
            const float bv = bias[gcol];
            #pragma unroll
            for (int m = 0; m < 4; ++m) {
                const int rbase = bm * 128 + wr * 64 + m * 16 + lg * 4;
                const int b = rbase >> 11, l0 = rbase & 2047;
                bf16x4 o4;
                #pragma unroll
                for (int r = 0; r < 4; ++r) o4[r] = (__bf16)(acc[m][n][r] + bv);
                *reinterpret_cast<bf16x4*>(&vT[((size_t)(b * 2 + kvh) * 128 + d) * 2048 + l0]) = o4;
            }
        } else {
            const bool isQ = (scol < 2048);
            const float qsc = isQ ? qscale : 1.0f;
            const int p = gcol & 127;                       // pair-interleaved index
            const int d_out = (p >> 1) + ((p & 1) << 6);    // original d
            const float sgn = (p & 1) ? 1.f : -1.f;
            const float bv = bias[gcol];
            #pragma unroll
            for (int m = 0; m < 4; ++m) {
                #pragma unroll
                for (int r = 0; r < 4; ++r) {
                    const float self = acc[m][n][r] + bv;
                    const float part = __shfl_xor(self, 1);
                    const int rowg = bm * 128 + wr * 64 + m * 16 + lg * 4 + r;
                    const int b = rowg >> 11, l = rowg & 2047;
                    const float cc = cosb[l * 128 + d_out], ss = sinb[l * 128 + d_out];
                    const float val = (self * cc + sgn * part * ss) * qsc;
                    if (isQ) {
                        const int h = gcol >> 7;
                        qT[(((size_t)(b * 16 + h)) * 2048 + l) * 128 + d_out] = (__bf16)val;
                    } else {
                        const int kvh = (gcol - 2048) >> 7;
                        kT[(((size_t)(b * 2 + kvh)) * 2048 + l) * 128 + d_out] = (__bf16)val;
                    }
                }
            }
        }
    }
}

// ---------- attn: one Q-group step (unchanged) ----------
__device__ __forceinline__ void attn_step(const char* KlB, const char* VlB, char* PlB,
                                          const bf16x8* qf, f32x4* o, float& mrow, float& srow,
                                          bool diag, int lg, int ll, int qloc) {
    f32x4 s[4];
    #pragma unroll
    for (int n = 0; n < 4; ++n) s[n] = f32x4{0.f, 0.f, 0.f, 0.f};
    __builtin_amdgcn_s_setprio(1);
    #pragma unroll
    for (int kk = 0; kk < 4; ++kk)
        #pragma unroll
        for (int n = 0; n < 4; ++n) {
            const int row = n * 16 + ll;
            bf16x8 kf = *reinterpret_cast<const bf16x8*>(
                KlB + row * 256 + (((kk * 4 + lg) ^ (ll & 7)) << 4));
            s[n] = __builtin_amdgcn_mfma_f32_16x16x32_bf16(kf, qf[kk], s[n], 0, 0, 0);
        }
    __builtin_amdgcn_s_setprio(0);

    if (diag) {
        #pragma unroll
        for (int n = 0; n < 4; ++n)
            #pragma unroll
            for (int r = 0; r < 4; ++r)
                if (n * 16 + lg * 4 + r > qloc) s[n][r] = -3e38f;
    }

    float tmax = s[0][0];
    #pragma unroll
    for (int n = 0; n < 4; ++n)
        #pragma unroll
        for (int r = 0; r < 4; ++r) tmax = fmaxf(tmax, s[n][r]);
    tmax = fmaxf(tmax, __shfl_xor(tmax, 16));
    tmax = fmaxf(tmax, __shfl_xor(tmax, 32));
    const float mnew = fmaxf(mrow, tmax);
    const float scl = __builtin_amdgcn_exp2f(mrow - mnew);
    mrow = mnew;
    float rs = 0.f;
    #pragma unroll
    for (int n = 0; n < 4; ++n)
        #pragma unroll
        for (int r = 0; r < 4; ++r) {
            const float p = __builtin_amdgcn_exp2f(s[n][r] - mnew);
            s[n][r] = p;
            rs += p;
        }
    rs += __shfl_xor(rs, 16);
    rs += __shfl_xor(rs, 32);
    srow = srow * scl + rs;

    #pragma unroll
    for (int nd = 0; nd < 8; ++nd)
        #pragma unroll
        for (int r = 0; r < 4; ++r) o[nd][r] *= scl;

    #pragma unroll
    for (int n = 0; n < 4; ++n)
        #pragma unroll
        for (int rp = 0; rp < 2; ++rp) {
            const int col = n * 16 + lg * 4 + rp * 2;
            bf16x2 pk;
            pk.x = (__bf16)s[n][rp * 2];
            pk.y = (__bf16)s[n][rp * 2 + 1];
            *reinterpret_cast<bf16x2*>(
                PlB + ll * 128 + (((col >> 3) ^ (ll & 7)) << 4) + (col & 7) * 2) = pk;
        }

    __builtin_amdgcn_s_setprio(1);
    #pragma unroll
    for (int kk = 0; kk < 2; ++kk) {
        bf16x8 pf = *reinterpret_cast<const bf16x8*>(
            PlB + ll * 128 + (((kk * 4 + lg) ^ (ll & 7)) << 4));
        #pragma unroll
        for (int nd = 0; nd < 8; ++nd) {
            const int row = nd * 16 + ll;
            bf16x8 vf = *reinterpret_cast<const bf16x8*>(
                VlB + row * 128 + (((kk * 4 + lg) ^ (ll & 7)) << 4));
            o[nd] = __builtin_amdgcn_mfma_f32_16x16x32_bf16(vf, pf, o[nd], 0, 0, 0);
        }
    }
    __builtin_amdgcn_s_setprio(0);
}

// ---------- causal GQA flash attention (unchanged) ----------
__global__ __launch_bounds__(256)
void attn_kernel(const __bf16* __restrict__ qT, const __bf16* __restrict__ kT,
                 const __bf16* __restrict__ vT, __bf16* __restrict__ attnb) {
    const int bx = blockIdx.x;
    const int qp = bx >> 5;
    const int hb = bx & 31;
    const int h = hb >> 1, b = hb & 1;
    const int kv = h >> 3;
    const int lo = qp, hi = 31 - qp;
    const int tid = threadIdx.x, wave = tid >> 6, lane = tid & 63, lg = lane >> 4, ll = lane & 15;
    const int qloc = wave * 16 + ll;

    __shared__ __align__(16) char smem[73728];
    lds_bf16* ldsE = (lds_bf16*)smem;

    const __bf16* kbase = kT + (size_t)((b * 2 + kv) * 2048) * 128;
    const __bf16* vbase = vT + (size_t)((b * 2 + kv) * 128) * 2048;

    bf16x8 qfL[4], qfH[4];
    {
        const __bf16* q0 = qT + ((size_t)((b * 16 + h) * 2048) + lo * 64 + wave * 16 + ll) * 128;
        const __bf16* q1 = qT + ((size_t)((b * 16 + h) * 2048) + hi * 64 + wave * 16 + ll) * 128;
        #pragma unroll
        for (int kk = 0; kk < 4; ++kk) {
            qfL[kk] = *reinterpret_cast<const bf16x8*>(q0 + kk * 32 + lg * 8);
            qfH[kk] = *reinterpret_cast<const bf16x8*>(q1 + kk * 32 + lg * 8);
        }
    }

    f32x4 oL[8], oH[8];
    #pragma unroll
    for (int nd = 0; nd < 8; ++nd) { oL[nd] = f32x4{0.f,0.f,0.f,0.f}; oH[nd] = f32x4{0.f,0.f,0.f,0.f}; }
    float mL = -3e38f, sL = 0.f, mH = -3e38f, sH = 0.f;

    const int ntiles = hi + 1;

    #define STAGE_KV(j0, buf)                                                              \
        do {                                                                               \
            lds_bf16* kl = ldsE + (buf) * 16384;                                           \
            lds_bf16* vl = ldsE + (buf) * 16384 + 8192;                                    \
            _Pragma("unroll")                                                              \
            for (int i = 0; i < 4; ++i) {                                                  \
                const int li = i * 256 + tid;                                              \
                const int key = li >> 4, c = li & 15;                                      \
                const __bf16* src = kbase + (size_t)((j0) + key) * 128 + ((c ^ (key & 7)) * 8); \
                __builtin_amdgcn_global_load_lds((gl_bf16*)src, kl + i * 2048 + wave * 512, 16, 0, 0); \
            }                                                                              \
            _Pragma("unroll")                                                              \
            for (int i = 0; i < 4; ++i) {                                                  \
                const int li = i * 256 + tid;                                              \
                const int dd = li >> 3, cv = li & 7;                                       \
                const __bf16* src = vbase + (size_t)dd * 2048 + (j0) + ((cv ^ (dd & 7)) * 8); \
                __builtin_amdgcn_global_load_lds((gl_bf16*)src, vl + i * 2048 + wave * 512, 16, 0, 0); \
            }                                                                              \
        } while (0)

    STAGE_KV(0, 0);
    char* PlB = smem + 65536 + wave * 2048;

    for (int t = 0; t < ntiles; ++t) {
        const int tn = (t + 1 < ntiles) ? t + 1 : t;
        STAGE_KV(tn * 64, (t + 1) & 1);
        asm volatile("s_waitcnt vmcnt(8)" ::: "memory");
        __builtin_amdgcn_s_barrier();
        asm volatile("" ::: "memory");

        const char* KlB = smem + (t & 1) * 32768;
        const char* VlB = smem + (t & 1) * 32768 + 16384;

        attn_step(KlB, VlB, PlB, qfH, oH, mH, sH, t == hi, lg, ll, qloc);
        if (t <= lo)
            attn_step(KlB, VlB, PlB, qfL, oL, mL, sL, t == lo, lg, ll, qloc);

        asm volatile("" ::: "memory");
        __builtin_amdgcn_s_barrier();
        asm volatile("" ::: "memory");
    }

    const float invH = __builtin_amdgcn_rcpf(sH);
    const float invL = __builtin_amdgcn_rcpf(sL);
    const int qHrow = hi * 64 + wave * 16 + ll;
    const int qLrow = lo * 64 + wave * 16 + ll;
    #pragma unroll
    for (int nd = 0; nd < 8; ++nd) {
        bf16x4 aH, aL;
        #pragma unroll
        for (int r = 0; r < 4; ++r) {
            aH[r] = (__bf16)(oH[nd][r] * invH);
            aL[r] = (__bf16)(oL[nd][r] * invL);
        }
        const size_t cb = h * 128 + nd * 16 + lg * 4;
        *reinterpret_cast<bf16x4*>(&attnb[((size_t)(b * 2048) + qHrow) * 2048 + cb]) = aH;
        *reinterpret_cast<bf16x4*>(&attnb[((size_t)(b * 2048) + qLrow) * 2048 + cb]) = aL;
    }
    #undef STAGE_KV
}

// ---------- host launch ----------
extern "C" void kernel_launch(void* const* d_in, const int* in_sizes, int n_in,
                              void* d_out, int out_size, void* d_ws, size_t ws_size,
                              hipStream_t stream) {
    const float* x    = (const float*)d_in[0];
    const float* cosb = (const float*)d_in[1];
    const float* sinb = (const float*)d_in[2];
    const float* wq   = (const float*)d_in[3];
    const float* bq   = (const float*)d_in[4];
    const float* wk   = (const float*)d_in[5];
    const float* bk   = (const float*)d_in[6];
    const float* wv   = (const float*)d_in[7];
    const float* bv   = (const float*)d_in[8];
    const float* wo   = (const float*)d_in[9];
    float* out = (float*)d_out;

    char* ws = (char*)d_ws;
    __bf16* xb    = (__bf16*)(ws);                         // 16,777,216  (later reused as attnb)
    __bf16* wb    = (__bf16*)(ws + 16777216);              // 10,485,760  (wq|wk|wv rows, 2560x2048)
    __bf16* wob   = (__bf16*)(ws + 27262976);              //  8,388,608
    float*  biasc = (float*) (ws + 35651584);              //     16,384 (2560 used)
    __bf16* qTp   = (__bf16*)(ws + 77611008);              // 16,777,216
    __bf16* kTp   = (__bf16*)(ws + 94388224);              //  2,097,152
    __bf16* vTp   = (__bf16*)(ws + 96485376);              //  2,097,152

    // 1) convert all fp32 inputs to bf16 (wq/wk pair-interleave-permuted)
    cvt_all<<<17408, 256, 0, stream>>>(
        x,  xb,
        wq, wb,
        wk, wb + 4194304,
        wv, wb + 4718592,
        wo, wob);
    concat_bias<<<10, 256, 0, stream>>>(bq, bk, bv, biasc);

    // 2) fused QKV GEMM + bias + RoPE + layout  [256 wg = FULL FILL, 512 thr]
    gemm_qkv_rope<<<256, 512, 0, stream>>>(xb, wb, biasc, cosb, sinb, qTp, kTp, vTp);

    // 3) flash attention -> attnb (reuses xb region, bf16 (B,L,H*D))
    attn_kernel<<<512, 256, 0, stream>>>(qTp, kTp, vTp, xb);

    // 4) output GEMM: 256x128 tiles, grid 256 (perfect fill), pipelined
    gemm_out<<<256, 512, 0, stream>>>(xb, wob, out);
}

// Round 13
// 177.567 us; speedup vs baseline: 1.8387x; 1.0013x over previous
//
#include <hip/hip_runtime.h>
#include <hip/hip_bf16.h>
#include <cstdint>

// ---------- types ----------
typedef __bf16 bf16x8 __attribute__((ext_vector_type(8)));
typedef __bf16 bf16x4 __attribute__((ext_vector_type(4)));
typedef __bf16 bf16x2 __attribute__((ext_vector_type(2)));
typedef float  f32x4  __attribute__((ext_vector_type(4)));
typedef __attribute__((address_space(3))) __bf16 lds_bf16;
typedef __attribute__((address_space(1))) const __bf16 gl_bf16;

// ---------- merged fp32 -> bf16 convert (exact-sized 1-D grid) ----------
// wq/wk segments are written ROW-PERMUTED: within each 128-row head,
// original row d -> ((d&63)<<1) + (d>>6)  (pair-interleave: RoPE partner
// d^64 becomes the adjacent row). Inverse applied in the GEMM epilogue.
__global__ void cvt_all(const float* __restrict__ s0, __bf16* __restrict__ d0,
                        const float* __restrict__ s1, __bf16* __restrict__ d1,
                        const float* __restrict__ s2, __bf16* __restrict__ d2,
                        const float* __restrict__ s3, __bf16* __restrict__ d3,
                        const float* __restrict__ s4, __bf16* __restrict__ d4) {
    const int blk = blockIdx.x;
    const float* s; __bf16* d; int base; bool perm = false;
    if (blk < 8192)       { s = s0; d = d0; base = blk; }
    else if (blk < 12288) { s = s1; d = d1; base = blk - 8192;  perm = true; }
    else if (blk < 12800) { s = s2; d = d2; base = blk - 12288; perm = true; }
    else if (blk < 13312) { s = s3; d = d3; base = blk - 12800; }
    else                  { s = s4; d = d4; base = blk - 13312; }
    const int i = (base * 256 + threadIdx.x) * 4;
    float4 v = *reinterpret_cast<const float4*>(s + i);
    bf16x4 o;
    o.x = (__bf16)v.x; o.y = (__bf16)v.y; o.z = (__bf16)v.z; o.w = (__bf16)v.w;
    int iout = i;
    if (perm) {
        const int row = base >> 1;                 // 1024 elems = half row of 2048
        const int h = row >> 7, dd = row & 127;
        const int pr = (h << 7) + ((dd & 63) << 1) + (dd >> 6);
        iout = pr * 2048 + (base & 1) * 1024 + threadIdx.x * 4;
    }
    *reinterpret_cast<bf16x4*>(d + iout) = o;
}

// ---------- concat bq|bk|bv (Q/K parts pair-interleave-permuted) ----------
__global__ void concat_bias(const float* __restrict__ bq, const float* __restrict__ bk,
                            const float* __restrict__ bv, float* __restrict__ dst) {
    int t = blockIdx.x * blockDim.x + threadIdx.x;
    if (t < 2048) {
        const int h = t >> 7, d = t & 127;
        dst[(h << 7) + ((d & 63) << 1) + (d >> 6)] = bq[t];
    } else if (t < 2304) {
        const int u = t - 2048, kvh = u >> 7, d = u & 127;
        dst[2048 + (kvh << 7) + ((d & 63) << 1) + (d >> 6)] = bk[u];
    } else if (t < 2560) {
        dst[t] = bv[t - 2304];
    }
}

// ---------- stage one 128x64 half-tile: 2 global_load_lds per thread ----------
__device__ __forceinline__ void stage_half(const __bf16* __restrict__ gbase, int K, int k0,
                                           lds_bf16* lbase, int tid) {
    const int cc = (tid & 7) ^ ((tid >> 3) & 7);
    const __bf16* s0 = gbase + (size_t)(tid >> 3) * K + k0 + cc * 8;
    __builtin_amdgcn_global_load_lds((gl_bf16*)s0, lbase + (tid >> 6) * 512, 16, 0, 0);
    const __bf16* s1 = gbase + (size_t)(64 + (tid >> 3)) * K + k0 + cc * 8;
    __builtin_amdgcn_global_load_lds((gl_bf16*)s1, lbase + 4096 + (tid >> 6) * 512, 16, 0, 0);
}

// ---------- stage a 320x64 B-tile: 5 stripes of 64 rows ----------
__device__ __forceinline__ void stage_B5(const __bf16* __restrict__ gbase, int K, int k0,
                                         lds_bf16* lbase, int tid) {
    const int cc = (tid & 7) ^ ((tid >> 3) & 7);
    #pragma unroll
    for (int s = 0; s < 5; ++s) {
        const __bf16* src = gbase + (size_t)(s * 64 + (tid >> 3)) * K + k0 + cc * 8;
        __builtin_amdgcn_global_load_lds((gl_bf16*)src, lbase + s * 4096 + (tid >> 6) * 512, 16, 0, 0);
    }
}

// ---------- out-proj GEMM (unchanged): 256x128 tile, grid 256 ----------
__global__ __launch_bounds__(512)
void gemm_out(const __bf16* __restrict__ A, const __bf16* __restrict__ B,
              float* __restrict__ C) {
    const int K = 2048, NT = 32;
    __shared__ __align__(16) char smem[98304];

    const int tid  = threadIdx.x;
    const int wave = tid >> 6, lane = tid & 63, lg = lane >> 4, ll = lane & 15;
    const int wr = wave >> 2, wc = wave & 3;

    const int orig = blockIdx.x;
    const int wg   = (orig & 7) * 32 + (orig >> 3);
    const int bm = wg >> 4, bn = wg & 15;

    const __bf16* Atile = A + (size_t)(bm * 256) * K;
    const __bf16* Btile = B + (size_t)(bn * 128) * K;

    lds_bf16* AsL = (lds_bf16*)smem;
    lds_bf16* BsL = (lds_bf16*)(smem + 65536);

    f32x4 acc[8][2];
    #pragma unroll
    for (int m = 0; m < 8; ++m)
        #pragma unroll
        for (int n = 0; n < 2; ++n)
            acc[m][n] = f32x4{0.f, 0.f, 0.f, 0.f};

    stage_half(Atile,                 K, 0, AsL,        tid);
    stage_half(Atile + (size_t)128*K, K, 0, AsL + 8192, tid);
    stage_half(Btile,                 K, 0, BsL,        tid);

    const char* smB = (const char*)smem;
    for (int t = 0; t < NT; ++t) {
        const int c   = t & 1;
        const int bfn = c ^ 1;
        const int k0n = ((t + 1 < NT) ? t + 1 : t) * 64;
        const char* AbB = smB + c * 32768 + wr * 16384;
        const char* BbB = smB + 65536 + c * 16384;
        bf16x8 af[8][2], bq[2][2];

        stage_half(Atile,                 K, k0n, AsL + bfn * 8192 * 2,        tid);
        stage_half(Atile + (size_t)128*K, K, k0n, AsL + bfn * 8192 * 2 + 8192, tid);
        asm volatile("s_waitcnt vmcnt(4)" ::: "memory");
        __builtin_amdgcn_s_barrier();
        asm volatile("" ::: "memory");
        #pragma unroll
        for (int kk = 0; kk < 2; ++kk) {
            #pragma unroll
            for (int mm = 0; mm < 8; ++mm)
                af[mm][kk] = *reinterpret_cast<const bf16x8*>(
                    AbB + (mm * 16 + ll) * 128 + (((kk * 4 + lg) ^ (ll & 7)) << 4));
            #pragma unroll
            for (int nn = 0; nn < 2; ++nn)
                bq[nn][kk] = *reinterpret_cast<const bf16x8*>(
                    BbB + (wc * 32 + nn * 16 + ll) * 128 + (((kk * 4 + lg) ^ (ll & 7)) << 4));
        }
        __builtin_amdgcn_s_setprio(1);
        #pragma unroll
        for (int kk = 0; kk < 2; ++kk)
            #pragma unroll
            for (int mm = 0; mm < 4; ++mm)
                #pragma unroll
                for (int nn = 0; nn < 2; ++nn)
                    acc[mm][nn] = __builtin_amdgcn_mfma_f32_16x16x32_bf16(af[mm][kk], bq[nn][kk], acc[mm][nn], 0, 0, 0);
        __builtin_amdgcn_s_setprio(0);
        asm volatile("" ::: "memory");
        __builtin_amdgcn_s_barrier();
        asm volatile("" ::: "memory");

        stage_half(Btile, K, k0n, BsL + bfn * 8192, tid);
        __builtin_amdgcn_s_setprio(1);
        #pragma unroll
        for (int kk = 0; kk < 2; ++kk)
            #pragma unroll
            for (int mm = 0; mm < 4; ++mm)
                #pragma unroll
                for (int nn = 0; nn < 2; ++nn)
                    acc[4 + mm][nn] = __builtin_amdgcn_mfma_f32_16x16x32_bf16(af[4 + mm][kk], bq[nn][kk], acc[4 + mm][nn], 0, 0, 0);
        __builtin_amdgcn_s_setprio(0);
        asm volatile("" ::: "memory");
        __builtin_amdgcn_s_barrier();
        asm volatile("" ::: "memory");
    }

    asm volatile("s_waitcnt vmcnt(0)" ::: "memory");

    #pragma unroll
    for (int m = 0; m < 8; ++m)
        #pragma unroll
        for (int n = 0; n < 2; ++n) {
            const int col = bn * 128 + wc * 32 + n * 16 + ll;
            #pragma unroll
            for (int r = 0; r < 4; ++r) {
                const int rowg = bm * 256 + wr * 128 + m * 16 + lg * 4 + r;
                C[(size_t)rowg * 2048 + col] = acc[m][n][r];
            }
        }
}

// ---------- QKV GEMM 128x320, grid 256 (full fill), fused bias+RoPE (unchanged) ----------
__global__ __launch_bounds__(512)
void gemm_qkv_rope(const __bf16* __restrict__ A, const __bf16* __restrict__ B,
                   const float* __restrict__ bias, const float* __restrict__ cosb,
                   const float* __restrict__ sinb, __bf16* __restrict__ qT,
                   __bf16* __restrict__ kT, __bf16* __restrict__ vT) {
    const int K = 2048, NT = 32;
    __shared__ __align__(16) char smem[114688];   // A: 2x16KB [0,32K); B: 2x40KB [32K,112K)

    const int tid  = threadIdx.x;
    const int wave = tid >> 6, lane = tid & 63, lg = lane >> 4, ll = lane & 15;
    const int wr = wave >> 2, wc = wave & 3;       // 2M x 4N; per-wave 64 x 80

    const int orig = blockIdx.x;                   // 256 wg, %8 == 0
    const int wg   = (orig & 7) * 32 + (orig >> 3);
    const int bm = wg >> 3, bn = wg & 7;           // 32 x 8

    const __bf16* Atile = A + (size_t)(bm * 128) * K;
    const __bf16* Btile = B + (size_t)(bn * 320) * K;

    lds_bf16* AsL = (lds_bf16*)smem;               // per buf 8192 elems
    lds_bf16* BsL = (lds_bf16*)(smem + 32768);     // per buf 20480 elems

    f32x4 acc[4][5];
    #pragma unroll
    for (int m = 0; m < 4; ++m)
        #pragma unroll
        for (int n = 0; n < 5; ++n)
            acc[m][n] = f32x4{0.f, 0.f, 0.f, 0.f};

    // prologue: tile 0 -> buf 0
    stage_half(Atile, K, 0, AsL, tid);
    stage_B5 (Btile, K, 0, BsL, tid);
    asm volatile("s_waitcnt vmcnt(0)" ::: "memory");
    __syncthreads();

    const char* smB = (const char*)smem;
    for (int t = 0; t < NT; ++t) {
        const int c   = t & 1;
        const int bfn = c ^ 1;
        const int k0n = ((t + 1 < NT) ? t + 1 : t) * 64;   // clamp keeps counts uniform

        // issue next tile's 7 loads
        stage_half(Atile, K, k0n, AsL + bfn * 8192,  tid);
        stage_B5 (Btile, K, k0n, BsL + bfn * 20480, tid);
        asm volatile("s_waitcnt vmcnt(7)" ::: "memory");   // retire THIS tile's 7
        __builtin_amdgcn_s_barrier();
        asm volatile("" ::: "memory");

        const char* AbB = smB + c * 16384 + wr * 8192;
        const char* BbB = smB + 32768 + c * 40960;
        bf16x8 af[4][2], bq[5][2];
        #pragma unroll
        for (int kk = 0; kk < 2; ++kk) {
            #pragma unroll
            for (int mm = 0; mm < 4; ++mm)
                af[mm][kk] = *reinterpret_cast<const bf16x8*>(
                    AbB + (mm * 16 + ll) * 128 + (((kk * 4 + lg) ^ (ll & 7)) << 4));
            #pragma unroll
            for (int nn = 0; nn < 5; ++nn)
                bq[nn][kk] = *reinterpret_cast<const bf16x8*>(
                    BbB + (wc * 80 + nn * 16 + ll) * 128 + (((kk * 4 + lg) ^ (ll & 7)) << 4));
        }
        __builtin_amdgcn_s_setprio(1);
        #pragma unroll
        for (int kk = 0; kk < 2; ++kk)
            #pragma unroll
            for (int mm = 0; mm < 4; ++mm)
                #pragma unroll
                for (int nn = 0; nn < 5; ++nn)
                    acc[mm][nn] = __builtin_amdgcn_mfma_f32_16x16x32_bf16(af[mm][kk], bq[nn][kk], acc[mm][nn], 0, 0, 0);
        __builtin_amdgcn_s_setprio(0);
        asm volatile("" ::: "memory");
        __builtin_amdgcn_s_barrier();
        asm volatile("" ::: "memory");
    }

    asm volatile("s_waitcnt vmcnt(0)" ::: "memory");   // drain clamped tail prefetch

    // ---- epilogue: per-section (uniform per 16-lane group) ----
    const float qscale = 0.08838834764831845f * 1.4426950408889634f;
    #pragma unroll
    for (int n = 0; n < 5; ++n) {
        const int scol = bn * 320 + wc * 80 + n * 16;   // 16-aligned section base
        const int gcol = scol + ll;
        if (scol >= 2304) {
            // V: bias only, transposed store (b, kv, d, l)
            const int kvh = (gcol - 2304) >> 7, d = (gcol - 2304) & 127;
            const float bv = bias[gcol];
            #pragma unroll
            for (int m = 0; m < 4; ++m) {
                const int rbase = bm * 128 + wr * 64 + m * 16 + lg * 4;
                const int b = rbase >> 11, l0 = rbase & 2047;
                bf16x4 o4;
                #pragma unroll
                for (int r = 0; r < 4; ++r) o4[r] = (__bf16)(acc[m][n][r] + bv);
                *reinterpret_cast<bf16x4*>(&vT[((size_t)(b * 2 + kvh) * 128 + d) * 2048 + l0]) = o4;
            }
        } else {
            const bool isQ = (scol < 2048);
            const float qsc = isQ ? qscale : 1.0f;
            const int p = gcol & 127;                       // pair-interleaved index
            const int d_out = (p >> 1) + ((p & 1) << 6);    // original d
            const float sgn = (p & 1) ? 1.f : -1.f;
            const float bv = bias[gcol];
            #pragma unroll
            for (int m = 0; m < 4; ++m) {
                #pragma unroll
                for (int r = 0; r < 4; ++r) {
                    const float self = acc[m][n][r] + bv;
                    const float part = __shfl_xor(self, 1);
                    const int rowg = bm * 128 + wr * 64 + m * 16 + lg * 4 + r;
                    const int b = rowg >> 11, l = rowg & 2047;
                    const float cc = cosb[l * 128 + d_out], ss = sinb[l * 128 + d_out];
                    const float val = (self * cc + sgn * part * ss) * qsc;
                    if (isQ) {
                        const int h = gcol >> 7;
                        qT[(((size_t)(b * 16 + h)) * 2048 + l) * 128 + d_out] = (__bf16)val;
                    } else {
                        const int kvh = (gcol - 2048) >> 7;
                        kT[(((size_t)(b * 2 + kvh)) * 2048 + l) * 128 + d_out] = (__bf16)val;
                    }
                }
            }
        }
    }
}

// ---------- attn: one Q-group step with wave-uniform defer-max (T13) ----------
__device__ __forceinline__ void attn_step(const char* KlB, const char* VlB, char* PlB,
                                          const bf16x8* qf, f32x4* o, float& mrow, float& srow,
                                          bool diag, int lg, int ll, int qloc) {
    f32x4 s[4];
    #pragma unroll
    for (int n = 0; n < 4; ++n) s[n] = f32x4{0.f, 0.f, 0.f, 0.f};
    __builtin_amdgcn_s_setprio(1);
    #pragma unroll
    for (int kk = 0; kk < 4; ++kk)
        #pragma unroll
        for (int n = 0; n < 4; ++n) {
            const int row = n * 16 + ll;
            bf16x8 kf = *reinterpret_cast<const bf16x8*>(
                KlB + row * 256 + (((kk * 4 + lg) ^ (ll & 7)) << 4));
            s[n] = __builtin_amdgcn_mfma_f32_16x16x32_bf16(kf, qf[kk], s[n], 0, 0, 0);
        }
    __builtin_amdgcn_s_setprio(0);

    if (diag) {
        #pragma unroll
        for (int n = 0; n < 4; ++n)
            #pragma unroll
            for (int r = 0; r < 4; ++r)
                if (n * 16 + lg * 4 + r > qloc) s[n][r] = -3e38f;
    }

    float tmax = s[0][0];
    #pragma unroll
    for (int n = 0; n < 4; ++n)
        #pragma unroll
        for (int r = 0; r < 4; ++r) tmax = fmaxf(tmax, s[n][r]);
    tmax = fmaxf(tmax, __shfl_xor(tmax, 16));
    tmax = fmaxf(tmax, __shfl_xor(tmax, 32));

    // T13 defer-max: rescale only when some lane's tile-max exceeds the stale
    // running max by >8 (log2 units). Wave-uniform branch; P bounded by 2^8.
    if (__any(tmax > mrow + 8.f)) {
        const float mnew = fmaxf(mrow, tmax);
        const float scl = __builtin_amdgcn_exp2f(mrow - mnew);
        mrow = mnew;
        srow *= scl;
        #pragma unroll
        for (int nd = 0; nd < 8; ++nd)
            #pragma unroll
            for (int r = 0; r < 4; ++r) o[nd][r] *= scl;
    }

    float rs = 0.f;
    #pragma unroll
    for (int n = 0; n < 4; ++n)
        #pragma unroll
        for (int r = 0; r < 4; ++r) {
            const float p = __builtin_amdgcn_exp2f(s[n][r] - mrow);
            s[n][r] = p;
            rs += p;
        }
    rs += __shfl_xor(rs, 16);
    rs += __shfl_xor(rs, 32);
    srow += rs;

    #pragma unroll
    for (int n = 0; n < 4; ++n)
        #pragma unroll
        for (int rp = 0; rp < 2; ++rp) {
            const int col = n * 16 + lg * 4 + rp * 2;
            bf16x2 pk;
            pk.x = (__bf16)s[n][rp * 2];
            pk.y = (__bf16)s[n][rp * 2 + 1];
            *reinterpret_cast<bf16x2*>(
                PlB + ll * 128 + (((col >> 3) ^ (ll & 7)) << 4) + (col & 7) * 2) = pk;
        }

    __builtin_amdgcn_s_setprio(1);
    #pragma unroll
    for (int kk = 0; kk < 2; ++kk) {
        bf16x8 pf = *reinterpret_cast<const bf16x8*>(
            PlB + ll * 128 + (((kk * 4 + lg) ^ (ll & 7)) << 4));
        #pragma unroll
        for (int nd = 0; nd < 8; ++nd) {
            const int row = nd * 16 + ll;
            bf16x8 vf = *reinterpret_cast<const bf16x8*>(
                VlB + row * 128 + (((kk * 4 + lg) ^ (ll & 7)) << 4));
            o[nd] = __builtin_amdgcn_mfma_f32_16x16x32_bf16(vf, pf, o[nd], 0, 0, 0);
        }
    }
    __builtin_amdgcn_s_setprio(0);
}

// ---------- causal GQA flash attention (structure unchanged) ----------
__global__ __launch_bounds__(256)
void attn_kernel(const __bf16* __restrict__ qT, const __bf16* __restrict__ kT,
                 const __bf16* __restrict__ vT, __bf16* __restrict__ attnb) {
    const int bx = blockIdx.x;
    const int qp = bx >> 5;
    const int hb = bx & 31;
    const int h = hb >> 1, b = hb & 1;
    const int kv = h >> 3;
    const int lo = qp, hi = 31 - qp;
    const int tid = threadIdx.x, wave = tid >> 6, lane = tid & 63, lg = lane >> 4, ll = lane & 15;
    const int qloc = wave * 16 + ll;

    __shared__ __align__(16) char smem[73728];
    lds_bf16* ldsE = (lds_bf16*)smem;

    const __bf16* kbase = kT + (size_t)((b * 2 + kv) * 2048) * 128;
    const __bf16* vbase = vT + (size_t)((b * 2 + kv) * 128) * 2048;

    bf16x8 qfL[4], qfH[4];
    {
        const __bf16* q0 = qT + ((size_t)((b * 16 + h) * 2048) + lo * 64 + wave * 16 + ll) * 128;
        const __bf16* q1 = qT + ((size_t)((b * 16 + h) * 2048) + hi * 64 + wave * 16 + ll) * 128;
        #pragma unroll
        for (int kk = 0; kk < 4; ++kk) {
            qfL[kk] = *reinterpret_cast<const bf16x8*>(q0 + kk * 32 + lg * 8);
            qfH[kk] = *reinterpret_cast<const bf16x8*>(q1 + kk * 32 + lg * 8);
        }
    }

    f32x4 oL[8], oH[8];
    #pragma unroll
    for (int nd = 0; nd < 8; ++nd) { oL[nd] = f32x4{0.f,0.f,0.f,0.f}; oH[nd] = f32x4{0.f,0.f,0.f,0.f}; }
    float mL = -3e38f, sL = 0.f, mH = -3e38f, sH = 0.f;

    const int ntiles = hi + 1;

    #define STAGE_KV(j0, buf)                                                              \
        do {                                                                               \
            lds_bf16* kl = ldsE + (buf) * 16384;                                           \
            lds_bf16* vl = ldsE + (buf) * 16384 + 8192;                                    \
            _Pragma("unroll")                                                              \
            for (int i = 0; i < 4; ++i) {                                                  \
                const int li = i * 256 + tid;                                              \
                const int key = li >> 4, c = li & 15;                                      \
                const __bf16* src = kbase + (size_t)((j0) + key) * 128 + ((c ^ (key & 7)) * 8); \
                __builtin_amdgcn_global_load_lds((gl_bf16*)src, kl + i * 2048 + wave * 512, 16, 0, 0); \
            }                                                                              \
            _Pragma("unroll")                                                              \
            for (int i = 0; i < 4; ++i) {                                                  \
                const int li = i * 256 + tid;                                              \
                const int dd = li >> 3, cv = li & 7;                                       \
                const __bf16* src = vbase + (size_t)dd * 2048 + (j0) + ((cv ^ (dd & 7)) * 8); \
                __builtin_amdgcn_global_load_lds((gl_bf16*)src, vl + i * 2048 + wave * 512, 16, 0, 0); \
            }                                                                              \
        } while (0)

    STAGE_KV(0, 0);
    char* PlB = smem + 65536 + wave * 2048;

    for (int t = 0; t < ntiles; ++t) {
        const int tn = (t + 1 < ntiles) ? t + 1 : t;
        STAGE_KV(tn * 64, (t + 1) & 1);
        asm volatile("s_waitcnt vmcnt(8)" ::: "memory");
        __builtin_amdgcn_s_barrier();
        asm volatile("" ::: "memory");

        const char* KlB = smem + (t & 1) * 32768;
        const char* VlB = smem + (t & 1) * 32768 + 16384;

        attn_step(KlB, VlB, PlB, qfH, oH, mH, sH, t == hi, lg, ll, qloc);
        if (t <= lo)
            attn_step(KlB, VlB, PlB, qfL, oL, mL, sL, t == lo, lg, ll, qloc);

        asm volatile("" ::: "memory");
        __builtin_amdgcn_s_barrier();
        asm volatile("" ::: "memory");
    }

    const float invH = __builtin_amdgcn_rcpf(sH);
    const float invL = __builtin_amdgcn_rcpf(sL);
    const int qHrow = hi * 64 + wave * 16 + ll;
    const int qLrow = lo * 64 + wave * 16 + ll;
    #pragma unroll
    for (int nd = 0; nd < 8; ++nd) {
        bf16x4 aH, aL;
        #pragma unroll
        for (int r = 0; r < 4; ++r) {
            aH[r] = (__bf16)(oH[nd][r] * invH);
            aL[r] = (__bf16)(oL[nd][r] * invL);
        }
        const size_t cb = h * 128 + nd * 16 + lg * 4;
        *reinterpret_cast<bf16x4*>(&attnb[((size_t)(b * 2048) + qHrow) * 2048 + cb]) = aH;
        *reinterpret_cast<bf16x4*>(&attnb[((size_t)(b * 2048) + qLrow) * 2048 + cb]) = aL;
    }
    #undef STAGE_KV
}

// ---------- host launch ----------
extern "C" void kernel_launch(void* const* d_in, const int* in_sizes, int n_in,
                              void* d_out, int out_size, void* d_ws, size_t ws_size,
                              hipStream_t stream) {
    const float* x    = (const float*)d_in[0];
    const float* cosb = (const float*)d_in[1];
    const float* sinb = (const float*)d_in[2];
    const float* wq   = (const float*)d_in[3];
    const float* bq   = (const float*)d_in[4];
    const float* wk   = (const float*)d_in[5];
    const float* bk   = (const float*)d_in[6];
    const float* wv   = (const float*)d_in[7];
    const float* bv   = (const float*)d_in[8];
    const float* wo   = (const float*)d_in[9];
    float* out = (float*)d_out;

    char* ws = (char*)d_ws;
    __bf16* xb    = (__bf16*)(ws);                         // 16,777,216  (later reused as attnb)
    __bf16* wb    = (__bf16*)(ws + 16777216);              // 10,485,760  (wq|wk|wv rows, 2560x2048)
    __bf16* wob   = (__bf16*)(ws + 27262976);              //  8,388,608
    float*  biasc = (float*) (ws + 35651584);              //     16,384 (2560 used)
    __bf16* qTp   = (__bf16*)(ws + 77611008);              // 16,777,216
    __bf16* kTp   = (__bf16*)(ws + 94388224);              //  2,097,152
    __bf16* vTp   = (__bf16*)(ws + 96485376);              //  2,097,152

    // 1) convert all fp32 inputs to bf16 (wq/wk pair-interleave-permuted)
    cvt_all<<<17408, 256, 0, stream>>>(
        x,  xb,
        wq, wb,
        wk, wb + 4194304,
        wv, wb + 4718592,
        wo, wob);
    concat_bias<<<10, 256, 0, stream>>>(bq, bk, bv, biasc);

    // 2) fused QKV GEMM + bias + RoPE + layout  [256 wg = full fill, 512 thr]
    gemm_qkv_rope<<<256, 512, 0, stream>>>(xb, wb, biasc, cosb, sinb, qTp, kTp, vTp);

    // 3) flash attention -> attnb (reuses xb region, bf16 (B,L,H*D))
    attn_kernel<<<512, 256, 0, stream>>>(qTp, kTp, vTp, xb);

    // 4) output GEMM: 256x128 tiles, grid 256 (perfect fill), pipelined
    gemm_out<<<256, 512, 0, stream>>>(xb, wob, out);
}